// Round 10
// baseline (486.417 us; speedup 1.0000x reference)
//
#include <hip/hip_runtime.h>

#define BB 8
#define NN 2048
#define CC 128
#define KMAX 32
#define NEG 0.2f
#define CH 16
#define CHSZ (NN / CH)   // 128
#define CAP 16           // per-thread candidate buffer (drain-on-full keeps j order)

// Map f32 to a u32 whose unsigned order == float order (handles negatives).
__device__ __forceinline__ unsigned int f2key(float f) {
  unsigned int b = __float_as_uint(f);
  return (b & 0x80000000u) ? ~b : (b | 0x80000000u);
}

// np-exact f32 squared norm: fl(fl(x^2+y^2)+z^2), no FMA contraction.
__device__ __forceinline__ float sq3(float x, float y, float z) {
  return __fadd_rn(__fadd_rn(__fmul_rn(x, x), __fmul_rn(y, y)), __fmul_rn(z, z));
}

// np-exact f32 distance key: d2 = fl( fl(sq_i+sq_j) - fl(2*dot) ),
// dot = fma(a2,b2, fma(a1,b1, round(a0*b0)))  (BLAS K-ascending FMA chain).
__device__ __forceinline__ float d2np(float px, float py, float pz, float sqq,
                                      float qx, float qy, float qz, float sqj) {
  float dot = __fmaf_rn(pz, qz, __fmaf_rn(py, qy, __fmul_rn(px, qx)));
  return __fsub_rn(__fadd_rn(sqq, sqj), __fmul_rn(2.0f, dot));
}

// ---------------------------------------------------------------------------
// K0: pack positions + squared norm into float4 (one 16B load per candidate).
// Same sq3 formula as before -> identical key values.
// ---------------------------------------------------------------------------
__global__ __launch_bounds__(256) void pos_stage(const float* __restrict__ pos,
                                                 float4* __restrict__ pos4) {
  int t = blockIdx.x * 256 + threadIdx.x;        // 0 .. BB*NN-1
  float x = pos[t * 3 + 0];
  float y = pos[t * 3 + 1];
  float z = pos[t * 3 + 2];
  pos4[t] = make_float4(x, y, z, sq3(x, y, z));
}

// ---------------------------------------------------------------------------
// K1a: KNN phase 1 — threshold-gated chunked selection, np-bit-exact keys.
// Restructured for occupancy: CH=16 chunks of 128, positions read from the
// L1-resident pos4 array (no position LDS), 16 queries/block, grid 1024.
// Selection semantics unchanged: the final nbr is the global stable
// (key, lower-j) top-32, which is chunk-partition invariant (validated R9).
// Pass A: top-2 keys per chunk -> T = max over 16 chunks of 2nd-smallest
//         (32 distinct candidates <= T => T >= true 32nd key; gate keeps
//         every global-top-32 member, ties at T included).
// Pass B: gate, buffer (j order), drain through the proven stable insert.
// Block = 256 threads = 16 queries x 16 chunks. Grid = 1024.
// ---------------------------------------------------------------------------
__global__ __launch_bounds__(256) void knn_p1(const float4* __restrict__ pos4,
                                              unsigned short* __restrict__ cand,
                                              unsigned int* __restrict__ candk) {
  __shared__ unsigned int sred[256];
  __shared__ unsigned short sbuf[256 * CAP];
  int b = blockIdx.x >> 7;                       // 128 blocks per batch
  int qbase = (blockIdx.x & 127) << 4;           // 16 queries per block
  const float4* pb = pos4 + (size_t)b * NN;

  int tid = threadIdx.x;
  int q = qbase + (tid >> 4);
  int c = tid & 15;
  float4 pq = pb[q];
  float px = pq.x, py = pq.y, pz = pq.z, sqq = pq.w;

  int j0 = c * CHSZ;

  // ---- Pass A: keys-only top-2 of this chunk (strict <, self-excluded) ----
  unsigned int a0 = 0xFFFFFFFFu, a1 = 0xFFFFFFFFu;
  for (int jj = 0; jj < CHSZ; ++jj) {
    int j = j0 + jj;
    float4 pj = pb[j];
    float d2 = d2np(px, py, pz, sqq, pj.x, pj.y, pj.z, pj.w);
    unsigned int key = f2key(d2);
    if (j == q) key = 0xFFFFFFFFu;
    if (key < a1) {
      bool c1 = key < a0;
      a1 = c1 ? a0 : key;
      a0 = c1 ? key : a0;
    }
  }
  sred[tid] = a1;
  __syncthreads();
  if (c == 0) {
    unsigned int m = sred[tid];
#pragma unroll
    for (int u = 1; u < CH; ++u) {
      unsigned int v = sred[tid + u];
      m = v > m ? v : m;
    }
    sred[tid] = m;
  }
  __syncthreads();
  unsigned int T = sred[tid & ~15];

  // ---- Pass B: gate, buffer, drain through the exact stable insert ----
  unsigned int ak[KMAX];
  int ai[KMAX];
#pragma unroll
  for (int k = 0; k < KMAX; ++k) { ak[k] = 0xFFFFFFFFu; ai[k] = 0xFFFF; }

  int sbase = tid * CAP;
  auto drain = [&](int cnt2) {
    for (int u = 0; u < cnt2; ++u) {
      int jj2 = (int)sbuf[sbase + u];
      int j = j0 + jj2;
      float4 pj = pb[j];
      float d2 = d2np(px, py, pz, sqq, pj.x, pj.y, pj.z, pj.w);
      unsigned int key = f2key(d2);               // self never buffered
      if (key < ak[KMAX - 1]) {                   // strict: stable ties -> lower j
#pragma unroll
        for (int k = KMAX - 1; k >= 1; --k) {
          bool ck  = key < ak[k];
          bool ckm = key < ak[k - 1];
          unsigned int tk = ckm ? ak[k - 1] : key;
          int          ti = ckm ? ai[k - 1] : j;
          ak[k] = ck ? tk : ak[k];
          ai[k] = ck ? ti : ai[k];
        }
        bool c0b = key < ak[0];
        ak[0] = c0b ? key : ak[0];
        ai[0] = c0b ? j : ai[0];
      }
    }
  };

  int cnt = 0;
  for (int jj = 0; jj < CHSZ; ++jj) {
    int j = j0 + jj;
    float4 pj = pb[j];
    float d2 = d2np(px, py, pz, sqq, pj.x, pj.y, pj.z, pj.w);
    unsigned int key = f2key(d2);
    if (j == q) key = 0xFFFFFFFFu;               // self fails gate (T < max)
    if (key <= T) {
      if (cnt == CAP) { drain(CAP); cnt = 0; }   // rare; preserves j order
      sbuf[sbase + cnt] = (unsigned short)jj;
      ++cnt;
    }
  }
  drain(cnt);

  size_t obase = (((size_t)(b * NN + q)) * CH + c) * KMAX;
  unsigned short* oc = cand + obase;
  unsigned int* ok = candk + obase;
#pragma unroll
  for (int k = 0; k < KMAX; ++k) {
    oc[k] = (unsigned short)ai[k];
    ok[k] = ak[k];
  }
}

// ---------------------------------------------------------------------------
// K1b: KNN phase 2 — 16-way merge of the stable-sorted chunk lists.
// Strict-< argmin scanning c=0..15 reproduces the (key, lower-j) stable rule
// (chunks are j-contiguous ascending) -> nbr identical to R9's validated
// selection. Sentinels (key 0xFFFFFFFF) never win while >=32 real entries
// exist (guaranteed by the gate). One thread per query.
// ---------------------------------------------------------------------------
__global__ __launch_bounds__(64) void knn_p2(const unsigned int* __restrict__ candk,
                                             const unsigned short* __restrict__ cand,
                                             int* __restrict__ nbr) {
  int q = blockIdx.x * 64 + threadIdx.x;         // global query id (b*NN+n)
  const unsigned int* k8 = candk + (size_t)q * (CH * KMAX);
  const unsigned short* i8 = cand + (size_t)q * (CH * KMAX);

  int head[CH];
  unsigned int hk[CH];
#pragma unroll
  for (int c = 0; c < CH; ++c) {
    head[c] = 0;
    hk[c] = k8[c * KMAX];
  }

  int* onb = nbr + (size_t)q * KMAX;
#pragma unroll
  for (int r = 0; r < KMAX; ++r) {
    int bc = 0;
    unsigned int bk = hk[0];
#pragma unroll
    for (int c = 1; c < CH; ++c) {
      if (hk[c] < bk) { bk = hk[c]; bc = c; }    // strict: ties -> lower c = lower j
    }
    onb[r] = (int)i8[bc * KMAX + head[bc]];
    ++head[bc];
    hk[bc] = (head[bc] < KMAX) ? k8[bc * KMAX + head[bc]] : 0xFFFFFFFFu;
  }
}

// ---------------------------------------------------------------------------
// K2: f32 tiled GEMM  out[M][128] = concat(A1[:,0:K1], A2[:,0:K-K1]) @ W
// blockIdx.z selects among up to 6 weight matrices and output slices.
// (verbatim from the R9 passing kernel)
// ---------------------------------------------------------------------------
__global__ __launch_bounds__(256) void gemm_kernel(
    const float* __restrict__ A1, int lda1, int K1,
    const float* __restrict__ A2, int lda2, int K,
    const float* __restrict__ Wa, const float* __restrict__ Wb,
    const float* __restrict__ Wc, const float* __restrict__ bias,
    float* __restrict__ outbase, int applyLeaky) {
  __shared__ float At[8][64];
  __shared__ float Wt[8][CC];

  int z = blockIdx.z;
  const float* W = (z < 2) ? (Wa + (size_t)z * CC * CC)
                 : (z < 4) ? (Wb + (size_t)(z - 2) * CC * CC)
                           : (Wc + (size_t)(z - 4) * CC * CC);
  float* out = outbase + (size_t)z * ((size_t)BB * NN * CC);

  int m0 = blockIdx.x * 64;
  int tid = threadIdx.x;
  int cg = tid & 31;
  int rg = tid >> 5;

  float acc[8][4];
#pragma unroll
  for (int r = 0; r < 8; ++r)
#pragma unroll
    for (int q = 0; q < 4; ++q) acc[r][q] = 0.f;

  int ksteps = (K + 7) >> 3;
  for (int ks = 0; ks < ksteps; ++ks) {
    int k0 = ks << 3;
    __syncthreads();
    {
      int f = tid * 2;
      int m = f >> 3;
      int kk = f & 7;
      int gm = m0 + m;
#pragma unroll
      for (int u = 0; u < 2; ++u) {
        int k = k0 + kk + u;
        float v = 0.f;
        if (k < K1) v = A1[(size_t)gm * lda1 + k];
        else if (k < K) v = A2[(size_t)gm * lda2 + (k - K1)];
        At[kk + u][m] = v;
      }
    }
    {
      int kk = tid >> 5;
      int c = (tid & 31) * 4;
      int k = k0 + kk;
      float4 w = make_float4(0.f, 0.f, 0.f, 0.f);
      if (k < K) w = *(const float4*)(W + (size_t)k * CC + c);
      *(float4*)(&Wt[kk][c]) = w;
    }
    __syncthreads();
#pragma unroll
    for (int kk = 0; kk < 8; ++kk) {
      float4 a0 = *(const float4*)(&At[kk][rg * 8]);
      float4 a1 = *(const float4*)(&At[kk][rg * 8 + 4]);
      float4 w = *(const float4*)(&Wt[kk][cg * 4]);
      float a[8] = {a0.x, a0.y, a0.z, a0.w, a1.x, a1.y, a1.z, a1.w};
#pragma unroll
      for (int r = 0; r < 8; ++r) {
        acc[r][0] += a[r] * w.x;
        acc[r][1] += a[r] * w.y;
        acc[r][2] += a[r] * w.z;
        acc[r][3] += a[r] * w.w;
      }
    }
  }

#pragma unroll
  for (int r = 0; r < 8; ++r) {
    int m = m0 + rg * 8 + r;
#pragma unroll
    for (int q = 0; q < 4; ++q) {
      int c = cg * 4 + q;
      float v = acc[r][q];
      if (bias) v += bias[c];
      if (applyLeaky) v = v > 0.f ? v : NEG * v;
      out[(size_t)m * CC + c] = v;
    }
  }
}

// ---------------------------------------------------------------------------
// K3: fused attention — both dilations in one launch, one h read/write.
// (verbatim from the R9 passing kernel)
// ---------------------------------------------------------------------------
__global__ __launch_bounds__(128) void attn2_kernel(
    const float* __restrict__ pos, const int* __restrict__ nbr,
    const float* __restrict__ s0, const float* __restrict__ v0,
    const float* __restrict__ t0,
    const float* __restrict__ s1, const float* __restrict__ v1,
    const float* __restrict__ t1,
    const float* __restrict__ Wpos, const float* __restrict__ bpos,
    float* __restrict__ h) {
  int bn = blockIdx.x;
  int b = bn >> 11;
  int n = bn & (NN - 1);
  int c = threadIdx.x;

  const float* pb = pos + (size_t)b * NN * 3;
  float pix = pb[n * 3 + 0], piy = pb[n * 3 + 1], piz = pb[n * 3 + 2];
  const int* nb = nbr + (size_t)bn * KMAX;

  float ht = h[(size_t)bn * CC + c];             // h_in (Wg output)

#pragma unroll
  for (int l = 0; l < 2; ++l) {
    int dil = l + 1;
    const float* s = l ? s1 : s0;
    const float* v = l ? v1 : v0;
    const float* t = l ? t1 : t0;
    const float* Wp = Wpos + (size_t)l * 3 * CC;
    float w0 = Wp[c], w1 = Wp[CC + c], w2 = Wp[2 * CC + c];
    float bp = bpos[(size_t)l * CC + c];
    float tc = t[(size_t)bn * CC + c];

    float alpha[17], del[17];
    float mx = -1e30f;
#pragma unroll
    for (int j = 0; j < 17; ++j) {
      int idx = (j < 16) ? nb[j * dil] : n;
      float dx = pix - pb[idx * 3 + 0];
      float dy = piy - pb[idx * 3 + 1];
      float dz = piz - pb[idx * 3 + 2];
      float d = dx * w0 + dy * w1 + dz * w2 + bp;
      del[j] = d;
      float sc = s[((size_t)(b * NN + idx)) * CC + c];
      float a = tc - sc + d;
      alpha[j] = a;
      mx = fmaxf(mx, a);
    }
    float sum = 0.f;
#pragma unroll
    for (int j = 0; j < 17; ++j) {
      float w = expf(alpha[j] - mx);
      alpha[j] = w;
      sum += w;
    }
    float inv = 1.f / sum;
    float hc = 0.f;
#pragma unroll
    for (int j = 0; j < 17; ++j) {
      int idx = (j < 16) ? nb[j * dil] : n;
      float vc = v[((size_t)(b * NN + idx)) * CC + c];
      hc += alpha[j] * (vc + del[j]);
    }
    ht += hc * inv;
  }

  h[(size_t)bn * CC + c] = ht;
}

// ---------------------------------------------------------------------------
// K5: out[m][0..2] = g[m] @ W2 + b2 + pos[m].  One wave per point.
// (verbatim from the R9 passing kernel)
// ---------------------------------------------------------------------------
__global__ __launch_bounds__(64) void final_kernel(
    const float* __restrict__ g, const float* __restrict__ W2,
    const float* __restrict__ b2, const float* __restrict__ pos,
    float* __restrict__ out) {
  int m = blockIdx.x;
  int k = threadIdx.x;
  float g0 = g[(size_t)m * CC + k];
  float g1 = g[(size_t)m * CC + 64 + k];
  float p0 = g0 * W2[k * 3 + 0] + g1 * W2[(k + 64) * 3 + 0];
  float p1 = g0 * W2[k * 3 + 1] + g1 * W2[(k + 64) * 3 + 1];
  float p2 = g0 * W2[k * 3 + 2] + g1 * W2[(k + 64) * 3 + 2];
#pragma unroll
  for (int off = 32; off >= 1; off >>= 1) {
    p0 += __shfl_down(p0, off);
    p1 += __shfl_down(p1, off);
    p2 += __shfl_down(p2, off);
  }
  if (k == 0) {
    out[m * 3 + 0] = p0 + b2[0] + pos[m * 3 + 0];
    out[m * 3 + 1] = p1 + b2[1] + pos[m * 3 + 1];
    out[m * 3 + 2] = p2 + b2[2] + pos[m * 3 + 2];
  }
}

extern "C" void kernel_launch(void* const* d_in, const int* in_sizes, int n_in,
                              void* d_out, int out_size, void* d_ws, size_t ws_size,
                              hipStream_t stream) {
  const float* x     = (const float*)d_in[0];
  const float* pos   = (const float*)d_in[1];
  const float* W_lin = (const float*)d_in[2];
  const float* W_src = (const float*)d_in[3];
  const float* W_dst = (const float*)d_in[4];
  const float* W_pos = (const float*)d_in[5];
  const float* b_pos = (const float*)d_in[6];
  const float* Wg    = (const float*)d_in[7];
  const float* bg    = (const float*)d_in[8];
  const float* W1    = (const float*)d_in[9];
  const float* b1    = (const float*)d_in[10];
  const float* W2    = (const float*)d_in[11];
  const float* b2    = (const float*)d_in[12];
  float* out = (float*)d_out;

  const size_t M = (size_t)BB * NN;        // 16384
  const size_t MC = M * CC;                // 2,097,152 floats

  // Same total footprint as the proven R9 layout (74.4 MB).
  char* ws = (char*)d_ws;
  int* nbr = (int*)ws;                               // 2 MB, alive throughout
  // old dedicated cand region (8.4 MB): first 256 KB hosts pos4
  float4* pos4 = (float4*)(ws + M * KMAX * sizeof(int));
  float* fb = (float*)(ws + M * KMAX * sizeof(int) + M * 8 * KMAX * sizeof(unsigned short));
  float* sb0 = fb + 0 * MC;
  float* sb1 = fb + 1 * MC;
  float* vb0 = fb + 2 * MC;
  float* vb1 = fb + 3 * MC;
  float* tb0 = fb + 4 * MC;
  float* tb1 = fb + 5 * MC;
  float* h   = fb + 6 * MC;
  float* g   = fb + 7 * MC;
  // candk (u32, M*CH*KMAX = 4*MC u32 = 33.5 MB) + cand (u16, 2*MC floats
  // worth = 16.8 MB) alias fb[0..6*MC): dead before the proj GEMM writes.
  unsigned int* candk = (unsigned int*)fb;
  unsigned short* cand = (unsigned short*)(fb + 4 * MC);

  // 1. KNN: stage pos4, gated chunk selection, 16-way sorted merge
  pos_stage<<<M / 256, 256, 0, stream>>>(pos, pos4);
  knn_p1<<<1024, 256, 0, stream>>>(pos4, cand, candk);
  knn_p2<<<256, 64, 0, stream>>>(candk, cand, nbr);

  // 2. six projections fused in ONE launch (z: sb0,sb1,vb0,vb1,tb0,tb1)
  gemm_kernel<<<dim3(M / 64, 1, 6), 256, 0, stream>>>(
      x, CC, CC, nullptr, 0, CC, W_src, W_lin, W_dst, nullptr, fb, 0);

  // 3. h = leaky(concat(x,pos) @ Wg + bg)
  gemm_kernel<<<dim3(M / 64, 1, 1), 256, 0, stream>>>(
      x, CC, CC, pos, 3, CC + 3, Wg, nullptr, nullptr, bg, h, 1);

  // 4. h += attention, both dilations fused
  attn2_kernel<<<M, 128, 0, stream>>>(pos, nbr, sb0, vb0, tb0,
                                      sb1, vb1, tb1, W_pos, b_pos, h);

  // 5. g = leaky(h @ W1 + b1)
  gemm_kernel<<<dim3(M / 64, 1, 1), 256, 0, stream>>>(
      h, CC, CC, nullptr, 0, CC, W1, nullptr, nullptr, b1, g, 1);

  // 6. out = g @ W2 + b2 + pos
  final_kernel<<<M, 64, 0, stream>>>(g, W2, b2, pos, out);
}

// Round 11
// 385.339 us; speedup vs baseline: 1.2623x; 1.2623x over previous
//
#include <hip/hip_runtime.h>

#define BB 8
#define NN 2048
#define CC 128
#define KMAX 32
#define NEG 0.2f
#define CH 8
#define CHSZ (NN / CH)   // 256
#define CPAD 260         // chunk stride in LDS: (260*c+jj)%32 = (4c+jj)%32 -> 8 distinct banks
#define CAP 32           // per-thread candidate buffer (drain-on-full keeps j order)

// Map f32 to a u32 whose unsigned order == float order (handles negatives).
__device__ __forceinline__ unsigned int f2key(float f) {
  unsigned int b = __float_as_uint(f);
  return (b & 0x80000000u) ? ~b : (b | 0x80000000u);
}

// np-exact f32 squared norm: fl(fl(x^2+y^2)+z^2), no FMA contraction.
__device__ __forceinline__ float sq3(float x, float y, float z) {
  return __fadd_rn(__fadd_rn(__fmul_rn(x, x), __fmul_rn(y, y)), __fmul_rn(z, z));
}

// np-exact f32 distance key: d2 = fl( fl(sq_i+sq_j) - fl(2*dot) ),
// dot = fma(a2,b2, fma(a1,b1, round(a0*b0)))  (BLAS K-ascending FMA chain).
__device__ __forceinline__ float d2np(float px, float py, float pz, float sqq,
                                      float qx, float qy, float qz, float sqj) {
  float dot = __fmaf_rn(pz, qz, __fmaf_rn(py, qy, __fmul_rn(px, qx)));
  return __fsub_rn(__fadd_rn(sqq, sqj), __fmul_rn(2.0f, dot));
}

// ---------------------------------------------------------------------------
// K1a: KNN phase 1 — threshold-gated chunked selection, np-bit-exact keys.
// FROZEN: verbatim from the R9 passing kernel (361 µs / absmax 0.00195).
// Block = 256 threads = 32 queries x 8 chunks of one batch. Grid = 512.
// ---------------------------------------------------------------------------
__global__ __launch_bounds__(256) void knn_p1(const float* __restrict__ pos,
                                              unsigned short* __restrict__ cand,
                                              unsigned int* __restrict__ candk) {
  __shared__ float spx[CH * CPAD], spy[CH * CPAD], spz[CH * CPAD], ssq[CH * CPAD];
  __shared__ unsigned int sred[256];
  __shared__ unsigned short sbuf[256 * CAP];
  int b = blockIdx.x >> 6;                       // 64 blocks per batch
  int qbase = (blockIdx.x & 63) * 32;
  const float* pb = pos + (size_t)b * NN * 3;
  for (int t = threadIdx.x; t < NN; t += 256) {
    int a = ((t >> 8) * CPAD) + (t & 255);       // padded SoA address of point t
    float x = pb[t * 3 + 0];
    float y = pb[t * 3 + 1];
    float z = pb[t * 3 + 2];
    spx[a] = x; spy[a] = y; spz[a] = z;
    ssq[a] = sq3(x, y, z);
  }
  __syncthreads();

  int q = qbase + (threadIdx.x >> 3);
  int c = threadIdx.x & 7;
  int qa = ((q >> 8) * CPAD) + (q & 255);
  float px = spx[qa], py = spy[qa], pz = spz[qa];
  float sqq = ssq[qa];

  int abase = c * CPAD;
  int j0 = c * CHSZ;

  // ---- Pass A: keys-only top-4 of this chunk (strict <, self-excluded) ----
  unsigned int a0 = 0xFFFFFFFFu, a1 = 0xFFFFFFFFu, a2 = 0xFFFFFFFFu, a3 = 0xFFFFFFFFu;
  for (int jj = 0; jj < CHSZ; ++jj) {
    int a = abase + jj;
    int j = j0 + jj;
    float d2 = d2np(px, py, pz, sqq, spx[a], spy[a], spz[a], ssq[a]);
    unsigned int key = f2key(d2);
    if (j == q) key = 0xFFFFFFFFu;
    if (key < a3) {
      bool c3 = key < a2;
      a3 = c3 ? a2 : key;
      bool c2 = key < a1;
      a2 = c3 ? (c2 ? a1 : key) : a2;
      bool c1 = key < a0;
      a1 = c2 ? (c1 ? a0 : key) : a1;
      a0 = c1 ? key : a0;
    }
  }
  sred[threadIdx.x] = a3;
  __syncthreads();
  if (c == 0) {
    unsigned int m = sred[threadIdx.x];
#pragma unroll
    for (int u = 1; u < 8; ++u) {
      unsigned int v = sred[threadIdx.x + u];
      m = v > m ? v : m;
    }
    sred[threadIdx.x] = m;
  }
  __syncthreads();
  unsigned int T = sred[threadIdx.x & ~7];

  // ---- Pass B: gate, buffer, drain through the exact R7 insert ----
  unsigned int ak[KMAX];
  int ai[KMAX];
#pragma unroll
  for (int k = 0; k < KMAX; ++k) { ak[k] = 0xFFFFFFFFu; ai[k] = 0xFFFF; }

  int sbase = threadIdx.x * CAP;
  auto drain = [&](int cnt2) {
    for (int u = 0; u < cnt2; ++u) {
      int jj2 = (int)sbuf[sbase + u];
      int a = abase + jj2;
      int j = j0 + jj2;
      float d2 = d2np(px, py, pz, sqq, spx[a], spy[a], spz[a], ssq[a]);
      unsigned int key = f2key(d2);               // self never buffered
      if (key < ak[KMAX - 1]) {                   // strict: stable ties -> lower j
#pragma unroll
        for (int k = KMAX - 1; k >= 1; --k) {
          bool ck  = key < ak[k];
          bool ckm = key < ak[k - 1];
          unsigned int tk = ckm ? ak[k - 1] : key;
          int          ti = ckm ? ai[k - 1] : j;
          ak[k] = ck ? tk : ak[k];
          ai[k] = ck ? ti : ai[k];
        }
        bool c0b = key < ak[0];
        ak[0] = c0b ? key : ak[0];
        ai[0] = c0b ? j : ai[0];
      }
    }
  };

  int cnt = 0;
  for (int jj = 0; jj < CHSZ; ++jj) {
    int a = abase + jj;
    int j = j0 + jj;
    float d2 = d2np(px, py, pz, sqq, spx[a], spy[a], spz[a], ssq[a]);
    unsigned int key = f2key(d2);
    if (j == q) key = 0xFFFFFFFFu;               // self fails gate (T < max)
    if (key <= T) {
      if (cnt == CAP) { drain(CAP); cnt = 0; }   // rare; preserves j order
      sbuf[sbase + cnt] = (unsigned short)jj;
      ++cnt;
    }
  }
  drain(cnt);

  size_t obase = (((size_t)(b * NN + q)) * CH + c) * KMAX;
  unsigned short* oc = cand + obase;
  unsigned int* ok = candk + obase;
#pragma unroll
  for (int k = 0; k < KMAX; ++k) {
    oc[k] = (unsigned short)ai[k];
    ok[k] = ak[k];
  }
}

// ---------------------------------------------------------------------------
// K1b: KNN phase 2 — 8-way merge of the stable-sorted chunk lists.
// FROZEN: verbatim from the R9 passing kernel.
// ---------------------------------------------------------------------------
__global__ __launch_bounds__(64) void knn_p2(const unsigned int* __restrict__ candk,
                                             const unsigned short* __restrict__ cand,
                                             int* __restrict__ nbr) {
  int q = blockIdx.x * 64 + threadIdx.x;         // global query id (b*NN+n)
  const unsigned int* k8 = candk + (size_t)q * (CH * KMAX);
  const unsigned short* i8 = cand + (size_t)q * (CH * KMAX);

  int head[CH];
  unsigned int hk[CH];
#pragma unroll
  for (int c = 0; c < CH; ++c) {
    head[c] = 0;
    hk[c] = k8[c * KMAX];
  }

  int* onb = nbr + (size_t)q * KMAX;
#pragma unroll
  for (int r = 0; r < KMAX; ++r) {
    int bc = 0;
    unsigned int bk = hk[0];
#pragma unroll
    for (int c = 1; c < CH; ++c) {
      if (hk[c] < bk) { bk = hk[c]; bc = c; }    // strict: ties -> lower c = lower j
    }
    onb[r] = (int)i8[bc * KMAX + head[bc]];
    ++head[bc];
    hk[bc] = (head[bc] < KMAX) ? k8[bc * KMAX + head[bc]] : 0xFFFFFFFFu;
  }
}

// ---------------------------------------------------------------------------
// K2: f32 tiled GEMM  out[M][128] = concat(A1[:,0:K1], A2[:,0:K-K1]) @ W
// NEW tile this round: 128 rows x 128 cols, 8x8 acc/thread (was 64x128, 8x4).
// Per-output k-chain (k ascending, fmac) identical to R9 -> bit-identical
// outputs. blockIdx.z selects among up to 6 weights / output slices.
// ---------------------------------------------------------------------------
__global__ __launch_bounds__(256) void gemm_kernel(
    const float* __restrict__ A1, int lda1, int K1,
    const float* __restrict__ A2, int lda2, int K,
    const float* __restrict__ Wa, const float* __restrict__ Wb,
    const float* __restrict__ Wc, const float* __restrict__ bias,
    float* __restrict__ outbase, int applyLeaky) {
  __shared__ float At[8][128];
  __shared__ float Wt[8][128];

  int z = blockIdx.z;
  const float* W = (z < 2) ? (Wa + (size_t)z * CC * CC)
                 : (z < 4) ? (Wb + (size_t)(z - 2) * CC * CC)
                           : (Wc + (size_t)(z - 4) * CC * CC);
  float* out = outbase + (size_t)z * ((size_t)BB * NN * CC);

  int m0 = blockIdx.x * 128;
  int tid = threadIdx.x;
  int cg = tid & 15;   // col group: cols cg*8 .. cg*8+7
  int rg = tid >> 4;   // row group: rows rg*8 .. rg*8+7

  float acc[8][8];
#pragma unroll
  for (int r = 0; r < 8; ++r)
#pragma unroll
    for (int q = 0; q < 8; ++q) acc[r][q] = 0.f;

  int ksteps = (K + 7) >> 3;
  for (int ks = 0; ks < ksteps; ++ks) {
    int k0 = ks << 3;
    __syncthreads();
    // A tile: 128 rows x 8 k = 1024 elems, 4 per thread (k-consecutive quad)
    {
      int m = tid >> 1;
      int kk = (tid & 1) * 4;
      int gm = m0 + m;
#pragma unroll
      for (int u = 0; u < 4; ++u) {
        int k = k0 + kk + u;
        float v = 0.f;
        if (k < K1) v = A1[(size_t)gm * lda1 + k];
        else if (k < K) v = A2[(size_t)gm * lda2 + (k - K1)];
        At[kk + u][m] = v;
      }
    }
    // W tile: 8 k x 128 cols = 1024 elems, float4 per thread
    {
      int kk = tid >> 5;
      int c = (tid & 31) * 4;
      int k = k0 + kk;
      float4 w = make_float4(0.f, 0.f, 0.f, 0.f);
      if (k < K) w = *(const float4*)(W + (size_t)k * CC + c);
      *(float4*)(&Wt[kk][c]) = w;
    }
    __syncthreads();
#pragma unroll
    for (int kk = 0; kk < 8; ++kk) {
      float4 va0 = *(const float4*)(&At[kk][rg * 8]);
      float4 va1 = *(const float4*)(&At[kk][rg * 8 + 4]);
      float4 vw0 = *(const float4*)(&Wt[kk][cg * 8]);
      float4 vw1 = *(const float4*)(&Wt[kk][cg * 8 + 4]);
      float a[8] = {va0.x, va0.y, va0.z, va0.w, va1.x, va1.y, va1.z, va1.w};
      float w[8] = {vw0.x, vw0.y, vw0.z, vw0.w, vw1.x, vw1.y, vw1.z, vw1.w};
#pragma unroll
      for (int r = 0; r < 8; ++r)
#pragma unroll
        for (int q = 0; q < 8; ++q)
          acc[r][q] += a[r] * w[q];
    }
  }

#pragma unroll
  for (int r = 0; r < 8; ++r) {
    int m = m0 + rg * 8 + r;
#pragma unroll
    for (int qv = 0; qv < 2; ++qv) {
      float4 o;
      float* ov = (float*)&o;
#pragma unroll
      for (int u = 0; u < 4; ++u) {
        int c = cg * 8 + qv * 4 + u;
        float v = acc[r][qv * 4 + u];
        if (bias) v += bias[c];
        if (applyLeaky) v = v > 0.f ? v : NEG * v;
        ov[u] = v;
      }
      *(float4*)(&out[(size_t)m * CC + cg * 8 + qv * 4]) = o;
    }
  }
}

// ---------------------------------------------------------------------------
// K3: fused attention — both dilations in one launch, one h read/write.
// (verbatim from the R9 passing kernel)
// ---------------------------------------------------------------------------
__global__ __launch_bounds__(128) void attn2_kernel(
    const float* __restrict__ pos, const int* __restrict__ nbr,
    const float* __restrict__ s0, const float* __restrict__ v0,
    const float* __restrict__ t0,
    const float* __restrict__ s1, const float* __restrict__ v1,
    const float* __restrict__ t1,
    const float* __restrict__ Wpos, const float* __restrict__ bpos,
    float* __restrict__ h) {
  int bn = blockIdx.x;
  int b = bn >> 11;
  int n = bn & (NN - 1);
  int c = threadIdx.x;

  const float* pb = pos + (size_t)b * NN * 3;
  float pix = pb[n * 3 + 0], piy = pb[n * 3 + 1], piz = pb[n * 3 + 2];
  const int* nb = nbr + (size_t)bn * KMAX;

  float ht = h[(size_t)bn * CC + c];             // h_in (Wg output)

#pragma unroll
  for (int l = 0; l < 2; ++l) {
    int dil = l + 1;
    const float* s = l ? s1 : s0;
    const float* v = l ? v1 : v0;
    const float* t = l ? t1 : t0;
    const float* Wp = Wpos + (size_t)l * 3 * CC;
    float w0 = Wp[c], w1 = Wp[CC + c], w2 = Wp[2 * CC + c];
    float bp = bpos[(size_t)l * CC + c];
    float tc = t[(size_t)bn * CC + c];

    float alpha[17], del[17];
    float mx = -1e30f;
#pragma unroll
    for (int j = 0; j < 17; ++j) {
      int idx = (j < 16) ? nb[j * dil] : n;
      float dx = pix - pb[idx * 3 + 0];
      float dy = piy - pb[idx * 3 + 1];
      float dz = piz - pb[idx * 3 + 2];
      float d = dx * w0 + dy * w1 + dz * w2 + bp;
      del[j] = d;
      float sc = s[((size_t)(b * NN + idx)) * CC + c];
      float a = tc - sc + d;
      alpha[j] = a;
      mx = fmaxf(mx, a);
    }
    float sum = 0.f;
#pragma unroll
    for (int j = 0; j < 17; ++j) {
      float w = expf(alpha[j] - mx);
      alpha[j] = w;
      sum += w;
    }
    float inv = 1.f / sum;
    float hc = 0.f;
#pragma unroll
    for (int j = 0; j < 17; ++j) {
      int idx = (j < 16) ? nb[j * dil] : n;
      float vc = v[((size_t)(b * NN + idx)) * CC + c];
      hc += alpha[j] * (vc + del[j]);
    }
    ht += hc * inv;
  }

  h[(size_t)bn * CC + c] = ht;
}

// ---------------------------------------------------------------------------
// K5: out[m][0..2] = g[m] @ W2 + b2 + pos[m].  One wave per point.
// (verbatim from the R9 passing kernel)
// ---------------------------------------------------------------------------
__global__ __launch_bounds__(64) void final_kernel(
    const float* __restrict__ g, const float* __restrict__ W2,
    const float* __restrict__ b2, const float* __restrict__ pos,
    float* __restrict__ out) {
  int m = blockIdx.x;
  int k = threadIdx.x;
  float g0 = g[(size_t)m * CC + k];
  float g1 = g[(size_t)m * CC + 64 + k];
  float p0 = g0 * W2[k * 3 + 0] + g1 * W2[(k + 64) * 3 + 0];
  float p1 = g0 * W2[k * 3 + 1] + g1 * W2[(k + 64) * 3 + 1];
  float p2 = g0 * W2[k * 3 + 2] + g1 * W2[(k + 64) * 3 + 2];
#pragma unroll
  for (int off = 32; off >= 1; off >>= 1) {
    p0 += __shfl_down(p0, off);
    p1 += __shfl_down(p1, off);
    p2 += __shfl_down(p2, off);
  }
  if (k == 0) {
    out[m * 3 + 0] = p0 + b2[0] + pos[m * 3 + 0];
    out[m * 3 + 1] = p1 + b2[1] + pos[m * 3 + 1];
    out[m * 3 + 2] = p2 + b2[2] + pos[m * 3 + 2];
  }
}

extern "C" void kernel_launch(void* const* d_in, const int* in_sizes, int n_in,
                              void* d_out, int out_size, void* d_ws, size_t ws_size,
                              hipStream_t stream) {
  const float* x     = (const float*)d_in[0];
  const float* pos   = (const float*)d_in[1];
  const float* W_lin = (const float*)d_in[2];
  const float* W_src = (const float*)d_in[3];
  const float* W_dst = (const float*)d_in[4];
  const float* W_pos = (const float*)d_in[5];
  const float* b_pos = (const float*)d_in[6];
  const float* Wg    = (const float*)d_in[7];
  const float* bg    = (const float*)d_in[8];
  const float* W1    = (const float*)d_in[9];
  const float* b1    = (const float*)d_in[10];
  const float* W2    = (const float*)d_in[11];
  const float* b2    = (const float*)d_in[12];
  float* out = (float*)d_out;

  const size_t M = (size_t)BB * NN;        // 16384
  const size_t MC = M * CC;                // 2,097,152 floats

  // R9 workspace layout, verbatim.
  char* ws = (char*)d_ws;
  int* nbr = (int*)ws;                               // M*KMAX ints   = 2 MB
  unsigned short* cand = (unsigned short*)(ws + M * KMAX * sizeof(int));  // 8.4 MB
  float* fb = (float*)(ws + M * KMAX * sizeof(int) + M * CH * KMAX * sizeof(unsigned short));
  float* sb0 = fb + 0 * MC;
  float* sb1 = fb + 1 * MC;
  float* vb0 = fb + 2 * MC;
  float* vb1 = fb + 3 * MC;
  float* tb0 = fb + 4 * MC;
  float* tb1 = fb + 5 * MC;
  float* h   = fb + 6 * MC;
  float* g   = fb + 7 * MC;
  // candk (u32, M*CH*KMAX = 16.78 MB) aliases h+g (exactly 2*MC floats):
  // dead before the Wg GEMM writes h (stream-ordered after knn_p2).
  unsigned int* candk = (unsigned int*)h;

  // 1. KNN: gated chunk selection, then 8-way sorted merge (frozen R9)
  knn_p1<<<512, 256, 0, stream>>>(pos, cand, candk);
  knn_p2<<<256, 64, 0, stream>>>(candk, cand, nbr);

  // 2. six projections fused in ONE launch (z: sb0,sb1,vb0,vb1,tb0,tb1)
  gemm_kernel<<<dim3(M / 128, 1, 6), 256, 0, stream>>>(
      x, CC, CC, nullptr, 0, CC, W_src, W_lin, W_dst, nullptr, fb, 0);

  // 3. h = leaky(concat(x,pos) @ Wg + bg)
  gemm_kernel<<<dim3(M / 128, 1, 1), 256, 0, stream>>>(
      x, CC, CC, pos, 3, CC + 3, Wg, nullptr, nullptr, bg, h, 1);

  // 4. h += attention, both dilations fused
  attn2_kernel<<<M, 128, 0, stream>>>(pos, nbr, sb0, vb0, tb0,
                                      sb1, vb1, tb1, W_pos, b_pos, h);

  // 5. g = leaky(h @ W1 + b1)
  gemm_kernel<<<dim3(M / 128, 1, 1), 256, 0, stream>>>(
      h, CC, CC, nullptr, 0, CC, W1, nullptr, nullptr, b1, g, 1);

  // 6. out = g @ W2 + b2 + pos
  final_kernel<<<M, 64, 0, stream>>>(g, W2, b2, pos, out);
}

// Round 12
// 360.504 us; speedup vs baseline: 1.3493x; 1.0689x over previous
//
#include <hip/hip_runtime.h>

#define BB 8
#define NN 2048
#define CC 128
#define KMAX 32
#define NEG 0.2f
#define CH 8
#define CHSZ (NN / CH)   // 256
#define CPAD4 257        // float4 stride/chunk: (c*257*4)%32 = 4c -> each lane's b128 covers 4 banks, 8 lanes cover all 32 exactly once
#define CAP 32           // per-thread candidate buffer (drain-on-full keeps j order)

// Map f32 to a u32 whose unsigned order == float order (handles negatives).
__device__ __forceinline__ unsigned int f2key(float f) {
  unsigned int b = __float_as_uint(f);
  return (b & 0x80000000u) ? ~b : (b | 0x80000000u);
}

// np-exact f32 squared norm: fl(fl(x^2+y^2)+z^2), no FMA contraction.
__device__ __forceinline__ float sq3(float x, float y, float z) {
  return __fadd_rn(__fadd_rn(__fmul_rn(x, x), __fmul_rn(y, y)), __fmul_rn(z, z));
}

// np-exact f32 distance key: d2 = fl( fl(sq_i+sq_j) - fl(2*dot) ),
// dot = fma(a2,b2, fma(a1,b1, round(a0*b0)))  (BLAS K-ascending FMA chain).
__device__ __forceinline__ float d2np(float px, float py, float pz, float sqq,
                                      float qx, float qy, float qz, float sqj) {
  float dot = __fmaf_rn(pz, qz, __fmaf_rn(py, qy, __fmul_rn(px, qx)));
  return __fsub_rn(__fadd_rn(sqq, sqj), __fmul_rn(2.0f, dot));
}

// ---------------------------------------------------------------------------
// K1a: KNN phase 1 — threshold-gated chunked selection, np-bit-exact keys.
// Selection semantics FROZEN (R9): CH=8, top-4 gate, j-order drain, stable
// insert. This round changes ONLY memory layout (R6->R7-class change):
// positions packed as one float4 LDS array (1 ds_read_b128 per candidate
// instead of 4 ds_read_b32), u8 sbuf, unroll-4 scan loops for MLP.
// Block = 256 threads = 32 queries x 8 chunks of one batch. Grid = 512.
// ---------------------------------------------------------------------------
__global__ __launch_bounds__(256) void knn_p1(const float* __restrict__ pos,
                                              unsigned short* __restrict__ cand,
                                              unsigned int* __restrict__ candk) {
  __shared__ float4 sp4[CH * CPAD4];             // 32.9 KB
  __shared__ unsigned int sred[256];             // 1 KB
  __shared__ unsigned char sbuf[256 * CAP];      // 8 KB
  int b = blockIdx.x >> 6;                       // 64 blocks per batch
  int qbase = (blockIdx.x & 63) * 32;
  const float* pb = pos + (size_t)b * NN * 3;
  for (int t = threadIdx.x; t < NN; t += 256) {
    int a = ((t >> 8) * CPAD4) + (t & 255);      // padded float4 address of point t
    float x = pb[t * 3 + 0];
    float y = pb[t * 3 + 1];
    float z = pb[t * 3 + 2];
    sp4[a] = make_float4(x, y, z, sq3(x, y, z)); // same values as R9
  }
  __syncthreads();

  int q = qbase + (threadIdx.x >> 3);
  int c = threadIdx.x & 7;
  int qa = ((q >> 8) * CPAD4) + (q & 255);
  float4 pq = sp4[qa];
  float px = pq.x, py = pq.y, pz = pq.z, sqq = pq.w;

  int abase = c * CPAD4;
  int j0 = c * CHSZ;

  // ---- Pass A: keys-only top-4 of this chunk (strict <, self-excluded) ----
  unsigned int a0 = 0xFFFFFFFFu, a1 = 0xFFFFFFFFu, a2 = 0xFFFFFFFFu, a3 = 0xFFFFFFFFu;
#pragma unroll 4
  for (int jj = 0; jj < CHSZ; ++jj) {
    int j = j0 + jj;
    float4 pj = sp4[abase + jj];
    float d2 = d2np(px, py, pz, sqq, pj.x, pj.y, pj.z, pj.w);
    unsigned int key = f2key(d2);
    if (j == q) key = 0xFFFFFFFFu;
    if (key < a3) {
      bool c3 = key < a2;
      a3 = c3 ? a2 : key;
      bool c2 = key < a1;
      a2 = c3 ? (c2 ? a1 : key) : a2;
      bool c1 = key < a0;
      a1 = c2 ? (c1 ? a0 : key) : a1;
      a0 = c1 ? key : a0;
    }
  }
  sred[threadIdx.x] = a3;
  __syncthreads();
  if (c == 0) {
    unsigned int m = sred[threadIdx.x];
#pragma unroll
    for (int u = 1; u < 8; ++u) {
      unsigned int v = sred[threadIdx.x + u];
      m = v > m ? v : m;
    }
    sred[threadIdx.x] = m;
  }
  __syncthreads();
  unsigned int T = sred[threadIdx.x & ~7];

  // ---- Pass B: gate, buffer, drain through the exact R9 insert ----
  unsigned int ak[KMAX];
  int ai[KMAX];
#pragma unroll
  for (int k = 0; k < KMAX; ++k) { ak[k] = 0xFFFFFFFFu; ai[k] = 0xFFFF; }

  int sbase = threadIdx.x * CAP;
  auto drain = [&](int cnt2) {
    for (int u = 0; u < cnt2; ++u) {
      int jj2 = (int)sbuf[sbase + u];
      int j = j0 + jj2;
      float4 pj = sp4[abase + jj2];
      float d2 = d2np(px, py, pz, sqq, pj.x, pj.y, pj.z, pj.w);
      unsigned int key = f2key(d2);               // self never buffered
      if (key < ak[KMAX - 1]) {                   // strict: stable ties -> lower j
#pragma unroll
        for (int k = KMAX - 1; k >= 1; --k) {
          bool ck  = key < ak[k];
          bool ckm = key < ak[k - 1];
          unsigned int tk = ckm ? ak[k - 1] : key;
          int          ti = ckm ? ai[k - 1] : j;
          ak[k] = ck ? tk : ak[k];
          ai[k] = ck ? ti : ai[k];
        }
        bool c0b = key < ak[0];
        ak[0] = c0b ? key : ak[0];
        ai[0] = c0b ? j : ai[0];
      }
    }
  };

  int cnt = 0;
#pragma unroll 4
  for (int jj = 0; jj < CHSZ; ++jj) {
    int j = j0 + jj;
    float4 pj = sp4[abase + jj];
    float d2 = d2np(px, py, pz, sqq, pj.x, pj.y, pj.z, pj.w);
    unsigned int key = f2key(d2);
    if (j == q) key = 0xFFFFFFFFu;               // self fails gate (T < max)
    if (key <= T) {
      if (cnt == CAP) { drain(CAP); cnt = 0; }   // rare; preserves j order
      sbuf[sbase + cnt] = (unsigned char)jj;     // jj < 256 fits u8
      ++cnt;
    }
  }
  drain(cnt);

  size_t obase = (((size_t)(b * NN + q)) * CH + c) * KMAX;
  unsigned short* oc = cand + obase;
  unsigned int* ok = candk + obase;
#pragma unroll
  for (int k = 0; k < KMAX; ++k) {
    oc[k] = (unsigned short)ai[k];
    ok[k] = ak[k];
  }
}

// ---------------------------------------------------------------------------
// K1b: KNN phase 2 — 8-way merge of the stable-sorted chunk lists.
// FROZEN: verbatim from the R9 passing kernel.
// ---------------------------------------------------------------------------
__global__ __launch_bounds__(64) void knn_p2(const unsigned int* __restrict__ candk,
                                             const unsigned short* __restrict__ cand,
                                             int* __restrict__ nbr) {
  int q = blockIdx.x * 64 + threadIdx.x;         // global query id (b*NN+n)
  const unsigned int* k8 = candk + (size_t)q * (CH * KMAX);
  const unsigned short* i8 = cand + (size_t)q * (CH * KMAX);

  int head[CH];
  unsigned int hk[CH];
#pragma unroll
  for (int c = 0; c < CH; ++c) {
    head[c] = 0;
    hk[c] = k8[c * KMAX];
  }

  int* onb = nbr + (size_t)q * KMAX;
#pragma unroll
  for (int r = 0; r < KMAX; ++r) {
    int bc = 0;
    unsigned int bk = hk[0];
#pragma unroll
    for (int c = 1; c < CH; ++c) {
      if (hk[c] < bk) { bk = hk[c]; bc = c; }    // strict: ties -> lower c = lower j
    }
    onb[r] = (int)i8[bc * KMAX + head[bc]];
    ++head[bc];
    hk[bc] = (head[bc] < KMAX) ? k8[bc * KMAX + head[bc]] : 0xFFFFFFFFu;
  }
}

// ---------------------------------------------------------------------------
// K2: f32 tiled GEMM  out[M][128] = concat(A1[:,0:K1], A2[:,0:K-K1]) @ W
// REVERTED to the R9-proven 64x128 tile (the R11 128x128 tile regressed).
// blockIdx.z selects among up to 6 weight matrices and output slices.
// ---------------------------------------------------------------------------
__global__ __launch_bounds__(256) void gemm_kernel(
    const float* __restrict__ A1, int lda1, int K1,
    const float* __restrict__ A2, int lda2, int K,
    const float* __restrict__ Wa, const float* __restrict__ Wb,
    const float* __restrict__ Wc, const float* __restrict__ bias,
    float* __restrict__ outbase, int applyLeaky) {
  __shared__ float At[8][64];
  __shared__ float Wt[8][CC];

  int z = blockIdx.z;
  const float* W = (z < 2) ? (Wa + (size_t)z * CC * CC)
                 : (z < 4) ? (Wb + (size_t)(z - 2) * CC * CC)
                           : (Wc + (size_t)(z - 4) * CC * CC);
  float* out = outbase + (size_t)z * ((size_t)BB * NN * CC);

  int m0 = blockIdx.x * 64;
  int tid = threadIdx.x;
  int cg = tid & 31;
  int rg = tid >> 5;

  float acc[8][4];
#pragma unroll
  for (int r = 0; r < 8; ++r)
#pragma unroll
    for (int q = 0; q < 4; ++q) acc[r][q] = 0.f;

  int ksteps = (K + 7) >> 3;
  for (int ks = 0; ks < ksteps; ++ks) {
    int k0 = ks << 3;
    __syncthreads();
    {
      int f = tid * 2;
      int m = f >> 3;
      int kk = f & 7;
      int gm = m0 + m;
#pragma unroll
      for (int u = 0; u < 2; ++u) {
        int k = k0 + kk + u;
        float v = 0.f;
        if (k < K1) v = A1[(size_t)gm * lda1 + k];
        else if (k < K) v = A2[(size_t)gm * lda2 + (k - K1)];
        At[kk + u][m] = v;
      }
    }
    {
      int kk = tid >> 5;
      int c = (tid & 31) * 4;
      int k = k0 + kk;
      float4 w = make_float4(0.f, 0.f, 0.f, 0.f);
      if (k < K) w = *(const float4*)(W + (size_t)k * CC + c);
      *(float4*)(&Wt[kk][c]) = w;
    }
    __syncthreads();
#pragma unroll
    for (int kk = 0; kk < 8; ++kk) {
      float4 a0 = *(const float4*)(&At[kk][rg * 8]);
      float4 a1 = *(const float4*)(&At[kk][rg * 8 + 4]);
      float4 w = *(const float4*)(&Wt[kk][cg * 4]);
      float a[8] = {a0.x, a0.y, a0.z, a0.w, a1.x, a1.y, a1.z, a1.w};
#pragma unroll
      for (int r = 0; r < 8; ++r) {
        acc[r][0] += a[r] * w.x;
        acc[r][1] += a[r] * w.y;
        acc[r][2] += a[r] * w.z;
        acc[r][3] += a[r] * w.w;
      }
    }
  }

#pragma unroll
  for (int r = 0; r < 8; ++r) {
    int m = m0 + rg * 8 + r;
#pragma unroll
    for (int q = 0; q < 4; ++q) {
      int c = cg * 4 + q;
      float v = acc[r][q];
      if (bias) v += bias[c];
      if (applyLeaky) v = v > 0.f ? v : NEG * v;
      out[(size_t)m * CC + c] = v;
    }
  }
}

// ---------------------------------------------------------------------------
// K3: fused attention — both dilations in one launch, one h read/write.
// (verbatim from the R9 passing kernel)
// ---------------------------------------------------------------------------
__global__ __launch_bounds__(128) void attn2_kernel(
    const float* __restrict__ pos, const int* __restrict__ nbr,
    const float* __restrict__ s0, const float* __restrict__ v0,
    const float* __restrict__ t0,
    const float* __restrict__ s1, const float* __restrict__ v1,
    const float* __restrict__ t1,
    const float* __restrict__ Wpos, const float* __restrict__ bpos,
    float* __restrict__ h) {
  int bn = blockIdx.x;
  int b = bn >> 11;
  int n = bn & (NN - 1);
  int c = threadIdx.x;

  const float* pb = pos + (size_t)b * NN * 3;
  float pix = pb[n * 3 + 0], piy = pb[n * 3 + 1], piz = pb[n * 3 + 2];
  const int* nb = nbr + (size_t)bn * KMAX;

  float ht = h[(size_t)bn * CC + c];             // h_in (Wg output)

#pragma unroll
  for (int l = 0; l < 2; ++l) {
    int dil = l + 1;
    const float* s = l ? s1 : s0;
    const float* v = l ? v1 : v0;
    const float* t = l ? t1 : t0;
    const float* Wp = Wpos + (size_t)l * 3 * CC;
    float w0 = Wp[c], w1 = Wp[CC + c], w2 = Wp[2 * CC + c];
    float bp = bpos[(size_t)l * CC + c];
    float tc = t[(size_t)bn * CC + c];

    float alpha[17], del[17];
    float mx = -1e30f;
#pragma unroll
    for (int j = 0; j < 17; ++j) {
      int idx = (j < 16) ? nb[j * dil] : n;
      float dx = pix - pb[idx * 3 + 0];
      float dy = piy - pb[idx * 3 + 1];
      float dz = piz - pb[idx * 3 + 2];
      float d = dx * w0 + dy * w1 + dz * w2 + bp;
      del[j] = d;
      float sc = s[((size_t)(b * NN + idx)) * CC + c];
      float a = tc - sc + d;
      alpha[j] = a;
      mx = fmaxf(mx, a);
    }
    float sum = 0.f;
#pragma unroll
    for (int j = 0; j < 17; ++j) {
      float w = expf(alpha[j] - mx);
      alpha[j] = w;
      sum += w;
    }
    float inv = 1.f / sum;
    float hc = 0.f;
#pragma unroll
    for (int j = 0; j < 17; ++j) {
      int idx = (j < 16) ? nb[j * dil] : n;
      float vc = v[((size_t)(b * NN + idx)) * CC + c];
      hc += alpha[j] * (vc + del[j]);
    }
    ht += hc * inv;
  }

  h[(size_t)bn * CC + c] = ht;
}

// ---------------------------------------------------------------------------
// K5: out[m][0..2] = g[m] @ W2 + b2 + pos[m].  One wave per point.
// (verbatim from the R9 passing kernel)
// ---------------------------------------------------------------------------
__global__ __launch_bounds__(64) void final_kernel(
    const float* __restrict__ g, const float* __restrict__ W2,
    const float* __restrict__ b2, const float* __restrict__ pos,
    float* __restrict__ out) {
  int m = blockIdx.x;
  int k = threadIdx.x;
  float g0 = g[(size_t)m * CC + k];
  float g1 = g[(size_t)m * CC + 64 + k];
  float p0 = g0 * W2[k * 3 + 0] + g1 * W2[(k + 64) * 3 + 0];
  float p1 = g0 * W2[k * 3 + 1] + g1 * W2[(k + 64) * 3 + 1];
  float p2 = g0 * W2[k * 3 + 2] + g1 * W2[(k + 64) * 3 + 2];
#pragma unroll
  for (int off = 32; off >= 1; off >>= 1) {
    p0 += __shfl_down(p0, off);
    p1 += __shfl_down(p1, off);
    p2 += __shfl_down(p2, off);
  }
  if (k == 0) {
    out[m * 3 + 0] = p0 + b2[0] + pos[m * 3 + 0];
    out[m * 3 + 1] = p1 + b2[1] + pos[m * 3 + 1];
    out[m * 3 + 2] = p2 + b2[2] + pos[m * 3 + 2];
  }
}

extern "C" void kernel_launch(void* const* d_in, const int* in_sizes, int n_in,
                              void* d_out, int out_size, void* d_ws, size_t ws_size,
                              hipStream_t stream) {
  const float* x     = (const float*)d_in[0];
  const float* pos   = (const float*)d_in[1];
  const float* W_lin = (const float*)d_in[2];
  const float* W_src = (const float*)d_in[3];
  const float* W_dst = (const float*)d_in[4];
  const float* W_pos = (const float*)d_in[5];
  const float* b_pos = (const float*)d_in[6];
  const float* Wg    = (const float*)d_in[7];
  const float* bg    = (const float*)d_in[8];
  const float* W1    = (const float*)d_in[9];
  const float* b1    = (const float*)d_in[10];
  const float* W2    = (const float*)d_in[11];
  const float* b2    = (const float*)d_in[12];
  float* out = (float*)d_out;

  const size_t M = (size_t)BB * NN;        // 16384
  const size_t MC = M * CC;                // 2,097,152 floats

  // R9 workspace layout, verbatim.
  char* ws = (char*)d_ws;
  int* nbr = (int*)ws;                               // M*KMAX ints   = 2 MB
  unsigned short* cand = (unsigned short*)(ws + M * KMAX * sizeof(int));  // 8.4 MB
  float* fb = (float*)(ws + M * KMAX * sizeof(int) + M * CH * KMAX * sizeof(unsigned short));
  float* sb0 = fb + 0 * MC;
  float* sb1 = fb + 1 * MC;
  float* vb0 = fb + 2 * MC;
  float* vb1 = fb + 3 * MC;
  float* tb0 = fb + 4 * MC;
  float* tb1 = fb + 5 * MC;
  float* h   = fb + 6 * MC;
  float* g   = fb + 7 * MC;
  // candk (u32, M*CH*KMAX = 16.78 MB) aliases h+g (exactly 2*MC floats):
  // dead before the Wg GEMM writes h (stream-ordered after knn_p2).
  unsigned int* candk = (unsigned int*)h;

  // 1. KNN: gated chunk selection, then 8-way sorted merge (frozen semantics)
  knn_p1<<<512, 256, 0, stream>>>(pos, cand, candk);
  knn_p2<<<256, 64, 0, stream>>>(candk, cand, nbr);

  // 2. six projections fused in ONE launch (z: sb0,sb1,vb0,vb1,tb0,tb1)
  gemm_kernel<<<dim3(M / 64, 1, 6), 256, 0, stream>>>(
      x, CC, CC, nullptr, 0, CC, W_src, W_lin, W_dst, nullptr, fb, 0);

  // 3. h = leaky(concat(x,pos) @ Wg + bg)
  gemm_kernel<<<dim3(M / 64, 1, 1), 256, 0, stream>>>(
      x, CC, CC, pos, 3, CC + 3, Wg, nullptr, nullptr, bg, h, 1);

  // 4. h += attention, both dilations fused
  attn2_kernel<<<M, 128, 0, stream>>>(pos, nbr, sb0, vb0, tb0,
                                      sb1, vb1, tb1, W_pos, b_pos, h);

  // 5. g = leaky(h @ W1 + b1)
  gemm_kernel<<<dim3(M / 64, 1, 1), 256, 0, stream>>>(
      h, CC, CC, nullptr, 0, CC, W1, nullptr, nullptr, b1, g, 1);

  // 6. out = g @ W2 + b2 + pos
  final_kernel<<<M, 64, 0, stream>>>(g, W2, b2, pos, out);
}

// Round 13
// 355.586 us; speedup vs baseline: 1.3679x; 1.0138x over previous
//
#include <hip/hip_runtime.h>

#define BB 8
#define NN 2048
#define CC 128
#define KMAX 32
#define NEG 0.2f
#define CH 8
#define CHSZ (NN / CH)   // 256
#define CPAD 260         // chunk stride in LDS: (260*c+jj)%32 = (4c+jj)%32 -> 8 distinct banks
#define CAP 32           // per-thread candidate buffer (drain-on-full keeps j order)

// Map f32 to a u32 whose unsigned order == float order (handles negatives).
__device__ __forceinline__ unsigned int f2key(float f) {
  unsigned int b = __float_as_uint(f);
  return (b & 0x80000000u) ? ~b : (b | 0x80000000u);
}

// np-exact f32 squared norm: fl(fl(x^2+y^2)+z^2), no FMA contraction.
__device__ __forceinline__ float sq3(float x, float y, float z) {
  return __fadd_rn(__fadd_rn(__fmul_rn(x, x), __fmul_rn(y, y)), __fmul_rn(z, z));
}

// np-exact f32 distance key: d2 = fl( fl(sq_i+sq_j) - fl(2*dot) ),
// dot = fma(a2,b2, fma(a1,b1, round(a0*b0)))  (BLAS K-ascending FMA chain).
__device__ __forceinline__ float d2np(float px, float py, float pz, float sqq,
                                      float qx, float qy, float qz, float sqj) {
  float dot = __fmaf_rn(pz, qz, __fmaf_rn(py, qy, __fmul_rn(px, qx)));
  return __fsub_rn(__fadd_rn(sqq, sqj), __fmul_rn(2.0f, dot));
}

// ---------------------------------------------------------------------------
// K1a: KNN phase 1 — threshold-gated chunked selection, np-bit-exact keys.
// FROZEN: byte-for-byte the R9/R11 passing version (absmax 0.00195). Four
// "provably equivalent" rewrites (R4/R5/R10/R12) changed selection; only
// these bytes are trusted. Do not touch.
// Block = 256 threads = 32 queries x 8 chunks of one batch. Grid = 512.
// ---------------------------------------------------------------------------
__global__ __launch_bounds__(256) void knn_p1(const float* __restrict__ pos,
                                              unsigned short* __restrict__ cand,
                                              unsigned int* __restrict__ candk) {
  __shared__ float spx[CH * CPAD], spy[CH * CPAD], spz[CH * CPAD], ssq[CH * CPAD];
  __shared__ unsigned int sred[256];
  __shared__ unsigned short sbuf[256 * CAP];
  int b = blockIdx.x >> 6;                       // 64 blocks per batch
  int qbase = (blockIdx.x & 63) * 32;
  const float* pb = pos + (size_t)b * NN * 3;
  for (int t = threadIdx.x; t < NN; t += 256) {
    int a = ((t >> 8) * CPAD) + (t & 255);       // padded SoA address of point t
    float x = pb[t * 3 + 0];
    float y = pb[t * 3 + 1];
    float z = pb[t * 3 + 2];
    spx[a] = x; spy[a] = y; spz[a] = z;
    ssq[a] = sq3(x, y, z);
  }
  __syncthreads();

  int q = qbase + (threadIdx.x >> 3);
  int c = threadIdx.x & 7;
  int qa = ((q >> 8) * CPAD) + (q & 255);
  float px = spx[qa], py = spy[qa], pz = spz[qa];
  float sqq = ssq[qa];

  int abase = c * CPAD;
  int j0 = c * CHSZ;

  // ---- Pass A: keys-only top-4 of this chunk (strict <, self-excluded) ----
  unsigned int a0 = 0xFFFFFFFFu, a1 = 0xFFFFFFFFu, a2 = 0xFFFFFFFFu, a3 = 0xFFFFFFFFu;
  for (int jj = 0; jj < CHSZ; ++jj) {
    int a = abase + jj;
    int j = j0 + jj;
    float d2 = d2np(px, py, pz, sqq, spx[a], spy[a], spz[a], ssq[a]);
    unsigned int key = f2key(d2);
    if (j == q) key = 0xFFFFFFFFu;
    if (key < a3) {
      bool c3 = key < a2;
      a3 = c3 ? a2 : key;
      bool c2 = key < a1;
      a2 = c3 ? (c2 ? a1 : key) : a2;
      bool c1 = key < a0;
      a1 = c2 ? (c1 ? a0 : key) : a1;
      a0 = c1 ? key : a0;
    }
  }
  sred[threadIdx.x] = a3;
  __syncthreads();
  if (c == 0) {
    unsigned int m = sred[threadIdx.x];
#pragma unroll
    for (int u = 1; u < 8; ++u) {
      unsigned int v = sred[threadIdx.x + u];
      m = v > m ? v : m;
    }
    sred[threadIdx.x] = m;
  }
  __syncthreads();
  unsigned int T = sred[threadIdx.x & ~7];

  // ---- Pass B: gate, buffer, drain through the exact R7 insert ----
  unsigned int ak[KMAX];
  int ai[KMAX];
#pragma unroll
  for (int k = 0; k < KMAX; ++k) { ak[k] = 0xFFFFFFFFu; ai[k] = 0xFFFF; }

  int sbase = threadIdx.x * CAP;
  auto drain = [&](int cnt2) {
    for (int u = 0; u < cnt2; ++u) {
      int jj2 = (int)sbuf[sbase + u];
      int a = abase + jj2;
      int j = j0 + jj2;
      float d2 = d2np(px, py, pz, sqq, spx[a], spy[a], spz[a], ssq[a]);
      unsigned int key = f2key(d2);               // self never buffered
      if (key < ak[KMAX - 1]) {                   // strict: stable ties -> lower j
#pragma unroll
        for (int k = KMAX - 1; k >= 1; --k) {
          bool ck  = key < ak[k];
          bool ckm = key < ak[k - 1];
          unsigned int tk = ckm ? ak[k - 1] : key;
          int          ti = ckm ? ai[k - 1] : j;
          ak[k] = ck ? tk : ak[k];
          ai[k] = ck ? ti : ai[k];
        }
        bool c0b = key < ak[0];
        ak[0] = c0b ? key : ak[0];
        ai[0] = c0b ? j : ai[0];
      }
    }
  };

  int cnt = 0;
  for (int jj = 0; jj < CHSZ; ++jj) {
    int a = abase + jj;
    int j = j0 + jj;
    float d2 = d2np(px, py, pz, sqq, spx[a], spy[a], spz[a], ssq[a]);
    unsigned int key = f2key(d2);
    if (j == q) key = 0xFFFFFFFFu;               // self fails gate (T < max)
    if (key <= T) {
      if (cnt == CAP) { drain(CAP); cnt = 0; }   // rare; preserves j order
      sbuf[sbase + cnt] = (unsigned short)jj;
      ++cnt;
    }
  }
  drain(cnt);

  size_t obase = (((size_t)(b * NN + q)) * CH + c) * KMAX;
  unsigned short* oc = cand + obase;
  unsigned int* ok = candk + obase;
#pragma unroll
  for (int k = 0; k < KMAX; ++k) {
    oc[k] = (unsigned short)ai[k];
    ok[k] = ak[k];
  }
}

// ---------------------------------------------------------------------------
// K1b: KNN phase 2 — 8-way merge of the stable-sorted chunk lists.
// FROZEN: verbatim from the R9 passing kernel.
// ---------------------------------------------------------------------------
__global__ __launch_bounds__(64) void knn_p2(const unsigned int* __restrict__ candk,
                                             const unsigned short* __restrict__ cand,
                                             int* __restrict__ nbr) {
  int q = blockIdx.x * 64 + threadIdx.x;         // global query id (b*NN+n)
  const unsigned int* k8 = candk + (size_t)q * (CH * KMAX);
  const unsigned short* i8 = cand + (size_t)q * (CH * KMAX);

  int head[CH];
  unsigned int hk[CH];
#pragma unroll
  for (int c = 0; c < CH; ++c) {
    head[c] = 0;
    hk[c] = k8[c * KMAX];
  }

  int* onb = nbr + (size_t)q * KMAX;
#pragma unroll
  for (int r = 0; r < KMAX; ++r) {
    int bc = 0;
    unsigned int bk = hk[0];
#pragma unroll
    for (int c = 1; c < CH; ++c) {
      if (hk[c] < bk) { bk = hk[c]; bc = c; }    // strict: ties -> lower c = lower j
    }
    onb[r] = (int)i8[bc * KMAX + head[bc]];
    ++head[bc];
    hk[bc] = (head[bc] < KMAX) ? k8[bc * KMAX + head[bc]] : 0xFFFFFFFFu;
  }
}

// ---------------------------------------------------------------------------
// K2: f32 tiled GEMM  out[M][128] = concat(A1[:,0:K1], A2[:,0:K-K1]) @ W
// R9-proven 64x128 tile. blockIdx.z selects weight / output slice.
// ---------------------------------------------------------------------------
__global__ __launch_bounds__(256) void gemm_kernel(
    const float* __restrict__ A1, int lda1, int K1,
    const float* __restrict__ A2, int lda2, int K,
    const float* __restrict__ Wa, const float* __restrict__ Wb,
    const float* __restrict__ Wc, const float* __restrict__ bias,
    float* __restrict__ outbase, int applyLeaky) {
  __shared__ float At[8][64];
  __shared__ float Wt[8][CC];

  int z = blockIdx.z;
  const float* W = (z < 2) ? (Wa + (size_t)z * CC * CC)
                 : (z < 4) ? (Wb + (size_t)(z - 2) * CC * CC)
                           : (Wc + (size_t)(z - 4) * CC * CC);
  float* out = outbase + (size_t)z * ((size_t)BB * NN * CC);

  int m0 = blockIdx.x * 64;
  int tid = threadIdx.x;
  int cg = tid & 31;
  int rg = tid >> 5;

  float acc[8][4];
#pragma unroll
  for (int r = 0; r < 8; ++r)
#pragma unroll
    for (int q = 0; q < 4; ++q) acc[r][q] = 0.f;

  int ksteps = (K + 7) >> 3;
  for (int ks = 0; ks < ksteps; ++ks) {
    int k0 = ks << 3;
    __syncthreads();
    {
      int f = tid * 2;
      int m = f >> 3;
      int kk = f & 7;
      int gm = m0 + m;
#pragma unroll
      for (int u = 0; u < 2; ++u) {
        int k = k0 + kk + u;
        float v = 0.f;
        if (k < K1) v = A1[(size_t)gm * lda1 + k];
        else if (k < K) v = A2[(size_t)gm * lda2 + (k - K1)];
        At[kk + u][m] = v;
      }
    }
    {
      int kk = tid >> 5;
      int c = (tid & 31) * 4;
      int k = k0 + kk;
      float4 w = make_float4(0.f, 0.f, 0.f, 0.f);
      if (k < K) w = *(const float4*)(W + (size_t)k * CC + c);
      *(float4*)(&Wt[kk][c]) = w;
    }
    __syncthreads();
#pragma unroll
    for (int kk = 0; kk < 8; ++kk) {
      float4 a0 = *(const float4*)(&At[kk][rg * 8]);
      float4 a1 = *(const float4*)(&At[kk][rg * 8 + 4]);
      float4 w = *(const float4*)(&Wt[kk][cg * 4]);
      float a[8] = {a0.x, a0.y, a0.z, a0.w, a1.x, a1.y, a1.z, a1.w};
#pragma unroll
      for (int r = 0; r < 8; ++r) {
        acc[r][0] += a[r] * w.x;
        acc[r][1] += a[r] * w.y;
        acc[r][2] += a[r] * w.z;
        acc[r][3] += a[r] * w.w;
      }
    }
  }

#pragma unroll
  for (int r = 0; r < 8; ++r) {
    int m = m0 + rg * 8 + r;
#pragma unroll
    for (int q = 0; q < 4; ++q) {
      int c = cg * 4 + q;
      float v = acc[r][q];
      if (bias) v += bias[c];
      if (applyLeaky) v = v > 0.f ? v : NEG * v;
      out[(size_t)m * CC + c] = v;
    }
  }
}

// ---------------------------------------------------------------------------
// K3: fused attention — both dilations in one launch, one h read/write.
// NEW this round: batch-locality block swizzle (b = blockIdx & 7) so blocks
// congruent mod 8 share a batch -> under round-robin XCD dispatch each XCD's
// L2 sees mostly one batch's s/v/t windows (6 MB) instead of all 48 MB.
// Pure work permutation: per-point arithmetic chain unchanged.
// ---------------------------------------------------------------------------
__global__ __launch_bounds__(128) void attn2_kernel(
    const float* __restrict__ pos, const int* __restrict__ nbr,
    const float* __restrict__ s0, const float* __restrict__ v0,
    const float* __restrict__ t0,
    const float* __restrict__ s1, const float* __restrict__ v1,
    const float* __restrict__ t1,
    const float* __restrict__ Wpos, const float* __restrict__ bpos,
    float* __restrict__ h) {
  int b = blockIdx.x & 7;                        // XCD-locality swizzle
  int n = blockIdx.x >> 3;
  int bn = (b << 11) + n;
  int c = threadIdx.x;

  const float* pb = pos + (size_t)b * NN * 3;
  float pix = pb[n * 3 + 0], piy = pb[n * 3 + 1], piz = pb[n * 3 + 2];
  const int* nb = nbr + (size_t)bn * KMAX;

  float ht = h[(size_t)bn * CC + c];             // h_in (Wg output)

#pragma unroll
  for (int l = 0; l < 2; ++l) {
    int dil = l + 1;
    const float* s = l ? s1 : s0;
    const float* v = l ? v1 : v0;
    const float* t = l ? t1 : t0;
    const float* Wp = Wpos + (size_t)l * 3 * CC;
    float w0 = Wp[c], w1 = Wp[CC + c], w2 = Wp[2 * CC + c];
    float bp = bpos[(size_t)l * CC + c];
    float tc = t[(size_t)bn * CC + c];

    float alpha[17], del[17];
    float mx = -1e30f;
#pragma unroll
    for (int j = 0; j < 17; ++j) {
      int idx = (j < 16) ? nb[j * dil] : n;
      float dx = pix - pb[idx * 3 + 0];
      float dy = piy - pb[idx * 3 + 1];
      float dz = piz - pb[idx * 3 + 2];
      float d = dx * w0 + dy * w1 + dz * w2 + bp;
      del[j] = d;
      float sc = s[((size_t)(b * NN + idx)) * CC + c];
      float a = tc - sc + d;
      alpha[j] = a;
      mx = fmaxf(mx, a);
    }
    float sum = 0.f;
#pragma unroll
    for (int j = 0; j < 17; ++j) {
      float w = expf(alpha[j] - mx);
      alpha[j] = w;
      sum += w;
    }
    float inv = 1.f / sum;
    float hc = 0.f;
#pragma unroll
    for (int j = 0; j < 17; ++j) {
      int idx = (j < 16) ? nb[j * dil] : n;
      float vc = v[((size_t)(b * NN + idx)) * CC + c];
      hc += alpha[j] * (vc + del[j]);
    }
    ht += hc * inv;
  }

  h[(size_t)bn * CC + c] = ht;
}

// ---------------------------------------------------------------------------
// K5: out[m][0..2] = g[m] @ W2 + b2 + pos[m].  One wave per point.
// (verbatim from the R9 passing kernel)
// ---------------------------------------------------------------------------
__global__ __launch_bounds__(64) void final_kernel(
    const float* __restrict__ g, const float* __restrict__ W2,
    const float* __restrict__ b2, const float* __restrict__ pos,
    float* __restrict__ out) {
  int m = blockIdx.x;
  int k = threadIdx.x;
  float g0 = g[(size_t)m * CC + k];
  float g1 = g[(size_t)m * CC + 64 + k];
  float p0 = g0 * W2[k * 3 + 0] + g1 * W2[(k + 64) * 3 + 0];
  float p1 = g0 * W2[k * 3 + 1] + g1 * W2[(k + 64) * 3 + 1];
  float p2 = g0 * W2[k * 3 + 2] + g1 * W2[(k + 64) * 3 + 2];
#pragma unroll
  for (int off = 32; off >= 1; off >>= 1) {
    p0 += __shfl_down(p0, off);
    p1 += __shfl_down(p1, off);
    p2 += __shfl_down(p2, off);
  }
  if (k == 0) {
    out[m * 3 + 0] = p0 + b2[0] + pos[m * 3 + 0];
    out[m * 3 + 1] = p1 + b2[1] + pos[m * 3 + 1];
    out[m * 3 + 2] = p2 + b2[2] + pos[m * 3 + 2];
  }
}

extern "C" void kernel_launch(void* const* d_in, const int* in_sizes, int n_in,
                              void* d_out, int out_size, void* d_ws, size_t ws_size,
                              hipStream_t stream) {
  const float* x     = (const float*)d_in[0];
  const float* pos   = (const float*)d_in[1];
  const float* W_lin = (const float*)d_in[2];
  const float* W_src = (const float*)d_in[3];
  const float* W_dst = (const float*)d_in[4];
  const float* W_pos = (const float*)d_in[5];
  const float* b_pos = (const float*)d_in[6];
  const float* Wg    = (const float*)d_in[7];
  const float* bg    = (const float*)d_in[8];
  const float* W1    = (const float*)d_in[9];
  const float* b1    = (const float*)d_in[10];
  const float* W2    = (const float*)d_in[11];
  const float* b2    = (const float*)d_in[12];
  float* out = (float*)d_out;

  const size_t M = (size_t)BB * NN;        // 16384
  const size_t MC = M * CC;                // 2,097,152 floats

  // R9 workspace layout, verbatim.
  char* ws = (char*)d_ws;
  int* nbr = (int*)ws;                               // M*KMAX ints   = 2 MB
  unsigned short* cand = (unsigned short*)(ws + M * KMAX * sizeof(int));  // 8.4 MB
  float* fb = (float*)(ws + M * KMAX * sizeof(int) + M * CH * KMAX * sizeof(unsigned short));
  float* sb0 = fb + 0 * MC;
  float* sb1 = fb + 1 * MC;
  float* vb0 = fb + 2 * MC;
  float* vb1 = fb + 3 * MC;
  float* tb0 = fb + 4 * MC;
  float* tb1 = fb + 5 * MC;
  float* h   = fb + 6 * MC;
  float* g   = fb + 7 * MC;
  // candk (u32, M*CH*KMAX = 16.78 MB) aliases h+g (exactly 2*MC floats):
  // dead before the Wg GEMM writes h (stream-ordered after knn_p2).
  unsigned int* candk = (unsigned int*)h;

  // 1. KNN: gated chunk selection, then 8-way sorted merge (frozen R9 bytes)
  knn_p1<<<512, 256, 0, stream>>>(pos, cand, candk);
  knn_p2<<<256, 64, 0, stream>>>(candk, cand, nbr);

  // 2. six projections fused in ONE launch (z: sb0,sb1,vb0,vb1,tb0,tb1)
  gemm_kernel<<<dim3(M / 64, 1, 6), 256, 0, stream>>>(
      x, CC, CC, nullptr, 0, CC, W_src, W_lin, W_dst, nullptr, fb, 0);

  // 3. h = leaky(concat(x,pos) @ Wg + bg)
  gemm_kernel<<<dim3(M / 64, 1, 1), 256, 0, stream>>>(
      x, CC, CC, pos, 3, CC + 3, Wg, nullptr, nullptr, bg, h, 1);

  // 4. h += attention, both dilations fused (batch-locality swizzle)
  attn2_kernel<<<M, 128, 0, stream>>>(pos, nbr, sb0, vb0, tb0,
                                      sb1, vb1, tb1, W_pos, b_pos, h);

  // 5. g = leaky(h @ W1 + b1)
  gemm_kernel<<<dim3(M / 64, 1, 1), 256, 0, stream>>>(
      h, CC, CC, nullptr, 0, CC, W1, nullptr, nullptr, b1, g, 1);

  // 6. out = g @ W2 + b2 + pos
  final_kernel<<<M, 64, 0, stream>>>(g, W2, b2, pos, out);
}

// Round 14
// 323.375 us; speedup vs baseline: 1.5042x; 1.0996x over previous
//
#include <hip/hip_runtime.h>

#define BB 8
#define NN 2048
#define CC 128
#define KMAX 32
#define NEG 0.2f
#define CH 8
#define CHSZ (NN / CH)   // 256
#define CPAD 260         // chunk stride in LDS: (260*c+jj)%32 = (4c+jj)%32 -> 8 distinct banks
#define CAP 32           // per-thread candidate buffer (drain-on-full keeps j order)

using bf16x8 = __attribute__((ext_vector_type(8))) short;  // 8 bf16 (4 VGPRs)
using f32x4  = __attribute__((ext_vector_type(4))) float;  // 4 fp32

// Map f32 to a u32 whose unsigned order == float order (handles negatives).
__device__ __forceinline__ unsigned int f2key(float f) {
  unsigned int b = __float_as_uint(f);
  return (b & 0x80000000u) ? ~b : (b | 0x80000000u);
}

// np-exact f32 squared norm: fl(fl(x^2+y^2)+z^2), no FMA contraction.
__device__ __forceinline__ float sq3(float x, float y, float z) {
  return __fadd_rn(__fadd_rn(__fmul_rn(x, x), __fmul_rn(y, y)), __fmul_rn(z, z));
}

// np-exact f32 distance key: d2 = fl( fl(sq_i+sq_j) - fl(2*dot) ).
__device__ __forceinline__ float d2np(float px, float py, float pz, float sqq,
                                      float qx, float qy, float qz, float sqj) {
  float dot = __fmaf_rn(pz, qz, __fmaf_rn(py, qy, __fmul_rn(px, qx)));
  return __fsub_rn(__fadd_rn(sqq, sqj), __fmul_rn(2.0f, dot));
}

// f32 -> bf16 (round to nearest even), finite inputs.
__device__ __forceinline__ unsigned short f2bf(float f) {
  unsigned int u = __float_as_uint(f);
  return (unsigned short)((u + 0x7fffu + ((u >> 16) & 1u)) >> 16);
}

// ---------------------------------------------------------------------------
// K1a: KNN phase 1 — FROZEN R9 bytes (absmax 0.00195). Do not touch.
// ---------------------------------------------------------------------------
__global__ __launch_bounds__(256) void knn_p1(const float* __restrict__ pos,
                                              unsigned short* __restrict__ cand,
                                              unsigned int* __restrict__ candk) {
  __shared__ float spx[CH * CPAD], spy[CH * CPAD], spz[CH * CPAD], ssq[CH * CPAD];
  __shared__ unsigned int sred[256];
  __shared__ unsigned short sbuf[256 * CAP];
  int b = blockIdx.x >> 6;                       // 64 blocks per batch
  int qbase = (blockIdx.x & 63) * 32;
  const float* pb = pos + (size_t)b * NN * 3;
  for (int t = threadIdx.x; t < NN; t += 256) {
    int a = ((t >> 8) * CPAD) + (t & 255);       // padded SoA address of point t
    float x = pb[t * 3 + 0];
    float y = pb[t * 3 + 1];
    float z = pb[t * 3 + 2];
    spx[a] = x; spy[a] = y; spz[a] = z;
    ssq[a] = sq3(x, y, z);
  }
  __syncthreads();

  int q = qbase + (threadIdx.x >> 3);
  int c = threadIdx.x & 7;
  int qa = ((q >> 8) * CPAD) + (q & 255);
  float px = spx[qa], py = spy[qa], pz = spz[qa];
  float sqq = ssq[qa];

  int abase = c * CPAD;
  int j0 = c * CHSZ;

  // ---- Pass A: keys-only top-4 of this chunk (strict <, self-excluded) ----
  unsigned int a0 = 0xFFFFFFFFu, a1 = 0xFFFFFFFFu, a2 = 0xFFFFFFFFu, a3 = 0xFFFFFFFFu;
  for (int jj = 0; jj < CHSZ; ++jj) {
    int a = abase + jj;
    int j = j0 + jj;
    float d2 = d2np(px, py, pz, sqq, spx[a], spy[a], spz[a], ssq[a]);
    unsigned int key = f2key(d2);
    if (j == q) key = 0xFFFFFFFFu;
    if (key < a3) {
      bool c3 = key < a2;
      a3 = c3 ? a2 : key;
      bool c2 = key < a1;
      a2 = c3 ? (c2 ? a1 : key) : a2;
      bool c1 = key < a0;
      a1 = c2 ? (c1 ? a0 : key) : a1;
      a0 = c1 ? key : a0;
    }
  }
  sred[threadIdx.x] = a3;
  __syncthreads();
  if (c == 0) {
    unsigned int m = sred[threadIdx.x];
#pragma unroll
    for (int u = 1; u < 8; ++u) {
      unsigned int v = sred[threadIdx.x + u];
      m = v > m ? v : m;
    }
    sred[threadIdx.x] = m;
  }
  __syncthreads();
  unsigned int T = sred[threadIdx.x & ~7];

  // ---- Pass B: gate, buffer, drain through the exact R7 insert ----
  unsigned int ak[KMAX];
  int ai[KMAX];
#pragma unroll
  for (int k = 0; k < KMAX; ++k) { ak[k] = 0xFFFFFFFFu; ai[k] = 0xFFFF; }

  int sbase = threadIdx.x * CAP;
  auto drain = [&](int cnt2) {
    for (int u = 0; u < cnt2; ++u) {
      int jj2 = (int)sbuf[sbase + u];
      int a = abase + jj2;
      int j = j0 + jj2;
      float d2 = d2np(px, py, pz, sqq, spx[a], spy[a], spz[a], ssq[a]);
      unsigned int key = f2key(d2);               // self never buffered
      if (key < ak[KMAX - 1]) {                   // strict: stable ties -> lower j
#pragma unroll
        for (int k = KMAX - 1; k >= 1; --k) {
          bool ck  = key < ak[k];
          bool ckm = key < ak[k - 1];
          unsigned int tk = ckm ? ak[k - 1] : key;
          int          ti = ckm ? ai[k - 1] : j;
          ak[k] = ck ? tk : ak[k];
          ai[k] = ck ? ti : ai[k];
        }
        bool c0b = key < ak[0];
        ak[0] = c0b ? key : ak[0];
        ai[0] = c0b ? j : ai[0];
      }
    }
  };

  int cnt = 0;
  for (int jj = 0; jj < CHSZ; ++jj) {
    int a = abase + jj;
    int j = j0 + jj;
    float d2 = d2np(px, py, pz, sqq, spx[a], spy[a], spz[a], ssq[a]);
    unsigned int key = f2key(d2);
    if (j == q) key = 0xFFFFFFFFu;               // self fails gate (T < max)
    if (key <= T) {
      if (cnt == CAP) { drain(CAP); cnt = 0; }   // rare; preserves j order
      sbuf[sbase + cnt] = (unsigned short)jj;
      ++cnt;
    }
  }
  drain(cnt);

  size_t obase = (((size_t)(b * NN + q)) * CH + c) * KMAX;
  unsigned short* oc = cand + obase;
  unsigned int* ok = candk + obase;
#pragma unroll
  for (int k = 0; k < KMAX; ++k) {
    oc[k] = (unsigned short)ai[k];
    ok[k] = ak[k];
  }
}

// ---------------------------------------------------------------------------
// K1b: KNN phase 2 — 8-way merge. FROZEN R9 bytes.
// ---------------------------------------------------------------------------
__global__ __launch_bounds__(64) void knn_p2(const unsigned int* __restrict__ candk,
                                             const unsigned short* __restrict__ cand,
                                             int* __restrict__ nbr) {
  int q = blockIdx.x * 64 + threadIdx.x;         // global query id (b*NN+n)
  const unsigned int* k8 = candk + (size_t)q * (CH * KMAX);
  const unsigned short* i8 = cand + (size_t)q * (CH * KMAX);

  int head[CH];
  unsigned int hk[CH];
#pragma unroll
  for (int c = 0; c < CH; ++c) {
    head[c] = 0;
    hk[c] = k8[c * KMAX];
  }

  int* onb = nbr + (size_t)q * KMAX;
#pragma unroll
  for (int r = 0; r < KMAX; ++r) {
    int bc = 0;
    unsigned int bk = hk[0];
#pragma unroll
    for (int c = 1; c < CH; ++c) {
      if (hk[c] < bk) { bk = hk[c]; bc = c; }    // strict: ties -> lower c = lower j
    }
    onb[r] = (int)i8[bc * KMAX + head[bc]];
    ++head[bc];
    hk[bc] = (head[bc] < KMAX) ? k8[bc * KMAX + head[bc]] : 0xFFFFFFFFu;
  }
}

// ---------------------------------------------------------------------------
// K-cvt: x (f32, M*CC) -> xb (bf16). One thread per 4 elements.
// ---------------------------------------------------------------------------
__global__ __launch_bounds__(256) void cvt_x(const float* __restrict__ x,
                                             unsigned short* __restrict__ xb) {
  int t = blockIdx.x * 256 + threadIdx.x;        // 0 .. M*CC/4-1
  float4 v = *(const float4*)(x + (size_t)t * 4);
  unsigned short o[4] = {f2bf(v.x), f2bf(v.y), f2bf(v.z), f2bf(v.w)};
  *(ushort2*)(xb + (size_t)t * 4 + 0) = make_ushort2(o[0], o[1]);
  *(ushort2*)(xb + (size_t)t * 4 + 2) = make_ushort2(o[2], o[3]);
}

// ---------------------------------------------------------------------------
// K-wcvt: weights (f32) -> bf16 B-fragment order.
// wf[(((z*8+nt)*4+ks)*64+lane)*8 + j] = W_z[k][n], n = nt*16 + (lane&15),
// k = ks*32 + (lane>>4)*8 + j.  (B[k][n]: n=lane&15, k=quad*8+j per 16x16x32)
// One thread per (z,nt,ks,lane): grid 48 x 256.
// ---------------------------------------------------------------------------
__global__ __launch_bounds__(256) void wcvt(const float* __restrict__ Wa,
                                            const float* __restrict__ Wb,
                                            const float* __restrict__ Wc,
                                            unsigned short* __restrict__ wf) {
  int t = blockIdx.x * 256 + threadIdx.x;        // 0 .. 12287
  int lane = t & 63;
  int ks = (t >> 6) & 3;
  int nt = (t >> 8) & 7;
  int z = t >> 11;
  const float* W = (z < 2) ? (Wa + (size_t)z * CC * CC)
                 : (z < 4) ? (Wb + (size_t)(z - 2) * CC * CC)
                           : (Wc + (size_t)(z - 4) * CC * CC);
  int n = nt * 16 + (lane & 15);
  int kb = ks * 32 + (lane >> 4) * 8;
  unsigned short* o = wf + (size_t)t * 8;
#pragma unroll
  for (int j = 0; j < 8; ++j)
    o[j] = f2bf(W[(size_t)(kb + j) * CC + n]);
}

// ---------------------------------------------------------------------------
// K2-mfma: the 6 projections via v_mfma_f32_16x16x32_bf16, fp32 accumulate.
// Each wave: one 16-row strip x all 128 cols (8 col-tiles), K=128 (4 ksteps).
// A[m=lane&15][k=quad*8+j] from xb; B frags preshuffled in wf; C/D
// col=lane&15, row=quad*4+reg (learn_hip-verified layouts).
// Block 256 = 4 waves (4 strips). Grid (M/64, 1, 6).
// ---------------------------------------------------------------------------
__global__ __launch_bounds__(256) void mfma_proj(const unsigned short* __restrict__ xb,
                                                 const unsigned short* __restrict__ wf,
                                                 float* __restrict__ outbase) {
  int z = blockIdx.z;
  float* out = outbase + (size_t)z * ((size_t)BB * NN * CC);
  int wave = threadIdx.x >> 6;
  int lane = threadIdx.x & 63;
  int m0 = (blockIdx.x * 4 + wave) * 16;
  int quad = lane >> 4;
  int am = m0 + (lane & 15);

  f32x4 acc[8];
#pragma unroll
  for (int nt = 0; nt < 8; ++nt) acc[nt] = (f32x4){0.f, 0.f, 0.f, 0.f};

  const unsigned short* wz = wf + (size_t)z * (8 * 4 * 64 * 8);
#pragma unroll
  for (int ks = 0; ks < 4; ++ks) {
    bf16x8 a = *(const bf16x8*)(xb + (size_t)am * CC + ks * 32 + quad * 8);
#pragma unroll
    for (int nt = 0; nt < 8; ++nt) {
      bf16x8 b = *(const bf16x8*)(wz + (size_t)(((nt * 4 + ks) * 64 + lane) * 8));
      acc[nt] = __builtin_amdgcn_mfma_f32_16x16x32_bf16(a, b, acc[nt], 0, 0, 0);
    }
  }

  int col0 = lane & 15;
#pragma unroll
  for (int nt = 0; nt < 8; ++nt)
#pragma unroll
    for (int r = 0; r < 4; ++r)
      out[(size_t)(m0 + quad * 4 + r) * CC + nt * 16 + col0] = acc[nt][r];
}

// ---------------------------------------------------------------------------
// K2: f32 tiled GEMM (R9-proven 64x128 tile) — still used for Wg and W1.
// ---------------------------------------------------------------------------
__global__ __launch_bounds__(256) void gemm_kernel(
    const float* __restrict__ A1, int lda1, int K1,
    const float* __restrict__ A2, int lda2, int K,
    const float* __restrict__ Wa, const float* __restrict__ Wb,
    const float* __restrict__ Wc, const float* __restrict__ bias,
    float* __restrict__ outbase, int applyLeaky) {
  __shared__ float At[8][64];
  __shared__ float Wt[8][CC];

  int z = blockIdx.z;
  const float* W = (z < 2) ? (Wa + (size_t)z * CC * CC)
                 : (z < 4) ? (Wb + (size_t)(z - 2) * CC * CC)
                           : (Wc + (size_t)(z - 4) * CC * CC);
  float* out = outbase + (size_t)z * ((size_t)BB * NN * CC);

  int m0 = blockIdx.x * 64;
  int tid = threadIdx.x;
  int cg = tid & 31;
  int rg = tid >> 5;

  float acc[8][4];
#pragma unroll
  for (int r = 0; r < 8; ++r)
#pragma unroll
    for (int q = 0; q < 4; ++q) acc[r][q] = 0.f;

  int ksteps = (K + 7) >> 3;
  for (int ks = 0; ks < ksteps; ++ks) {
    int k0 = ks << 3;
    __syncthreads();
    {
      int f = tid * 2;
      int m = f >> 3;
      int kk = f & 7;
      int gm = m0 + m;
#pragma unroll
      for (int u = 0; u < 2; ++u) {
        int k = k0 + kk + u;
        float v = 0.f;
        if (k < K1) v = A1[(size_t)gm * lda1 + k];
        else if (k < K) v = A2[(size_t)gm * lda2 + (k - K1)];
        At[kk + u][m] = v;
      }
    }
    {
      int kk = tid >> 5;
      int c = (tid & 31) * 4;
      int k = k0 + kk;
      float4 w = make_float4(0.f, 0.f, 0.f, 0.f);
      if (k < K) w = *(const float4*)(W + (size_t)k * CC + c);
      *(float4*)(&Wt[kk][c]) = w;
    }
    __syncthreads();
#pragma unroll
    for (int kk = 0; kk < 8; ++kk) {
      float4 a0 = *(const float4*)(&At[kk][rg * 8]);
      float4 a1 = *(const float4*)(&At[kk][rg * 8 + 4]);
      float4 w = *(const float4*)(&Wt[kk][cg * 4]);
      float a[8] = {a0.x, a0.y, a0.z, a0.w, a1.x, a1.y, a1.z, a1.w};
#pragma unroll
      for (int r = 0; r < 8; ++r) {
        acc[r][0] += a[r] * w.x;
        acc[r][1] += a[r] * w.y;
        acc[r][2] += a[r] * w.z;
        acc[r][3] += a[r] * w.w;
      }
    }
  }

#pragma unroll
  for (int r = 0; r < 8; ++r) {
    int m = m0 + rg * 8 + r;
#pragma unroll
    for (int q = 0; q < 4; ++q) {
      int c = cg * 4 + q;
      float v = acc[r][q];
      if (bias) v += bias[c];
      if (applyLeaky) v = v > 0.f ? v : NEG * v;
      out[(size_t)m * CC + c] = v;
    }
  }
}

// ---------------------------------------------------------------------------
// K3: fused attention — both dilations, batch-locality swizzle (R13 WIN).
// ---------------------------------------------------------------------------
__global__ __launch_bounds__(128) void attn2_kernel(
    const float* __restrict__ pos, const int* __restrict__ nbr,
    const float* __restrict__ s0, const float* __restrict__ v0,
    const float* __restrict__ t0,
    const float* __restrict__ s1, const float* __restrict__ v1,
    const float* __restrict__ t1,
    const float* __restrict__ Wpos, const float* __restrict__ bpos,
    float* __restrict__ h) {
  int b = blockIdx.x & 7;                        // XCD-locality swizzle
  int n = blockIdx.x >> 3;
  int bn = (b << 11) + n;
  int c = threadIdx.x;

  const float* pb = pos + (size_t)b * NN * 3;
  float pix = pb[n * 3 + 0], piy = pb[n * 3 + 1], piz = pb[n * 3 + 2];
  const int* nb = nbr + (size_t)bn * KMAX;

  float ht = h[(size_t)bn * CC + c];             // h_in (Wg output)

#pragma unroll
  for (int l = 0; l < 2; ++l) {
    int dil = l + 1;
    const float* s = l ? s1 : s0;
    const float* v = l ? v1 : v0;
    const float* t = l ? t1 : t0;
    const float* Wp = Wpos + (size_t)l * 3 * CC;
    float w0 = Wp[c], w1 = Wp[CC + c], w2 = Wp[2 * CC + c];
    float bp = bpos[(size_t)l * CC + c];
    float tc = t[(size_t)bn * CC + c];

    float alpha[17], del[17];
    float mx = -1e30f;
#pragma unroll
    for (int j = 0; j < 17; ++j) {
      int idx = (j < 16) ? nb[j * dil] : n;
      float dx = pix - pb[idx * 3 + 0];
      float dy = piy - pb[idx * 3 + 1];
      float dz = piz - pb[idx * 3 + 2];
      float d = dx * w0 + dy * w1 + dz * w2 + bp;
      del[j] = d;
      float sc = s[((size_t)(b * NN + idx)) * CC + c];
      float a = tc - sc + d;
      alpha[j] = a;
      mx = fmaxf(mx, a);
    }
    float sum = 0.f;
#pragma unroll
    for (int j = 0; j < 17; ++j) {
      float w = expf(alpha[j] - mx);
      alpha[j] = w;
      sum += w;
    }
    float inv = 1.f / sum;
    float hc = 0.f;
#pragma unroll
    for (int j = 0; j < 17; ++j) {
      int idx = (j < 16) ? nb[j * dil] : n;
      float vc = v[((size_t)(b * NN + idx)) * CC + c];
      hc += alpha[j] * (vc + del[j]);
    }
    ht += hc * inv;
  }

  h[(size_t)bn * CC + c] = ht;
}

// ---------------------------------------------------------------------------
// K5: out[m][0..2] = g[m] @ W2 + b2 + pos[m].  One wave per point.
// ---------------------------------------------------------------------------
__global__ __launch_bounds__(64) void final_kernel(
    const float* __restrict__ g, const float* __restrict__ W2,
    const float* __restrict__ b2, const float* __restrict__ pos,
    float* __restrict__ out) {
  int m = blockIdx.x;
  int k = threadIdx.x;
  float g0 = g[(size_t)m * CC + k];
  float g1 = g[(size_t)m * CC + 64 + k];
  float p0 = g0 * W2[k * 3 + 0] + g1 * W2[(k + 64) * 3 + 0];
  float p1 = g0 * W2[k * 3 + 1] + g1 * W2[(k + 64) * 3 + 1];
  float p2 = g0 * W2[k * 3 + 2] + g1 * W2[(k + 64) * 3 + 2];
#pragma unroll
  for (int off = 32; off >= 1; off >>= 1) {
    p0 += __shfl_down(p0, off);
    p1 += __shfl_down(p1, off);
    p2 += __shfl_down(p2, off);
  }
  if (k == 0) {
    out[m * 3 + 0] = p0 + b2[0] + pos[m * 3 + 0];
    out[m * 3 + 1] = p1 + b2[1] + pos[m * 3 + 1];
    out[m * 3 + 2] = p2 + b2[2] + pos[m * 3 + 2];
  }
}

extern "C" void kernel_launch(void* const* d_in, const int* in_sizes, int n_in,
                              void* d_out, int out_size, void* d_ws, size_t ws_size,
                              hipStream_t stream) {
  const float* x     = (const float*)d_in[0];
  const float* pos   = (const float*)d_in[1];
  const float* W_lin = (const float*)d_in[2];
  const float* W_src = (const float*)d_in[3];
  const float* W_dst = (const float*)d_in[4];
  const float* W_pos = (const float*)d_in[5];
  const float* b_pos = (const float*)d_in[6];
  const float* Wg    = (const float*)d_in[7];
  const float* bg    = (const float*)d_in[8];
  const float* W1    = (const float*)d_in[9];
  const float* b1    = (const float*)d_in[10];
  const float* W2    = (const float*)d_in[11];
  const float* b2    = (const float*)d_in[12];
  float* out = (float*)d_out;

  const size_t M = (size_t)BB * NN;        // 16384
  const size_t MC = M * CC;                // 2,097,152 floats

  // R9 workspace layout, verbatim.
  char* ws = (char*)d_ws;
  int* nbr = (int*)ws;                               // M*KMAX ints   = 2 MB
  unsigned short* cand = (unsigned short*)(ws + M * KMAX * sizeof(int));  // 8.4 MB
  float* fb = (float*)(ws + M * KMAX * sizeof(int) + M * CH * KMAX * sizeof(unsigned short));
  float* sb0 = fb + 0 * MC;
  float* sb1 = fb + 1 * MC;
  float* vb0 = fb + 2 * MC;
  float* vb1 = fb + 3 * MC;
  float* tb0 = fb + 4 * MC;
  float* tb1 = fb + 5 * MC;
  float* h   = fb + 6 * MC;
  float* g   = fb + 7 * MC;
  // candk (u32, 16.78 MB) aliases h+g: dead before the Wg GEMM writes h.
  unsigned int* candk = (unsigned int*)h;
  // xb (bf16, 4 MB) + wf (bf16 fragments, 192 KB) alias the cand region:
  // dead after knn_p2 (stream-ordered before cvt_x/wcvt).
  unsigned short* xb = cand;
  unsigned short* wf = cand + MC;          // 4 MB in, well inside 8.4 MB

  // 1. KNN: gated chunk selection, then 8-way sorted merge (frozen R9 bytes)
  knn_p1<<<512, 256, 0, stream>>>(pos, cand, candk);
  knn_p2<<<256, 64, 0, stream>>>(candk, cand, nbr);

  // 2. bf16 casts + six projections via MFMA (z: sb0,sb1,vb0,vb1,tb0,tb1)
  cvt_x<<<MC / 1024, 256, 0, stream>>>(x, xb);
  wcvt<<<48, 256, 0, stream>>>(W_src, W_lin, W_dst, wf);
  mfma_proj<<<dim3(M / 64, 1, 6), 256, 0, stream>>>(xb, wf, fb);

  // 3. h = leaky(concat(x,pos) @ Wg + bg)   (f32)
  gemm_kernel<<<dim3(M / 64, 1, 1), 256, 0, stream>>>(
      x, CC, CC, pos, 3, CC + 3, Wg, nullptr, nullptr, bg, h, 1);

  // 4. h += attention, both dilations fused (batch-locality swizzle)
  attn2_kernel<<<M, 128, 0, stream>>>(pos, nbr, sb0, vb0, tb0,
                                      sb1, vb1, tb1, W_pos, b_pos, h);

  // 5. g = leaky(h @ W1 + b1)   (f32)
  gemm_kernel<<<dim3(M / 64, 1, 1), 256, 0, stream>>>(
      h, CC, CC, nullptr, 0, CC, W1, nullptr, nullptr, b1, g, 1);

  // 6. out = g @ W2 + b2 + pos
  final_kernel<<<M, 64, 0, stream>>>(g, W2, b2, pos, out);
}

// Round 15
// 309.857 us; speedup vs baseline: 1.5698x; 1.0436x over previous
//
#include <hip/hip_runtime.h>

#define BB 8
#define NN 2048
#define CC 128
#define KMAX 32
#define NEG 0.2f
#define CH 8
#define CHSZ (NN / CH)   // 256
#define CPAD 260         // chunk stride in LDS: (260*c+jj)%32 = (4c+jj)%32 -> 8 distinct banks
#define CAP 32           // per-thread candidate buffer (drain-on-full keeps j order)

using bf16x8 = __attribute__((ext_vector_type(8))) short;  // 8 bf16 (4 VGPRs)
using f32x4  = __attribute__((ext_vector_type(4))) float;  // 4 fp32

// Map f32 to a u32 whose unsigned order == float order (handles negatives).
__device__ __forceinline__ unsigned int f2key(float f) {
  unsigned int b = __float_as_uint(f);
  return (b & 0x80000000u) ? ~b : (b | 0x80000000u);
}

// np-exact f32 squared norm: fl(fl(x^2+y^2)+z^2), no FMA contraction.
__device__ __forceinline__ float sq3(float x, float y, float z) {
  return __fadd_rn(__fadd_rn(__fmul_rn(x, x), __fmul_rn(y, y)), __fmul_rn(z, z));
}

// np-exact f32 distance key: d2 = fl( fl(sq_i+sq_j) - fl(2*dot) ).
__device__ __forceinline__ float d2np(float px, float py, float pz, float sqq,
                                      float qx, float qy, float qz, float sqj) {
  float dot = __fmaf_rn(pz, qz, __fmaf_rn(py, qy, __fmul_rn(px, qx)));
  return __fsub_rn(__fadd_rn(sqq, sqj), __fmul_rn(2.0f, dot));
}

// f32 -> bf16 (round to nearest even), finite inputs.
__device__ __forceinline__ unsigned short f2bf(float f) {
  unsigned int u = __float_as_uint(f);
  return (unsigned short)((u + 0x7fffu + ((u >> 16) & 1u)) >> 16);
}

// ---------------------------------------------------------------------------
// FUSED FRONT: blocks [0,512) = knn_p1 (FROZEN R9 body, blockIdx arithmetic
// unchanged because knn blocks come first); blocks [512,2048) = mfma_proj
// (R14 body, bx = blockIdx.x-512 -> z = bx>>8, mx = bx&255). The two halves
// are data-independent: knn writes cand+candk, mfma reads xb/wf (dedicated
// regions, no aliasing) and writes fb[0..6MC). mfma uses no LDS -> co-
// schedules with knn's VALU/LDS waves (MFMA+VALU overlap, m114).
// ---------------------------------------------------------------------------
__global__ __launch_bounds__(256) void fused_front(
    const float* __restrict__ pos,
    unsigned short* __restrict__ cand,
    unsigned int* __restrict__ candk,
    const unsigned short* __restrict__ xb,
    const unsigned short* __restrict__ wf,
    float* __restrict__ outbase) {
  __shared__ float spx[CH * CPAD], spy[CH * CPAD], spz[CH * CPAD], ssq[CH * CPAD];
  __shared__ unsigned int sred[256];
  __shared__ unsigned short sbuf[256 * CAP];

  if (blockIdx.x < 512) {
    // ---------------- knn_p1: FROZEN R9 body. Do not touch. ----------------
    int b = blockIdx.x >> 6;                       // 64 blocks per batch
    int qbase = (blockIdx.x & 63) * 32;
    const float* pb = pos + (size_t)b * NN * 3;
    for (int t = threadIdx.x; t < NN; t += 256) {
      int a = ((t >> 8) * CPAD) + (t & 255);       // padded SoA address of point t
      float x = pb[t * 3 + 0];
      float y = pb[t * 3 + 1];
      float z = pb[t * 3 + 2];
      spx[a] = x; spy[a] = y; spz[a] = z;
      ssq[a] = sq3(x, y, z);
    }
    __syncthreads();

    int q = qbase + (threadIdx.x >> 3);
    int c = threadIdx.x & 7;
    int qa = ((q >> 8) * CPAD) + (q & 255);
    float px = spx[qa], py = spy[qa], pz = spz[qa];
    float sqq = ssq[qa];

    int abase = c * CPAD;
    int j0 = c * CHSZ;

    // ---- Pass A: keys-only top-4 of this chunk (strict <, self-excluded) ----
    unsigned int a0 = 0xFFFFFFFFu, a1 = 0xFFFFFFFFu, a2 = 0xFFFFFFFFu, a3 = 0xFFFFFFFFu;
    for (int jj = 0; jj < CHSZ; ++jj) {
      int a = abase + jj;
      int j = j0 + jj;
      float d2 = d2np(px, py, pz, sqq, spx[a], spy[a], spz[a], ssq[a]);
      unsigned int key = f2key(d2);
      if (j == q) key = 0xFFFFFFFFu;
      if (key < a3) {
        bool c3 = key < a2;
        a3 = c3 ? a2 : key;
        bool c2 = key < a1;
        a2 = c3 ? (c2 ? a1 : key) : a2;
        bool c1 = key < a0;
        a1 = c2 ? (c1 ? a0 : key) : a1;
        a0 = c1 ? key : a0;
      }
    }
    sred[threadIdx.x] = a3;
    __syncthreads();
    if (c == 0) {
      unsigned int m = sred[threadIdx.x];
#pragma unroll
      for (int u = 1; u < 8; ++u) {
        unsigned int v = sred[threadIdx.x + u];
        m = v > m ? v : m;
      }
      sred[threadIdx.x] = m;
    }
    __syncthreads();
    unsigned int T = sred[threadIdx.x & ~7];

    // ---- Pass B: gate, buffer, drain through the exact R7 insert ----
    unsigned int ak[KMAX];
    int ai[KMAX];
#pragma unroll
    for (int k = 0; k < KMAX; ++k) { ak[k] = 0xFFFFFFFFu; ai[k] = 0xFFFF; }

    int sbase = threadIdx.x * CAP;
    auto drain = [&](int cnt2) {
      for (int u = 0; u < cnt2; ++u) {
        int jj2 = (int)sbuf[sbase + u];
        int a = abase + jj2;
        int j = j0 + jj2;
        float d2 = d2np(px, py, pz, sqq, spx[a], spy[a], spz[a], ssq[a]);
        unsigned int key = f2key(d2);               // self never buffered
        if (key < ak[KMAX - 1]) {                   // strict: stable ties -> lower j
#pragma unroll
          for (int k = KMAX - 1; k >= 1; --k) {
            bool ck  = key < ak[k];
            bool ckm = key < ak[k - 1];
            unsigned int tk = ckm ? ak[k - 1] : key;
            int          ti = ckm ? ai[k - 1] : j;
            ak[k] = ck ? tk : ak[k];
            ai[k] = ck ? ti : ai[k];
          }
          bool c0b = key < ak[0];
          ak[0] = c0b ? key : ak[0];
          ai[0] = c0b ? j : ai[0];
        }
      }
    };

    int cnt = 0;
    for (int jj = 0; jj < CHSZ; ++jj) {
      int a = abase + jj;
      int j = j0 + jj;
      float d2 = d2np(px, py, pz, sqq, spx[a], spy[a], spz[a], ssq[a]);
      unsigned int key = f2key(d2);
      if (j == q) key = 0xFFFFFFFFu;               // self fails gate (T < max)
      if (key <= T) {
        if (cnt == CAP) { drain(CAP); cnt = 0; }   // rare; preserves j order
        sbuf[sbase + cnt] = (unsigned short)jj;
        ++cnt;
      }
    }
    drain(cnt);

    size_t obase = (((size_t)(b * NN + q)) * CH + c) * KMAX;
    unsigned short* oc = cand + obase;
    unsigned int* ok = candk + obase;
#pragma unroll
    for (int k = 0; k < KMAX; ++k) {
      oc[k] = (unsigned short)ai[k];
      ok[k] = ak[k];
    }
  } else {
    // ---------------- mfma_proj: R14 body, remapped block id ----------------
    int bx = blockIdx.x - 512;
    int z = bx >> 8;                               // 0..5
    int mx = bx & 255;
    float* out = outbase + (size_t)z * ((size_t)BB * NN * CC);
    int wave = threadIdx.x >> 6;
    int lane = threadIdx.x & 63;
    int m0 = (mx * 4 + wave) * 16;
    int quad = lane >> 4;
    int am = m0 + (lane & 15);

    f32x4 acc[8];
#pragma unroll
    for (int nt = 0; nt < 8; ++nt) acc[nt] = (f32x4){0.f, 0.f, 0.f, 0.f};

    const unsigned short* wz = wf + (size_t)z * (8 * 4 * 64 * 8);
#pragma unroll
    for (int ks = 0; ks < 4; ++ks) {
      bf16x8 a = *(const bf16x8*)(xb + (size_t)am * CC + ks * 32 + quad * 8);
#pragma unroll
      for (int nt = 0; nt < 8; ++nt) {
        bf16x8 bfr = *(const bf16x8*)(wz + (size_t)(((nt * 4 + ks) * 64 + lane) * 8));
        acc[nt] = __builtin_amdgcn_mfma_f32_16x16x32_bf16(a, bfr, acc[nt], 0, 0, 0);
      }
    }

    int col0 = lane & 15;
#pragma unroll
    for (int nt = 0; nt < 8; ++nt)
#pragma unroll
      for (int r = 0; r < 4; ++r)
        out[(size_t)(m0 + quad * 4 + r) * CC + nt * 16 + col0] = acc[nt][r];
  }
}

// ---------------------------------------------------------------------------
// K1a (fallback path only): knn_p1 standalone — FROZEN R9 bytes.
// ---------------------------------------------------------------------------
__global__ __launch_bounds__(256) void knn_p1(const float* __restrict__ pos,
                                              unsigned short* __restrict__ cand,
                                              unsigned int* __restrict__ candk) {
  __shared__ float spx[CH * CPAD], spy[CH * CPAD], spz[CH * CPAD], ssq[CH * CPAD];
  __shared__ unsigned int sred[256];
  __shared__ unsigned short sbuf[256 * CAP];
  int b = blockIdx.x >> 6;                       // 64 blocks per batch
  int qbase = (blockIdx.x & 63) * 32;
  const float* pb = pos + (size_t)b * NN * 3;
  for (int t = threadIdx.x; t < NN; t += 256) {
    int a = ((t >> 8) * CPAD) + (t & 255);       // padded SoA address of point t
    float x = pb[t * 3 + 0];
    float y = pb[t * 3 + 1];
    float z = pb[t * 3 + 2];
    spx[a] = x; spy[a] = y; spz[a] = z;
    ssq[a] = sq3(x, y, z);
  }
  __syncthreads();

  int q = qbase + (threadIdx.x >> 3);
  int c = threadIdx.x & 7;
  int qa = ((q >> 8) * CPAD) + (q & 255);
  float px = spx[qa], py = spy[qa], pz = spz[qa];
  float sqq = ssq[qa];

  int abase = c * CPAD;
  int j0 = c * CHSZ;

  unsigned int a0 = 0xFFFFFFFFu, a1 = 0xFFFFFFFFu, a2 = 0xFFFFFFFFu, a3 = 0xFFFFFFFFu;
  for (int jj = 0; jj < CHSZ; ++jj) {
    int a = abase + jj;
    int j = j0 + jj;
    float d2 = d2np(px, py, pz, sqq, spx[a], spy[a], spz[a], ssq[a]);
    unsigned int key = f2key(d2);
    if (j == q) key = 0xFFFFFFFFu;
    if (key < a3) {
      bool c3 = key < a2;
      a3 = c3 ? a2 : key;
      bool c2 = key < a1;
      a2 = c3 ? (c2 ? a1 : key) : a2;
      bool c1 = key < a0;
      a1 = c2 ? (c1 ? a0 : key) : a1;
      a0 = c1 ? key : a0;
    }
  }
  sred[threadIdx.x] = a3;
  __syncthreads();
  if (c == 0) {
    unsigned int m = sred[threadIdx.x];
#pragma unroll
    for (int u = 1; u < 8; ++u) {
      unsigned int v = sred[threadIdx.x + u];
      m = v > m ? v : m;
    }
    sred[threadIdx.x] = m;
  }
  __syncthreads();
  unsigned int T = sred[threadIdx.x & ~7];

  unsigned int ak[KMAX];
  int ai[KMAX];
#pragma unroll
  for (int k = 0; k < KMAX; ++k) { ak[k] = 0xFFFFFFFFu; ai[k] = 0xFFFF; }

  int sbase = threadIdx.x * CAP;
  auto drain = [&](int cnt2) {
    for (int u = 0; u < cnt2; ++u) {
      int jj2 = (int)sbuf[sbase + u];
      int a = abase + jj2;
      int j = j0 + jj2;
      float d2 = d2np(px, py, pz, sqq, spx[a], spy[a], spz[a], ssq[a]);
      unsigned int key = f2key(d2);               // self never buffered
      if (key < ak[KMAX - 1]) {                   // strict: stable ties -> lower j
#pragma unroll
        for (int k = KMAX - 1; k >= 1; --k) {
          bool ck  = key < ak[k];
          bool ckm = key < ak[k - 1];
          unsigned int tk = ckm ? ak[k - 1] : key;
          int          ti = ckm ? ai[k - 1] : j;
          ak[k] = ck ? tk : ak[k];
          ai[k] = ck ? ti : ai[k];
        }
        bool c0b = key < ak[0];
        ak[0] = c0b ? key : ak[0];
        ai[0] = c0b ? j : ai[0];
      }
    }
  };

  int cnt = 0;
  for (int jj = 0; jj < CHSZ; ++jj) {
    int a = abase + jj;
    int j = j0 + jj;
    float d2 = d2np(px, py, pz, sqq, spx[a], spy[a], spz[a], ssq[a]);
    unsigned int key = f2key(d2);
    if (j == q) key = 0xFFFFFFFFu;               // self fails gate (T < max)
    if (key <= T) {
      if (cnt == CAP) { drain(CAP); cnt = 0; }   // rare; preserves j order
      sbuf[sbase + cnt] = (unsigned short)jj;
      ++cnt;
    }
  }
  drain(cnt);

  size_t obase = (((size_t)(b * NN + q)) * CH + c) * KMAX;
  unsigned short* oc = cand + obase;
  unsigned int* ok = candk + obase;
#pragma unroll
  for (int k = 0; k < KMAX; ++k) {
    oc[k] = (unsigned short)ai[k];
    ok[k] = ak[k];
  }
}

// ---------------------------------------------------------------------------
// K1b: KNN phase 2 — 8-way merge. FROZEN R9 bytes.
// ---------------------------------------------------------------------------
__global__ __launch_bounds__(64) void knn_p2(const unsigned int* __restrict__ candk,
                                             const unsigned short* __restrict__ cand,
                                             int* __restrict__ nbr) {
  int q = blockIdx.x * 64 + threadIdx.x;         // global query id (b*NN+n)
  const unsigned int* k8 = candk + (size_t)q * (CH * KMAX);
  const unsigned short* i8 = cand + (size_t)q * (CH * KMAX);

  int head[CH];
  unsigned int hk[CH];
#pragma unroll
  for (int c = 0; c < CH; ++c) {
    head[c] = 0;
    hk[c] = k8[c * KMAX];
  }

  int* onb = nbr + (size_t)q * KMAX;
#pragma unroll
  for (int r = 0; r < KMAX; ++r) {
    int bc = 0;
    unsigned int bk = hk[0];
#pragma unroll
    for (int c = 1; c < CH; ++c) {
      if (hk[c] < bk) { bk = hk[c]; bc = c; }    // strict: ties -> lower c = lower j
    }
    onb[r] = (int)i8[bc * KMAX + head[bc]];
    ++head[bc];
    hk[bc] = (head[bc] < KMAX) ? k8[bc * KMAX + head[bc]] : 0xFFFFFFFFu;
  }
}

// ---------------------------------------------------------------------------
// K-cvt: x (f32, M*CC) -> xb (bf16). One thread per 4 elements.
// ---------------------------------------------------------------------------
__global__ __launch_bounds__(256) void cvt_x(const float* __restrict__ x,
                                             unsigned short* __restrict__ xb) {
  int t = blockIdx.x * 256 + threadIdx.x;        // 0 .. M*CC/4-1
  float4 v = *(const float4*)(x + (size_t)t * 4);
  unsigned short o[4] = {f2bf(v.x), f2bf(v.y), f2bf(v.z), f2bf(v.w)};
  *(ushort2*)(xb + (size_t)t * 4 + 0) = make_ushort2(o[0], o[1]);
  *(ushort2*)(xb + (size_t)t * 4 + 2) = make_ushort2(o[2], o[3]);
}

// ---------------------------------------------------------------------------
// K-wcvt: weights (f32) -> bf16 B-fragment order (R14 verbatim).
// ---------------------------------------------------------------------------
__global__ __launch_bounds__(256) void wcvt(const float* __restrict__ Wa,
                                            const float* __restrict__ Wb,
                                            const float* __restrict__ Wc,
                                            unsigned short* __restrict__ wf) {
  int t = blockIdx.x * 256 + threadIdx.x;        // 0 .. 12287
  int lane = t & 63;
  int ks = (t >> 6) & 3;
  int nt = (t >> 8) & 7;
  int z = t >> 11;
  const float* W = (z < 2) ? (Wa + (size_t)z * CC * CC)
                 : (z < 4) ? (Wb + (size_t)(z - 2) * CC * CC)
                           : (Wc + (size_t)(z - 4) * CC * CC);
  int n = nt * 16 + (lane & 15);
  int kb = ks * 32 + (lane >> 4) * 8;
  unsigned short* o = wf + (size_t)t * 8;
#pragma unroll
  for (int j = 0; j < 8; ++j)
    o[j] = f2bf(W[(size_t)(kb + j) * CC + n]);
}

// ---------------------------------------------------------------------------
// K2-mfma (fallback path only): R14 standalone mfma_proj.
// ---------------------------------------------------------------------------
__global__ __launch_bounds__(256) void mfma_proj(const unsigned short* __restrict__ xb,
                                                 const unsigned short* __restrict__ wf,
                                                 float* __restrict__ outbase) {
  int z = blockIdx.z;
  float* out = outbase + (size_t)z * ((size_t)BB * NN * CC);
  int wave = threadIdx.x >> 6;
  int lane = threadIdx.x & 63;
  int m0 = (blockIdx.x * 4 + wave) * 16;
  int quad = lane >> 4;
  int am = m0 + (lane & 15);

  f32x4 acc[8];
#pragma unroll
  for (int nt = 0; nt < 8; ++nt) acc[nt] = (f32x4){0.f, 0.f, 0.f, 0.f};

  const unsigned short* wz = wf + (size_t)z * (8 * 4 * 64 * 8);
#pragma unroll
  for (int ks = 0; ks < 4; ++ks) {
    bf16x8 a = *(const bf16x8*)(xb + (size_t)am * CC + ks * 32 + quad * 8);
#pragma unroll
    for (int nt = 0; nt < 8; ++nt) {
      bf16x8 b = *(const bf16x8*)(wz + (size_t)(((nt * 4 + ks) * 64 + lane) * 8));
      acc[nt] = __builtin_amdgcn_mfma_f32_16x16x32_bf16(a, b, acc[nt], 0, 0, 0);
    }
  }

  int col0 = lane & 15;
#pragma unroll
  for (int nt = 0; nt < 8; ++nt)
#pragma unroll
    for (int r = 0; r < 4; ++r)
      out[(size_t)(m0 + quad * 4 + r) * CC + nt * 16 + col0] = acc[nt][r];
}

// ---------------------------------------------------------------------------
// K2: f32 tiled GEMM (R9-proven 64x128 tile) — used for Wg and W1.
// ---------------------------------------------------------------------------
__global__ __launch_bounds__(256) void gemm_kernel(
    const float* __restrict__ A1, int lda1, int K1,
    const float* __restrict__ A2, int lda2, int K,
    const float* __restrict__ Wa, const float* __restrict__ Wb,
    const float* __restrict__ Wc, const float* __restrict__ bias,
    float* __restrict__ outbase, int applyLeaky) {
  __shared__ float At[8][64];
  __shared__ float Wt[8][CC];

  int z = blockIdx.z;
  const float* W = (z < 2) ? (Wa + (size_t)z * CC * CC)
                 : (z < 4) ? (Wb + (size_t)(z - 2) * CC * CC)
                           : (Wc + (size_t)(z - 4) * CC * CC);
  float* out = outbase + (size_t)z * ((size_t)BB * NN * CC);

  int m0 = blockIdx.x * 64;
  int tid = threadIdx.x;
  int cg = tid & 31;
  int rg = tid >> 5;

  float acc[8][4];
#pragma unroll
  for (int r = 0; r < 8; ++r)
#pragma unroll
    for (int q = 0; q < 4; ++q) acc[r][q] = 0.f;

  int ksteps = (K + 7) >> 3;
  for (int ks = 0; ks < ksteps; ++ks) {
    int k0 = ks << 3;
    __syncthreads();
    {
      int f = tid * 2;
      int m = f >> 3;
      int kk = f & 7;
      int gm = m0 + m;
#pragma unroll
      for (int u = 0; u < 2; ++u) {
        int k = k0 + kk + u;
        float v = 0.f;
        if (k < K1) v = A1[(size_t)gm * lda1 + k];
        else if (k < K) v = A2[(size_t)gm * lda2 + (k - K1)];
        At[kk + u][m] = v;
      }
    }
    {
      int kk = tid >> 5;
      int c = (tid & 31) * 4;
      int k = k0 + kk;
      float4 w = make_float4(0.f, 0.f, 0.f, 0.f);
      if (k < K) w = *(const float4*)(W + (size_t)k * CC + c);
      *(float4*)(&Wt[kk][c]) = w;
    }
    __syncthreads();
#pragma unroll
    for (int kk = 0; kk < 8; ++kk) {
      float4 a0 = *(const float4*)(&At[kk][rg * 8]);
      float4 a1 = *(const float4*)(&At[kk][rg * 8 + 4]);
      float4 w = *(const float4*)(&Wt[kk][cg * 4]);
      float a[8] = {a0.x, a0.y, a0.z, a0.w, a1.x, a1.y, a1.z, a1.w};
#pragma unroll
      for (int r = 0; r < 8; ++r) {
        acc[r][0] += a[r] * w.x;
        acc[r][1] += a[r] * w.y;
        acc[r][2] += a[r] * w.z;
        acc[r][3] += a[r] * w.w;
      }
    }
  }

#pragma unroll
  for (int r = 0; r < 8; ++r) {
    int m = m0 + rg * 8 + r;
#pragma unroll
    for (int q = 0; q < 4; ++q) {
      int c = cg * 4 + q;
      float v = acc[r][q];
      if (bias) v += bias[c];
      if (applyLeaky) v = v > 0.f ? v : NEG * v;
      out[(size_t)m * CC + c] = v;
    }
  }
}

// ---------------------------------------------------------------------------
// K3: fused attention — both dilations, batch-locality swizzle (R13 WIN).
// ---------------------------------------------------------------------------
__global__ __launch_bounds__(128) void attn2_kernel(
    const float* __restrict__ pos, const int* __restrict__ nbr,
    const float* __restrict__ s0, const float* __restrict__ v0,
    const float* __restrict__ t0,
    const float* __restrict__ s1, const float* __restrict__ v1,
    const float* __restrict__ t1,
    const float* __restrict__ Wpos, const float* __restrict__ bpos,
    float* __restrict__ h) {
  int b = blockIdx.x & 7;                        // XCD-locality swizzle
  int n = blockIdx.x >> 3;
  int bn = (b << 11) + n;
  int c = threadIdx.x;

  const float* pb = pos + (size_t)b * NN * 3;
  float pix = pb[n * 3 + 0], piy = pb[n * 3 + 1], piz = pb[n * 3 + 2];
  const int* nb = nbr + (size_t)bn * KMAX;

  float ht = h[(size_t)bn * CC + c];             // h_in (Wg output)

#pragma unroll
  for (int l = 0; l < 2; ++l) {
    int dil = l + 1;
    const float* s = l ? s1 : s0;
    const float* v = l ? v1 : v0;
    const float* t = l ? t1 : t0;
    const float* Wp = Wpos + (size_t)l * 3 * CC;
    float w0 = Wp[c], w1 = Wp[CC + c], w2 = Wp[2 * CC + c];
    float bp = bpos[(size_t)l * CC + c];
    float tc = t[(size_t)bn * CC + c];

    float alpha[17], del[17];
    float mx = -1e30f;
#pragma unroll
    for (int j = 0; j < 17; ++j) {
      int idx = (j < 16) ? nb[j * dil] : n;
      float dx = pix - pb[idx * 3 + 0];
      float dy = piy - pb[idx * 3 + 1];
      float dz = piz - pb[idx * 3 + 2];
      float d = dx * w0 + dy * w1 + dz * w2 + bp;
      del[j] = d;
      float sc = s[((size_t)(b * NN + idx)) * CC + c];
      float a = tc - sc + d;
      alpha[j] = a;
      mx = fmaxf(mx, a);
    }
    float sum = 0.f;
#pragma unroll
    for (int j = 0; j < 17; ++j) {
      float w = expf(alpha[j] - mx);
      alpha[j] = w;
      sum += w;
    }
    float inv = 1.f / sum;
    float hc = 0.f;
#pragma unroll
    for (int j = 0; j < 17; ++j) {
      int idx = (j < 16) ? nb[j * dil] : n;
      float vc = v[((size_t)(b * NN + idx)) * CC + c];
      hc += alpha[j] * (vc + del[j]);
    }
    ht += hc * inv;
  }

  h[(size_t)bn * CC + c] = ht;
}

// ---------------------------------------------------------------------------
// K5: out[m][0..2] = g[m] @ W2 + b2 + pos[m].  One wave per point.
// ---------------------------------------------------------------------------
__global__ __launch_bounds__(64) void final_kernel(
    const float* __restrict__ g, const float* __restrict__ W2,
    const float* __restrict__ b2, const float* __restrict__ pos,
    float* __restrict__ out) {
  int m = blockIdx.x;
  int k = threadIdx.x;
  float g0 = g[(size_t)m * CC + k];
  float g1 = g[(size_t)m * CC + 64 + k];
  float p0 = g0 * W2[k * 3 + 0] + g1 * W2[(k + 64) * 3 + 0];
  float p1 = g0 * W2[k * 3 + 1] + g1 * W2[(k + 64) * 3 + 1];
  float p2 = g0 * W2[k * 3 + 2] + g1 * W2[(k + 64) * 3 + 2];
#pragma unroll
  for (int off = 32; off >= 1; off >>= 1) {
    p0 += __shfl_down(p0, off);
    p1 += __shfl_down(p1, off);
    p2 += __shfl_down(p2, off);
  }
  if (k == 0) {
    out[m * 3 + 0] = p0 + b2[0] + pos[m * 3 + 0];
    out[m * 3 + 1] = p1 + b2[1] + pos[m * 3 + 1];
    out[m * 3 + 2] = p2 + b2[2] + pos[m * 3 + 2];
  }
}

extern "C" void kernel_launch(void* const* d_in, const int* in_sizes, int n_in,
                              void* d_out, int out_size, void* d_ws, size_t ws_size,
                              hipStream_t stream) {
  const float* x     = (const float*)d_in[0];
  const float* pos   = (const float*)d_in[1];
  const float* W_lin = (const float*)d_in[2];
  const float* W_src = (const float*)d_in[3];
  const float* W_dst = (const float*)d_in[4];
  const float* W_pos = (const float*)d_in[5];
  const float* b_pos = (const float*)d_in[6];
  const float* Wg    = (const float*)d_in[7];
  const float* bg    = (const float*)d_in[8];
  const float* W1    = (const float*)d_in[9];
  const float* b1    = (const float*)d_in[10];
  const float* W2    = (const float*)d_in[11];
  const float* b2    = (const float*)d_in[12];
  float* out = (float*)d_out;

  const size_t M = (size_t)BB * NN;        // 16384
  const size_t MC = M * CC;                // 2,097,152 floats

  // Base layout (proven): nbr 2MB | cand 8MB | fb 64MB.  candk aliases h+g.
  char* ws = (char*)d_ws;
  int* nbr = (int*)ws;
  unsigned short* cand = (unsigned short*)(ws + M * KMAX * sizeof(int));
  float* fb = (float*)(ws + M * KMAX * sizeof(int) + M * CH * KMAX * sizeof(unsigned short));
  float* sb0 = fb + 0 * MC;
  float* sb1 = fb + 1 * MC;
  float* vb0 = fb + 2 * MC;
  float* vb1 = fb + 3 * MC;
  float* tb0 = fb + 4 * MC;
  float* tb1 = fb + 5 * MC;
  float* h   = fb + 6 * MC;
  float* g   = fb + 7 * MC;
  unsigned int* candk = (unsigned int*)h;  // legal: h untouched until Wg (after p2)

  const size_t BASE = M * KMAX * sizeof(int) + M * CH * KMAX * sizeof(unsigned short)
                    + 8 * MC * sizeof(float);                 // 77,594,624
  const size_t XB_BYTES = MC * sizeof(unsigned short);        // 4 MB
  const size_t WF_BYTES = 48 * 256 * 8 * sizeof(unsigned short);  // 192 KB
  bool fused_ok = ws_size >= BASE + XB_BYTES + WF_BYTES;

  if (fused_ok) {
    // xb/wf in dedicated space beyond the base layout: no overlap with cand,
    // so knn_p1 and mfma_proj can run concurrently in one dispatch.
    unsigned short* xb = (unsigned short*)(ws + BASE);
    unsigned short* wf = (unsigned short*)(ws + BASE + XB_BYTES);

    cvt_x<<<MC / 1024, 256, 0, stream>>>(x, xb);
    wcvt<<<48, 256, 0, stream>>>(W_src, W_lin, W_dst, wf);
    // knn_p1 (blocks 0..511, frozen body) + mfma_proj (blocks 512..2047)
    fused_front<<<2048, 256, 0, stream>>>(pos, cand, candk, xb, wf, fb);
    knn_p2<<<256, 64, 0, stream>>>(candk, cand, nbr);
  } else {
    // Fallback: exact R14 sequential path (xb/wf alias cand after knn done).
    unsigned short* xb = cand;
    unsigned short* wf = cand + MC;
    knn_p1<<<512, 256, 0, stream>>>(pos, cand, candk);
    knn_p2<<<256, 64, 0, stream>>>(candk, cand, nbr);
    cvt_x<<<MC / 1024, 256, 0, stream>>>(x, xb);
    wcvt<<<48, 256, 0, stream>>>(W_src, W_lin, W_dst, wf);
    mfma_proj<<<dim3(M / 64, 1, 6), 256, 0, stream>>>(xb, wf, fb);
  }

  // 3. h = leaky(concat(x,pos) @ Wg + bg)   (f32; clobbers candk -> after p2)
  gemm_kernel<<<dim3(M / 64, 1, 1), 256, 0, stream>>>(
      x, CC, CC, pos, 3, CC + 3, Wg, nullptr, nullptr, bg, h, 1);

  // 4. h += attention, both dilations fused (batch-locality swizzle)
  attn2_kernel<<<M, 128, 0, stream>>>(pos, nbr, sb0, vb0, tb0,
                                      sb1, vb1, tb1, W_pos, b_pos, h);

  // 5. g = leaky(h @ W1 + b1)   (f32)
  gemm_kernel<<<dim3(M / 64, 1, 1), 256, 0, stream>>>(
      h, CC, CC, nullptr, 0, CC, W1, nullptr, nullptr, b1, g, 1);

  // 6. out = g @ W2 + b2 + pos
  final_kernel<<<M, 64, 0, stream>>>(g, W2, b2, pos, out);
}

// Round 16
// 277.921 us; speedup vs baseline: 1.7502x; 1.1149x over previous
//
#include <hip/hip_runtime.h>

#define BB 8
#define NN 2048
#define CC 128
#define KMAX 32
#define NEG 0.2f
#define CH 8
#define CHSZ (NN / CH)   // 256
#define CPAD 260         // chunk stride in LDS: (260*c+jj)%32 = (4c+jj)%32 -> 8 distinct banks
#define CAP 32           // per-thread candidate buffer (drain-on-full keeps j order)

using bf16x8 = __attribute__((ext_vector_type(8))) short;  // 8 bf16 (4 VGPRs)
using f32x4  = __attribute__((ext_vector_type(4))) float;  // 4 fp32

// Map f32 to a u32 whose unsigned order == float order (handles negatives).
__device__ __forceinline__ unsigned int f2key(float f) {
  unsigned int b = __float_as_uint(f);
  return (b & 0x80000000u) ? ~b : (b | 0x80000000u);
}

// np-exact f32 squared norm: fl(fl(x^2+y^2)+z^2), no FMA contraction.
__device__ __forceinline__ float sq3(float x, float y, float z) {
  return __fadd_rn(__fadd_rn(__fmul_rn(x, x), __fmul_rn(y, y)), __fmul_rn(z, z));
}

// np-exact f32 distance key: d2 = fl( fl(sq_i+sq_j) - fl(2*dot) ).
__device__ __forceinline__ float d2np(float px, float py, float pz, float sqq,
                                      float qx, float qy, float qz, float sqj) {
  float dot = __fmaf_rn(pz, qz, __fmaf_rn(py, qy, __fmul_rn(px, qx)));
  return __fsub_rn(__fadd_rn(sqq, sqj), __fmul_rn(2.0f, dot));
}

// f32 -> bf16 (round to nearest even), finite inputs.
__device__ __forceinline__ unsigned short f2bf(float f) {
  unsigned int u = __float_as_uint(f);
  return (unsigned short)((u + 0x7fffu + ((u >> 16) & 1u)) >> 16);
}

// ---------------------------------------------------------------------------
// FUSED FRONT: blocks [0,512) = knn_p1 (FROZEN R9 body); blocks [512,2048) =
// mfma_proj (R14 body). Data-independent halves; mfma uses no LDS -> co-
// schedules with knn's VALU/LDS waves (m114).  (R15 verbatim.)
// ---------------------------------------------------------------------------
__global__ __launch_bounds__(256) void fused_front(
    const float* __restrict__ pos,
    unsigned short* __restrict__ cand,
    unsigned int* __restrict__ candk,
    const unsigned short* __restrict__ xb,
    const unsigned short* __restrict__ wf,
    float* __restrict__ outbase) {
  __shared__ float spx[CH * CPAD], spy[CH * CPAD], spz[CH * CPAD], ssq[CH * CPAD];
  __shared__ unsigned int sred[256];
  __shared__ unsigned short sbuf[256 * CAP];

  if (blockIdx.x < 512) {
    // ---------------- knn_p1: FROZEN R9 body. Do not touch. ----------------
    int b = blockIdx.x >> 6;                       // 64 blocks per batch
    int qbase = (blockIdx.x & 63) * 32;
    const float* pb = pos + (size_t)b * NN * 3;
    for (int t = threadIdx.x; t < NN; t += 256) {
      int a = ((t >> 8) * CPAD) + (t & 255);       // padded SoA address of point t
      float x = pb[t * 3 + 0];
      float y = pb[t * 3 + 1];
      float z = pb[t * 3 + 2];
      spx[a] = x; spy[a] = y; spz[a] = z;
      ssq[a] = sq3(x, y, z);
    }
    __syncthreads();

    int q = qbase + (threadIdx.x >> 3);
    int c = threadIdx.x & 7;
    int qa = ((q >> 8) * CPAD) + (q & 255);
    float px = spx[qa], py = spy[qa], pz = spz[qa];
    float sqq = ssq[qa];

    int abase = c * CPAD;
    int j0 = c * CHSZ;

    unsigned int a0 = 0xFFFFFFFFu, a1 = 0xFFFFFFFFu, a2 = 0xFFFFFFFFu, a3 = 0xFFFFFFFFu;
    for (int jj = 0; jj < CHSZ; ++jj) {
      int a = abase + jj;
      int j = j0 + jj;
      float d2 = d2np(px, py, pz, sqq, spx[a], spy[a], spz[a], ssq[a]);
      unsigned int key = f2key(d2);
      if (j == q) key = 0xFFFFFFFFu;
      if (key < a3) {
        bool c3 = key < a2;
        a3 = c3 ? a2 : key;
        bool c2 = key < a1;
        a2 = c3 ? (c2 ? a1 : key) : a2;
        bool c1 = key < a0;
        a1 = c2 ? (c1 ? a0 : key) : a1;
        a0 = c1 ? key : a0;
      }
    }
    sred[threadIdx.x] = a3;
    __syncthreads();
    if (c == 0) {
      unsigned int m = sred[threadIdx.x];
#pragma unroll
      for (int u = 1; u < 8; ++u) {
        unsigned int v = sred[threadIdx.x + u];
        m = v > m ? v : m;
      }
      sred[threadIdx.x] = m;
    }
    __syncthreads();
    unsigned int T = sred[threadIdx.x & ~7];

    unsigned int ak[KMAX];
    int ai[KMAX];
#pragma unroll
    for (int k = 0; k < KMAX; ++k) { ak[k] = 0xFFFFFFFFu; ai[k] = 0xFFFF; }

    int sbase = threadIdx.x * CAP;
    auto drain = [&](int cnt2) {
      for (int u = 0; u < cnt2; ++u) {
        int jj2 = (int)sbuf[sbase + u];
        int a = abase + jj2;
        int j = j0 + jj2;
        float d2 = d2np(px, py, pz, sqq, spx[a], spy[a], spz[a], ssq[a]);
        unsigned int key = f2key(d2);               // self never buffered
        if (key < ak[KMAX - 1]) {                   // strict: stable ties -> lower j
#pragma unroll
          for (int k = KMAX - 1; k >= 1; --k) {
            bool ck  = key < ak[k];
            bool ckm = key < ak[k - 1];
            unsigned int tk = ckm ? ak[k - 1] : key;
            int          ti = ckm ? ai[k - 1] : j;
            ak[k] = ck ? tk : ak[k];
            ai[k] = ck ? ti : ai[k];
          }
          bool c0b = key < ak[0];
          ak[0] = c0b ? key : ak[0];
          ai[0] = c0b ? j : ai[0];
        }
      }
    };

    int cnt = 0;
    for (int jj = 0; jj < CHSZ; ++jj) {
      int a = abase + jj;
      int j = j0 + jj;
      float d2 = d2np(px, py, pz, sqq, spx[a], spy[a], spz[a], ssq[a]);
      unsigned int key = f2key(d2);
      if (j == q) key = 0xFFFFFFFFu;               // self fails gate (T < max)
      if (key <= T) {
        if (cnt == CAP) { drain(CAP); cnt = 0; }   // rare; preserves j order
        sbuf[sbase + cnt] = (unsigned short)jj;
        ++cnt;
      }
    }
    drain(cnt);

    size_t obase = (((size_t)(b * NN + q)) * CH + c) * KMAX;
    unsigned short* oc = cand + obase;
    unsigned int* ok = candk + obase;
#pragma unroll
    for (int k = 0; k < KMAX; ++k) {
      oc[k] = (unsigned short)ai[k];
      ok[k] = ak[k];
    }
  } else {
    // ---------------- mfma_proj: R14 body, remapped block id ----------------
    int bx = blockIdx.x - 512;
    int z = bx >> 8;                               // 0..5
    int mx = bx & 255;
    float* out = outbase + (size_t)z * ((size_t)BB * NN * CC);
    int wave = threadIdx.x >> 6;
    int lane = threadIdx.x & 63;
    int m0 = (mx * 4 + wave) * 16;
    int quad = lane >> 4;
    int am = m0 + (lane & 15);

    f32x4 acc[8];
#pragma unroll
    for (int nt = 0; nt < 8; ++nt) acc[nt] = (f32x4){0.f, 0.f, 0.f, 0.f};

    const unsigned short* wz = wf + (size_t)z * (8 * 4 * 64 * 8);
#pragma unroll
    for (int ks = 0; ks < 4; ++ks) {
      bf16x8 a = *(const bf16x8*)(xb + (size_t)am * CC + ks * 32 + quad * 8);
#pragma unroll
      for (int nt = 0; nt < 8; ++nt) {
        bf16x8 bfr = *(const bf16x8*)(wz + (size_t)(((nt * 4 + ks) * 64 + lane) * 8));
        acc[nt] = __builtin_amdgcn_mfma_f32_16x16x32_bf16(a, bfr, acc[nt], 0, 0, 0);
      }
    }

    int col0 = lane & 15;
#pragma unroll
    for (int nt = 0; nt < 8; ++nt)
#pragma unroll
      for (int r = 0; r < 4; ++r)
        out[(size_t)(m0 + quad * 4 + r) * CC + nt * 16 + col0] = acc[nt][r];
  }
}

// ---------------------------------------------------------------------------
// K1a (fallback path only): knn_p1 standalone — FROZEN R9 bytes.
// ---------------------------------------------------------------------------
__global__ __launch_bounds__(256) void knn_p1(const float* __restrict__ pos,
                                              unsigned short* __restrict__ cand,
                                              unsigned int* __restrict__ candk) {
  __shared__ float spx[CH * CPAD], spy[CH * CPAD], spz[CH * CPAD], ssq[CH * CPAD];
  __shared__ unsigned int sred[256];
  __shared__ unsigned short sbuf[256 * CAP];
  int b = blockIdx.x >> 6;                       // 64 blocks per batch
  int qbase = (blockIdx.x & 63) * 32;
  const float* pb = pos + (size_t)b * NN * 3;
  for (int t = threadIdx.x; t < NN; t += 256) {
    int a = ((t >> 8) * CPAD) + (t & 255);       // padded SoA address of point t
    float x = pb[t * 3 + 0];
    float y = pb[t * 3 + 1];
    float z = pb[t * 3 + 2];
    spx[a] = x; spy[a] = y; spz[a] = z;
    ssq[a] = sq3(x, y, z);
  }
  __syncthreads();

  int q = qbase + (threadIdx.x >> 3);
  int c = threadIdx.x & 7;
  int qa = ((q >> 8) * CPAD) + (q & 255);
  float px = spx[qa], py = spy[qa], pz = spz[qa];
  float sqq = ssq[qa];

  int abase = c * CPAD;
  int j0 = c * CHSZ;

  unsigned int a0 = 0xFFFFFFFFu, a1 = 0xFFFFFFFFu, a2 = 0xFFFFFFFFu, a3 = 0xFFFFFFFFu;
  for (int jj = 0; jj < CHSZ; ++jj) {
    int a = abase + jj;
    int j = j0 + jj;
    float d2 = d2np(px, py, pz, sqq, spx[a], spy[a], spz[a], ssq[a]);
    unsigned int key = f2key(d2);
    if (j == q) key = 0xFFFFFFFFu;
    if (key < a3) {
      bool c3 = key < a2;
      a3 = c3 ? a2 : key;
      bool c2 = key < a1;
      a2 = c3 ? (c2 ? a1 : key) : a2;
      bool c1 = key < a0;
      a1 = c2 ? (c1 ? a0 : key) : a1;
      a0 = c1 ? key : a0;
    }
  }
  sred[threadIdx.x] = a3;
  __syncthreads();
  if (c == 0) {
    unsigned int m = sred[threadIdx.x];
#pragma unroll
    for (int u = 1; u < 8; ++u) {
      unsigned int v = sred[threadIdx.x + u];
      m = v > m ? v : m;
    }
    sred[threadIdx.x] = m;
  }
  __syncthreads();
  unsigned int T = sred[threadIdx.x & ~7];

  unsigned int ak[KMAX];
  int ai[KMAX];
#pragma unroll
  for (int k = 0; k < KMAX; ++k) { ak[k] = 0xFFFFFFFFu; ai[k] = 0xFFFF; }

  int sbase = threadIdx.x * CAP;
  auto drain = [&](int cnt2) {
    for (int u = 0; u < cnt2; ++u) {
      int jj2 = (int)sbuf[sbase + u];
      int a = abase + jj2;
      int j = j0 + jj2;
      float d2 = d2np(px, py, pz, sqq, spx[a], spy[a], spz[a], ssq[a]);
      unsigned int key = f2key(d2);               // self never buffered
      if (key < ak[KMAX - 1]) {                   // strict: stable ties -> lower j
#pragma unroll
        for (int k = KMAX - 1; k >= 1; --k) {
          bool ck  = key < ak[k];
          bool ckm = key < ak[k - 1];
          unsigned int tk = ckm ? ak[k - 1] : key;
          int          ti = ckm ? ai[k - 1] : j;
          ak[k] = ck ? tk : ak[k];
          ai[k] = ck ? ti : ai[k];
        }
        bool c0b = key < ak[0];
        ak[0] = c0b ? key : ak[0];
        ai[0] = c0b ? j : ai[0];
      }
    }
  };

  int cnt = 0;
  for (int jj = 0; jj < CHSZ; ++jj) {
    int a = abase + jj;
    int j = j0 + jj;
    float d2 = d2np(px, py, pz, sqq, spx[a], spy[a], spz[a], ssq[a]);
    unsigned int key = f2key(d2);
    if (j == q) key = 0xFFFFFFFFu;               // self fails gate (T < max)
    if (key <= T) {
      if (cnt == CAP) { drain(CAP); cnt = 0; }   // rare; preserves j order
      sbuf[sbase + cnt] = (unsigned short)jj;
      ++cnt;
    }
  }
  drain(cnt);

  size_t obase = (((size_t)(b * NN + q)) * CH + c) * KMAX;
  unsigned short* oc = cand + obase;
  unsigned int* ok = candk + obase;
#pragma unroll
  for (int k = 0; k < KMAX; ++k) {
    oc[k] = (unsigned short)ai[k];
    ok[k] = ak[k];
  }
}

// ---------------------------------------------------------------------------
// K1b: KNN phase 2 — 8-way merge. FROZEN R9 bytes.
// ---------------------------------------------------------------------------
__global__ __launch_bounds__(64) void knn_p2(const unsigned int* __restrict__ candk,
                                             const unsigned short* __restrict__ cand,
                                             int* __restrict__ nbr) {
  int q = blockIdx.x * 64 + threadIdx.x;         // global query id (b*NN+n)
  const unsigned int* k8 = candk + (size_t)q * (CH * KMAX);
  const unsigned short* i8 = cand + (size_t)q * (CH * KMAX);

  int head[CH];
  unsigned int hk[CH];
#pragma unroll
  for (int c = 0; c < CH; ++c) {
    head[c] = 0;
    hk[c] = k8[c * KMAX];
  }

  int* onb = nbr + (size_t)q * KMAX;
#pragma unroll
  for (int r = 0; r < KMAX; ++r) {
    int bc = 0;
    unsigned int bk = hk[0];
#pragma unroll
    for (int c = 1; c < CH; ++c) {
      if (hk[c] < bk) { bk = hk[c]; bc = c; }    // strict: ties -> lower c = lower j
    }
    onb[r] = (int)i8[bc * KMAX + head[bc]];
    ++head[bc];
    hk[bc] = (head[bc] < KMAX) ? k8[bc * KMAX + head[bc]] : 0xFFFFFFFFu;
  }
}

// ---------------------------------------------------------------------------
// K-cvt: f32 (len = gridDim*1024) -> bf16. Used for x->xb and h->hb.
// ---------------------------------------------------------------------------
__global__ __launch_bounds__(256) void cvt_x(const float* __restrict__ x,
                                             unsigned short* __restrict__ xb) {
  int t = blockIdx.x * 256 + threadIdx.x;
  float4 v = *(const float4*)(x + (size_t)t * 4);
  unsigned short o[4] = {f2bf(v.x), f2bf(v.y), f2bf(v.z), f2bf(v.w)};
  *(ushort2*)(xb + (size_t)t * 4 + 0) = make_ushort2(o[0], o[1]);
  *(ushort2*)(xb + (size_t)t * 4 + 2) = make_ushort2(o[2], o[3]);
}

// ---------------------------------------------------------------------------
// K-wcvt: 8 weight matrices (f32) -> bf16 B-fragment order.
// z=0..5: W_src[0,1], W_lin[0,1], W_dst[0,1]; z=6: Wg rows 0..127; z=7: W1.
// Grid 64 x 256.
// ---------------------------------------------------------------------------
__global__ __launch_bounds__(256) void wcvt(const float* __restrict__ Wa,
                                            const float* __restrict__ Wb,
                                            const float* __restrict__ Wc,
                                            const float* __restrict__ Wgm,
                                            const float* __restrict__ W1m,
                                            unsigned short* __restrict__ wf) {
  int t = blockIdx.x * 256 + threadIdx.x;        // 0 .. 16383
  int lane = t & 63;
  int ks = (t >> 6) & 3;
  int nt = (t >> 8) & 7;
  int z = t >> 11;
  const float* W = (z < 2) ? (Wa + (size_t)z * CC * CC)
                 : (z < 4) ? (Wb + (size_t)(z - 2) * CC * CC)
                 : (z < 6) ? (Wc + (size_t)(z - 4) * CC * CC)
                 : (z == 6) ? Wgm : W1m;
  int n = nt * 16 + (lane & 15);
  int kb = ks * 32 + (lane >> 4) * 8;
  unsigned short* o = wf + (size_t)t * 8;
#pragma unroll
  for (int j = 0; j < 8; ++j)
    o[j] = f2bf(W[(size_t)(kb + j) * CC + n]);
}

// ---------------------------------------------------------------------------
// K2-epi: single bf16 MFMA GEMM (R14 structure) + epilogue:
// v = acc + bias[col] (+ pos[m]·wgtail[:,col] if wgtail) ; leaky ; store.
// Used for Wg (wgtail = Wg rows 128..130, posf = pos) and W1 (wgtail null).
// Grid M/64 x 256.
// ---------------------------------------------------------------------------
__global__ __launch_bounds__(256) void mfma_epi(const unsigned short* __restrict__ ain,
                                                const unsigned short* __restrict__ wz,
                                                const float* __restrict__ bias,
                                                const float* __restrict__ wgtail,
                                                const float* __restrict__ posf,
                                                float* __restrict__ out) {
  int wave = threadIdx.x >> 6;
  int lane = threadIdx.x & 63;
  int m0 = (blockIdx.x * 4 + wave) * 16;
  int quad = lane >> 4;
  int am = m0 + (lane & 15);

  f32x4 acc[8];
#pragma unroll
  for (int nt = 0; nt < 8; ++nt) acc[nt] = (f32x4){0.f, 0.f, 0.f, 0.f};

#pragma unroll
  for (int ks = 0; ks < 4; ++ks) {
    bf16x8 a = *(const bf16x8*)(ain + (size_t)am * CC + ks * 32 + quad * 8);
#pragma unroll
    for (int nt = 0; nt < 8; ++nt) {
      bf16x8 b = *(const bf16x8*)(wz + (size_t)(((nt * 4 + ks) * 64 + lane) * 8));
      acc[nt] = __builtin_amdgcn_mfma_f32_16x16x32_bf16(a, b, acc[nt], 0, 0, 0);
    }
  }

  float posr[4][3];
  if (wgtail) {
#pragma unroll
    for (int r = 0; r < 4; ++r) {
      int m = m0 + quad * 4 + r;
      posr[r][0] = posf[m * 3 + 0];
      posr[r][1] = posf[m * 3 + 1];
      posr[r][2] = posf[m * 3 + 2];
    }
  }

  int col0 = lane & 15;
#pragma unroll
  for (int nt = 0; nt < 8; ++nt) {
    int col = nt * 16 + col0;
    float bv = bias[col];
    float t0 = 0.f, t1 = 0.f, t2 = 0.f;
    if (wgtail) {
      t0 = wgtail[col];
      t1 = wgtail[CC + col];
      t2 = wgtail[2 * CC + col];
    }
#pragma unroll
    for (int r = 0; r < 4; ++r) {
      float v = acc[nt][r] + bv;
      if (wgtail)
        v += posr[r][0] * t0 + posr[r][1] * t1 + posr[r][2] * t2;
      v = v > 0.f ? v : NEG * v;
      out[(size_t)(m0 + quad * 4 + r) * CC + col] = v;
    }
  }
}

// ---------------------------------------------------------------------------
// K2-mfma (fallback path only): R14 standalone mfma_proj.
// ---------------------------------------------------------------------------
__global__ __launch_bounds__(256) void mfma_proj(const unsigned short* __restrict__ xb,
                                                 const unsigned short* __restrict__ wf,
                                                 float* __restrict__ outbase) {
  int z = blockIdx.z;
  float* out = outbase + (size_t)z * ((size_t)BB * NN * CC);
  int wave = threadIdx.x >> 6;
  int lane = threadIdx.x & 63;
  int m0 = (blockIdx.x * 4 + wave) * 16;
  int quad = lane >> 4;
  int am = m0 + (lane & 15);

  f32x4 acc[8];
#pragma unroll
  for (int nt = 0; nt < 8; ++nt) acc[nt] = (f32x4){0.f, 0.f, 0.f, 0.f};

  const unsigned short* wz = wf + (size_t)z * (8 * 4 * 64 * 8);
#pragma unroll
  for (int ks = 0; ks < 4; ++ks) {
    bf16x8 a = *(const bf16x8*)(xb + (size_t)am * CC + ks * 32 + quad * 8);
#pragma unroll
    for (int nt = 0; nt < 8; ++nt) {
      bf16x8 b = *(const bf16x8*)(wz + (size_t)(((nt * 4 + ks) * 64 + lane) * 8));
      acc[nt] = __builtin_amdgcn_mfma_f32_16x16x32_bf16(a, b, acc[nt], 0, 0, 0);
    }
  }

  int col0 = lane & 15;
#pragma unroll
  for (int nt = 0; nt < 8; ++nt)
#pragma unroll
    for (int r = 0; r < 4; ++r)
      out[(size_t)(m0 + quad * 4 + r) * CC + nt * 16 + col0] = acc[nt][r];
}

// ---------------------------------------------------------------------------
// K2: f32 tiled GEMM (fallback path only — Wg and W1).
// ---------------------------------------------------------------------------
__global__ __launch_bounds__(256) void gemm_kernel(
    const float* __restrict__ A1, int lda1, int K1,
    const float* __restrict__ A2, int lda2, int K,
    const float* __restrict__ Wa, const float* __restrict__ Wb,
    const float* __restrict__ Wc, const float* __restrict__ bias,
    float* __restrict__ outbase, int applyLeaky) {
  __shared__ float At[8][64];
  __shared__ float Wt[8][CC];

  int z = blockIdx.z;
  const float* W = (z < 2) ? (Wa + (size_t)z * CC * CC)
                 : (z < 4) ? (Wb + (size_t)(z - 2) * CC * CC)
                           : (Wc + (size_t)(z - 4) * CC * CC);
  float* out = outbase + (size_t)z * ((size_t)BB * NN * CC);

  int m0 = blockIdx.x * 64;
  int tid = threadIdx.x;
  int cg = tid & 31;
  int rg = tid >> 5;

  float acc[8][4];
#pragma unroll
  for (int r = 0; r < 8; ++r)
#pragma unroll
    for (int q = 0; q < 4; ++q) acc[r][q] = 0.f;

  int ksteps = (K + 7) >> 3;
  for (int ks = 0; ks < ksteps; ++ks) {
    int k0 = ks << 3;
    __syncthreads();
    {
      int f = tid * 2;
      int m = f >> 3;
      int kk = f & 7;
      int gm = m0 + m;
#pragma unroll
      for (int u = 0; u < 2; ++u) {
        int k = k0 + kk + u;
        float v = 0.f;
        if (k < K1) v = A1[(size_t)gm * lda1 + k];
        else if (k < K) v = A2[(size_t)gm * lda2 + (k - K1)];
        At[kk + u][m] = v;
      }
    }
    {
      int kk = tid >> 5;
      int c = (tid & 31) * 4;
      int k = k0 + kk;
      float4 w = make_float4(0.f, 0.f, 0.f, 0.f);
      if (k < K) w = *(const float4*)(W + (size_t)k * CC + c);
      *(float4*)(&Wt[kk][c]) = w;
    }
    __syncthreads();
#pragma unroll
    for (int kk = 0; kk < 8; ++kk) {
      float4 a0 = *(const float4*)(&At[kk][rg * 8]);
      float4 a1 = *(const float4*)(&At[kk][rg * 8 + 4]);
      float4 w = *(const float4*)(&Wt[kk][cg * 4]);
      float a[8] = {a0.x, a0.y, a0.z, a0.w, a1.x, a1.y, a1.z, a1.w};
#pragma unroll
      for (int r = 0; r < 8; ++r) {
        acc[r][0] += a[r] * w.x;
        acc[r][1] += a[r] * w.y;
        acc[r][2] += a[r] * w.z;
        acc[r][3] += a[r] * w.w;
      }
    }
  }

#pragma unroll
  for (int r = 0; r < 8; ++r) {
    int m = m0 + rg * 8 + r;
#pragma unroll
    for (int q = 0; q < 4; ++q) {
      int c = cg * 4 + q;
      float v = acc[r][q];
      if (bias) v += bias[c];
      if (applyLeaky) v = v > 0.f ? v : NEG * v;
      out[(size_t)m * CC + c] = v;
    }
  }
}

// ---------------------------------------------------------------------------
// K3: fused attention — both dilations, batch-locality swizzle (R13 WIN).
// ---------------------------------------------------------------------------
__global__ __launch_bounds__(128) void attn2_kernel(
    const float* __restrict__ pos, const int* __restrict__ nbr,
    const float* __restrict__ s0, const float* __restrict__ v0,
    const float* __restrict__ t0,
    const float* __restrict__ s1, const float* __restrict__ v1,
    const float* __restrict__ t1,
    const float* __restrict__ Wpos, const float* __restrict__ bpos,
    float* __restrict__ h) {
  int b = blockIdx.x & 7;                        // XCD-locality swizzle
  int n = blockIdx.x >> 3;
  int bn = (b << 11) + n;
  int c = threadIdx.x;

  const float* pb = pos + (size_t)b * NN * 3;
  float pix = pb[n * 3 + 0], piy = pb[n * 3 + 1], piz = pb[n * 3 + 2];
  const int* nb = nbr + (size_t)bn * KMAX;

  float ht = h[(size_t)bn * CC + c];             // h_in (Wg output)

#pragma unroll
  for (int l = 0; l < 2; ++l) {
    int dil = l + 1;
    const float* s = l ? s1 : s0;
    const float* v = l ? v1 : v0;
    const float* t = l ? t1 : t0;
    const float* Wp = Wpos + (size_t)l * 3 * CC;
    float w0 = Wp[c], w1 = Wp[CC + c], w2 = Wp[2 * CC + c];
    float bp = bpos[(size_t)l * CC + c];
    float tc = t[(size_t)bn * CC + c];

    float alpha[17], del[17];
    float mx = -1e30f;
#pragma unroll
    for (int j = 0; j < 17; ++j) {
      int idx = (j < 16) ? nb[j * dil] : n;
      float dx = pix - pb[idx * 3 + 0];
      float dy = piy - pb[idx * 3 + 1];
      float dz = piz - pb[idx * 3 + 2];
      float d = dx * w0 + dy * w1 + dz * w2 + bp;
      del[j] = d;
      float sc = s[((size_t)(b * NN + idx)) * CC + c];
      float a = tc - sc + d;
      alpha[j] = a;
      mx = fmaxf(mx, a);
    }
    float sum = 0.f;
#pragma unroll
    for (int j = 0; j < 17; ++j) {
      float w = expf(alpha[j] - mx);
      alpha[j] = w;
      sum += w;
    }
    float inv = 1.f / sum;
    float hc = 0.f;
#pragma unroll
    for (int j = 0; j < 17; ++j) {
      int idx = (j < 16) ? nb[j * dil] : n;
      float vc = v[((size_t)(b * NN + idx)) * CC + c];
      hc += alpha[j] * (vc + del[j]);
    }
    ht += hc * inv;
  }

  h[(size_t)bn * CC + c] = ht;
}

// ---------------------------------------------------------------------------
// K5: out[m][0..2] = g[m] @ W2 + b2 + pos[m].  One wave per point.
// ---------------------------------------------------------------------------
__global__ __launch_bounds__(64) void final_kernel(
    const float* __restrict__ g, const float* __restrict__ W2,
    const float* __restrict__ b2, const float* __restrict__ pos,
    float* __restrict__ out) {
  int m = blockIdx.x;
  int k = threadIdx.x;
  float g0 = g[(size_t)m * CC + k];
  float g1 = g[(size_t)m * CC + 64 + k];
  float p0 = g0 * W2[k * 3 + 0] + g1 * W2[(k + 64) * 3 + 0];
  float p1 = g0 * W2[k * 3 + 1] + g1 * W2[(k + 64) * 3 + 1];
  float p2 = g0 * W2[k * 3 + 2] + g1 * W2[(k + 64) * 3 + 2];
#pragma unroll
  for (int off = 32; off >= 1; off >>= 1) {
    p0 += __shfl_down(p0, off);
    p1 += __shfl_down(p1, off);
    p2 += __shfl_down(p2, off);
  }
  if (k == 0) {
    out[m * 3 + 0] = p0 + b2[0] + pos[m * 3 + 0];
    out[m * 3 + 1] = p1 + b2[1] + pos[m * 3 + 1];
    out[m * 3 + 2] = p2 + b2[2] + pos[m * 3 + 2];
  }
}

extern "C" void kernel_launch(void* const* d_in, const int* in_sizes, int n_in,
                              void* d_out, int out_size, void* d_ws, size_t ws_size,
                              hipStream_t stream) {
  const float* x     = (const float*)d_in[0];
  const float* pos   = (const float*)d_in[1];
  const float* W_lin = (const float*)d_in[2];
  const float* W_src = (const float*)d_in[3];
  const float* W_dst = (const float*)d_in[4];
  const float* W_pos = (const float*)d_in[5];
  const float* b_pos = (const float*)d_in[6];
  const float* Wg    = (const float*)d_in[7];
  const float* bg    = (const float*)d_in[8];
  const float* W1    = (const float*)d_in[9];
  const float* b1    = (const float*)d_in[10];
  const float* W2    = (const float*)d_in[11];
  const float* b2    = (const float*)d_in[12];
  float* out = (float*)d_out;

  const size_t M = (size_t)BB * NN;        // 16384
  const size_t MC = M * CC;                // 2,097,152 floats

  // Base layout (proven): nbr 2MB | cand 8MB | fb 64MB.  candk aliases h+g.
  char* ws = (char*)d_ws;
  int* nbr = (int*)ws;
  unsigned short* cand = (unsigned short*)(ws + M * KMAX * sizeof(int));
  float* fb = (float*)(ws + M * KMAX * sizeof(int) + M * CH * KMAX * sizeof(unsigned short));
  float* sb0 = fb + 0 * MC;
  float* sb1 = fb + 1 * MC;
  float* vb0 = fb + 2 * MC;
  float* vb1 = fb + 3 * MC;
  float* tb0 = fb + 4 * MC;
  float* tb1 = fb + 5 * MC;
  float* h   = fb + 6 * MC;
  float* g   = fb + 7 * MC;
  unsigned int* candk = (unsigned int*)h;  // legal: h untouched until Wg-mfma (after p2)

  const size_t BASE = M * KMAX * sizeof(int) + M * CH * KMAX * sizeof(unsigned short)
                    + 8 * MC * sizeof(float);                 // 77,594,624
  const size_t XB_BYTES = MC * sizeof(unsigned short);        // 4 MB
  const size_t WF_BYTES = 8 * 16384 * sizeof(unsigned short); // 256 KB (8 weights)
  const size_t FRAG = (size_t)(8 * 4 * 64 * 8);               // bf16 elems per weight
  bool fused_ok = ws_size >= BASE + XB_BYTES + WF_BYTES;

  if (fused_ok) {
    unsigned short* xb = (unsigned short*)(ws + BASE);
    unsigned short* wf = (unsigned short*)(ws + BASE + XB_BYTES);
    unsigned short* hb = xb;   // reuse xb region for bf16(h): xb dead after Wg-mfma

    cvt_x<<<MC / 1024, 256, 0, stream>>>(x, xb);
    wcvt<<<64, 256, 0, stream>>>(W_src, W_lin, W_dst, Wg, W1, wf);
    // knn_p1 (blocks 0..511, frozen body) + 6-proj mfma (blocks 512..2047)
    fused_front<<<2048, 256, 0, stream>>>(pos, cand, candk, xb, wf, fb);
    knn_p2<<<256, 64, 0, stream>>>(candk, cand, nbr);

    // h = leaky(x@Wg[0:128] + pos·Wg[128:131] + bg)  -- bf16 MFMA + f32 tail
    mfma_epi<<<M / 64, 256, 0, stream>>>(xb, wf + 6 * FRAG, bg,
                                         Wg + 128 * CC, pos, h);

    // h += attention, both dilations fused (batch-locality swizzle)
    attn2_kernel<<<M, 128, 0, stream>>>(pos, nbr, sb0, vb0, tb0,
                                        sb1, vb1, tb1, W_pos, b_pos, h);

    // g = leaky(h@W1 + b1)  -- bf16 MFMA
    cvt_x<<<MC / 1024, 256, 0, stream>>>(h, hb);
    mfma_epi<<<M / 64, 256, 0, stream>>>(hb, wf + 7 * FRAG, b1,
                                         nullptr, nullptr, g);

    final_kernel<<<M, 64, 0, stream>>>(g, W2, b2, pos, out);
  } else {
    // Fallback: R14-style sequential path with f32 Wg/W1 GEMMs.
    unsigned short* xb = cand;
    unsigned short* wf = cand + MC;
    knn_p1<<<512, 256, 0, stream>>>(pos, cand, candk);
    knn_p2<<<256, 64, 0, stream>>>(candk, cand, nbr);
    cvt_x<<<MC / 1024, 256, 0, stream>>>(x, xb);
    wcvt<<<64, 256, 0, stream>>>(W_src, W_lin, W_dst, Wg, W1, wf);
    mfma_proj<<<dim3(M / 64, 1, 6), 256, 0, stream>>>(xb, wf, fb);
    gemm_kernel<<<dim3(M / 64, 1, 1), 256, 0, stream>>>(
        x, CC, CC, pos, 3, CC + 3, Wg, nullptr, nullptr, bg, h, 1);
    attn2_kernel<<<M, 128, 0, stream>>>(pos, nbr, sb0, vb0, tb0,
                                        sb1, vb1, tb1, W_pos, b_pos, h);
    gemm_kernel<<<dim3(M / 64, 1, 1), 256, 0, stream>>>(
        h, CC, CC, nullptr, 0, CC, W1, nullptr, nullptr, b1, g, 1);
    final_kernel<<<M, 64, 0, stream>>>(g, W2, b2, pos, out);
  }
}

// Round 17
// 259.479 us; speedup vs baseline: 1.8746x; 1.0711x over previous
//
#include <hip/hip_runtime.h>

#define BB 8
#define NN 2048
#define CC 128
#define KMAX 32
#define NEG 0.2f
#define CH 8
#define CHSZ (NN / CH)   // 256
#define CPAD 260         // chunk stride in LDS: (260*c+jj)%32 = (4c+jj)%32 -> 8 distinct banks
#define CAP 32           // per-thread candidate buffer (drain-on-full keeps j order)

using bf16x8 = __attribute__((ext_vector_type(8))) short;  // 8 bf16 (4 VGPRs)
using f32x4  = __attribute__((ext_vector_type(4))) float;  // 4 fp32

// Map f32 to a u32 whose unsigned order == float order (handles negatives).
__device__ __forceinline__ unsigned int f2key(float f) {
  unsigned int b = __float_as_uint(f);
  return (b & 0x80000000u) ? ~b : (b | 0x80000000u);
}

// np-exact f32 squared norm: fl(fl(x^2+y^2)+z^2), no FMA contraction.
__device__ __forceinline__ float sq3(float x, float y, float z) {
  return __fadd_rn(__fadd_rn(__fmul_rn(x, x), __fmul_rn(y, y)), __fmul_rn(z, z));
}

// np-exact f32 distance key: d2 = fl( fl(sq_i+sq_j) - fl(2*dot) ).
__device__ __forceinline__ float d2np(float px, float py, float pz, float sqq,
                                      float qx, float qy, float qz, float sqj) {
  float dot = __fmaf_rn(pz, qz, __fmaf_rn(py, qy, __fmul_rn(px, qx)));
  return __fsub_rn(__fadd_rn(sqq, sqj), __fmul_rn(2.0f, dot));
}

// f32 -> bf16 (round to nearest even), finite inputs.
__device__ __forceinline__ unsigned short f2bf(float f) {
  unsigned int u = __float_as_uint(f);
  return (unsigned short)((u + 0x7fffu + ((u >> 16) & 1u)) >> 16);
}
// bf16 -> f32, exact.
__device__ __forceinline__ float bf2f(unsigned short u) {
  return __uint_as_float(((unsigned int)u) << 16);
}

// ---------------------------------------------------------------------------
// FUSED FRONT: blocks [0,512) = knn_p1 (FROZEN R9 body); blocks [512,2048) =
// 6-projection bf16 MFMA (R14 body, bf16 epilogue); blocks [2048,2304) =
// Wg epilogue MFMA (h = leaky(x@Wg[0:128] + pos·Wg[128:131] + bg), f32 out).
// All three are data-independent: knn writes cand+candk(fb[3MC..5MC)),
// proj writes projb(fb[0..3MC) as bf16), Wg-epi writes h(fb[5MC..6MC)).
// ---------------------------------------------------------------------------
__global__ __launch_bounds__(256) void fused_front(
    const float* __restrict__ pos,
    unsigned short* __restrict__ cand,
    unsigned int* __restrict__ candk,
    const unsigned short* __restrict__ xb,
    const unsigned short* __restrict__ wf,
    unsigned short* __restrict__ projb,
    const float* __restrict__ wgtail,
    const float* __restrict__ bg,
    float* __restrict__ h) {
  __shared__ float spx[CH * CPAD], spy[CH * CPAD], spz[CH * CPAD], ssq[CH * CPAD];
  __shared__ unsigned int sred[256];
  __shared__ unsigned short sbuf[256 * CAP];

  if (blockIdx.x < 512) {
    // ---------------- knn_p1: FROZEN R9 body. Do not touch. ----------------
    int b = blockIdx.x >> 6;                       // 64 blocks per batch
    int qbase = (blockIdx.x & 63) * 32;
    const float* pb = pos + (size_t)b * NN * 3;
    for (int t = threadIdx.x; t < NN; t += 256) {
      int a = ((t >> 8) * CPAD) + (t & 255);       // padded SoA address of point t
      float x = pb[t * 3 + 0];
      float y = pb[t * 3 + 1];
      float z = pb[t * 3 + 2];
      spx[a] = x; spy[a] = y; spz[a] = z;
      ssq[a] = sq3(x, y, z);
    }
    __syncthreads();

    int q = qbase + (threadIdx.x >> 3);
    int c = threadIdx.x & 7;
    int qa = ((q >> 8) * CPAD) + (q & 255);
    float px = spx[qa], py = spy[qa], pz = spz[qa];
    float sqq = ssq[qa];

    int abase = c * CPAD;
    int j0 = c * CHSZ;

    unsigned int a0 = 0xFFFFFFFFu, a1 = 0xFFFFFFFFu, a2 = 0xFFFFFFFFu, a3 = 0xFFFFFFFFu;
    for (int jj = 0; jj < CHSZ; ++jj) {
      int a = abase + jj;
      int j = j0 + jj;
      float d2 = d2np(px, py, pz, sqq, spx[a], spy[a], spz[a], ssq[a]);
      unsigned int key = f2key(d2);
      if (j == q) key = 0xFFFFFFFFu;
      if (key < a3) {
        bool c3 = key < a2;
        a3 = c3 ? a2 : key;
        bool c2 = key < a1;
        a2 = c3 ? (c2 ? a1 : key) : a2;
        bool c1 = key < a0;
        a1 = c2 ? (c1 ? a0 : key) : a1;
        a0 = c1 ? key : a0;
      }
    }
    sred[threadIdx.x] = a3;
    __syncthreads();
    if (c == 0) {
      unsigned int m = sred[threadIdx.x];
#pragma unroll
      for (int u = 1; u < 8; ++u) {
        unsigned int v = sred[threadIdx.x + u];
        m = v > m ? v : m;
      }
      sred[threadIdx.x] = m;
    }
    __syncthreads();
    unsigned int T = sred[threadIdx.x & ~7];

    unsigned int ak[KMAX];
    int ai[KMAX];
#pragma unroll
    for (int k = 0; k < KMAX; ++k) { ak[k] = 0xFFFFFFFFu; ai[k] = 0xFFFF; }

    int sbase = threadIdx.x * CAP;
    auto drain = [&](int cnt2) {
      for (int u = 0; u < cnt2; ++u) {
        int jj2 = (int)sbuf[sbase + u];
        int a = abase + jj2;
        int j = j0 + jj2;
        float d2 = d2np(px, py, pz, sqq, spx[a], spy[a], spz[a], ssq[a]);
        unsigned int key = f2key(d2);               // self never buffered
        if (key < ak[KMAX - 1]) {                   // strict: stable ties -> lower j
#pragma unroll
          for (int k = KMAX - 1; k >= 1; --k) {
            bool ck  = key < ak[k];
            bool ckm = key < ak[k - 1];
            unsigned int tk = ckm ? ak[k - 1] : key;
            int          ti = ckm ? ai[k - 1] : j;
            ak[k] = ck ? tk : ak[k];
            ai[k] = ck ? ti : ai[k];
          }
          bool c0b = key < ak[0];
          ak[0] = c0b ? key : ak[0];
          ai[0] = c0b ? j : ai[0];
        }
      }
    };

    int cnt = 0;
    for (int jj = 0; jj < CHSZ; ++jj) {
      int a = abase + jj;
      int j = j0 + jj;
      float d2 = d2np(px, py, pz, sqq, spx[a], spy[a], spz[a], ssq[a]);
      unsigned int key = f2key(d2);
      if (j == q) key = 0xFFFFFFFFu;               // self fails gate (T < max)
      if (key <= T) {
        if (cnt == CAP) { drain(CAP); cnt = 0; }   // rare; preserves j order
        sbuf[sbase + cnt] = (unsigned short)jj;
        ++cnt;
      }
    }
    drain(cnt);

    size_t obase = (((size_t)(b * NN + q)) * CH + c) * KMAX;
    unsigned short* oc = cand + obase;
    unsigned int* ok = candk + obase;
#pragma unroll
    for (int k = 0; k < KMAX; ++k) {
      oc[k] = (unsigned short)ai[k];
      ok[k] = ak[k];
    }
  } else if (blockIdx.x < 2048) {
    // ------------- 6-proj bf16 MFMA (R14 body, bf16 epilogue) -------------
    int bx = blockIdx.x - 512;
    int z = bx >> 8;                               // 0..5
    int mx = bx & 255;
    unsigned short* out = projb + (size_t)z * ((size_t)BB * NN * CC);
    int wave = threadIdx.x >> 6;
    int lane = threadIdx.x & 63;
    int m0 = (mx * 4 + wave) * 16;
    int quad = lane >> 4;
    int am = m0 + (lane & 15);

    f32x4 acc[8];
#pragma unroll
    for (int nt = 0; nt < 8; ++nt) acc[nt] = (f32x4){0.f, 0.f, 0.f, 0.f};

    const unsigned short* wz = wf + (size_t)z * (8 * 4 * 64 * 8);
#pragma unroll
    for (int ks = 0; ks < 4; ++ks) {
      bf16x8 a = *(const bf16x8*)(xb + (size_t)am * CC + ks * 32 + quad * 8);
#pragma unroll
      for (int nt = 0; nt < 8; ++nt) {
        bf16x8 bfr = *(const bf16x8*)(wz + (size_t)(((nt * 4 + ks) * 64 + lane) * 8));
        acc[nt] = __builtin_amdgcn_mfma_f32_16x16x32_bf16(a, bfr, acc[nt], 0, 0, 0);
      }
    }

    int col0 = lane & 15;
#pragma unroll
    for (int nt = 0; nt < 8; ++nt)
#pragma unroll
      for (int r = 0; r < 4; ++r)
        out[(size_t)(m0 + quad * 4 + r) * CC + nt * 16 + col0] = f2bf(acc[nt][r]);
  } else {
    // ------------- Wg epilogue MFMA (R16 mfma_epi body, f32 out) ----------
    int mx = blockIdx.x - 2048;                    // 0..255
    int wave = threadIdx.x >> 6;
    int lane = threadIdx.x & 63;
    int m0 = (mx * 4 + wave) * 16;
    int quad = lane >> 4;
    int am = m0 + (lane & 15);

    f32x4 acc[8];
#pragma unroll
    for (int nt = 0; nt < 8; ++nt) acc[nt] = (f32x4){0.f, 0.f, 0.f, 0.f};

    const unsigned short* wz = wf + (size_t)6 * (8 * 4 * 64 * 8);
#pragma unroll
    for (int ks = 0; ks < 4; ++ks) {
      bf16x8 a = *(const bf16x8*)(xb + (size_t)am * CC + ks * 32 + quad * 8);
#pragma unroll
      for (int nt = 0; nt < 8; ++nt) {
        bf16x8 b = *(const bf16x8*)(wz + (size_t)(((nt * 4 + ks) * 64 + lane) * 8));
        acc[nt] = __builtin_amdgcn_mfma_f32_16x16x32_bf16(a, b, acc[nt], 0, 0, 0);
      }
    }

    float posr[4][3];
#pragma unroll
    for (int r = 0; r < 4; ++r) {
      int m = m0 + quad * 4 + r;
      posr[r][0] = pos[m * 3 + 0];
      posr[r][1] = pos[m * 3 + 1];
      posr[r][2] = pos[m * 3 + 2];
    }

    int col0 = lane & 15;
#pragma unroll
    for (int nt = 0; nt < 8; ++nt) {
      int col = nt * 16 + col0;
      float bv = bg[col];
      float t0 = wgtail[col];
      float t1 = wgtail[CC + col];
      float t2 = wgtail[2 * CC + col];
#pragma unroll
      for (int r = 0; r < 4; ++r) {
        float v = acc[nt][r] + bv
                + posr[r][0] * t0 + posr[r][1] * t1 + posr[r][2] * t2;
        v = v > 0.f ? v : NEG * v;
        h[(size_t)(m0 + quad * 4 + r) * CC + col] = v;
      }
    }
  }
}

// ---------------------------------------------------------------------------
// K1a (fallback path only): knn_p1 standalone — FROZEN R9 bytes.
// ---------------------------------------------------------------------------
__global__ __launch_bounds__(256) void knn_p1(const float* __restrict__ pos,
                                              unsigned short* __restrict__ cand,
                                              unsigned int* __restrict__ candk) {
  __shared__ float spx[CH * CPAD], spy[CH * CPAD], spz[CH * CPAD], ssq[CH * CPAD];
  __shared__ unsigned int sred[256];
  __shared__ unsigned short sbuf[256 * CAP];
  int b = blockIdx.x >> 6;                       // 64 blocks per batch
  int qbase = (blockIdx.x & 63) * 32;
  const float* pb = pos + (size_t)b * NN * 3;
  for (int t = threadIdx.x; t < NN; t += 256) {
    int a = ((t >> 8) * CPAD) + (t & 255);       // padded SoA address of point t
    float x = pb[t * 3 + 0];
    float y = pb[t * 3 + 1];
    float z = pb[t * 3 + 2];
    spx[a] = x; spy[a] = y; spz[a] = z;
    ssq[a] = sq3(x, y, z);
  }
  __syncthreads();

  int q = qbase + (threadIdx.x >> 3);
  int c = threadIdx.x & 7;
  int qa = ((q >> 8) * CPAD) + (q & 255);
  float px = spx[qa], py = spy[qa], pz = spz[qa];
  float sqq = ssq[qa];

  int abase = c * CPAD;
  int j0 = c * CHSZ;

  unsigned int a0 = 0xFFFFFFFFu, a1 = 0xFFFFFFFFu, a2 = 0xFFFFFFFFu, a3 = 0xFFFFFFFFu;
  for (int jj = 0; jj < CHSZ; ++jj) {
    int a = abase + jj;
    int j = j0 + jj;
    float d2 = d2np(px, py, pz, sqq, spx[a], spy[a], spz[a], ssq[a]);
    unsigned int key = f2key(d2);
    if (j == q) key = 0xFFFFFFFFu;
    if (key < a3) {
      bool c3 = key < a2;
      a3 = c3 ? a2 : key;
      bool c2 = key < a1;
      a2 = c3 ? (c2 ? a1 : key) : a2;
      bool c1 = key < a0;
      a1 = c2 ? (c1 ? a0 : key) : a1;
      a0 = c1 ? key : a0;
    }
  }
  sred[threadIdx.x] = a3;
  __syncthreads();
  if (c == 0) {
    unsigned int m = sred[threadIdx.x];
#pragma unroll
    for (int u = 1; u < 8; ++u) {
      unsigned int v = sred[threadIdx.x + u];
      m = v > m ? v : m;
    }
    sred[threadIdx.x] = m;
  }
  __syncthreads();
  unsigned int T = sred[threadIdx.x & ~7];

  unsigned int ak[KMAX];
  int ai[KMAX];
#pragma unroll
  for (int k = 0; k < KMAX; ++k) { ak[k] = 0xFFFFFFFFu; ai[k] = 0xFFFF; }

  int sbase = threadIdx.x * CAP;
  auto drain = [&](int cnt2) {
    for (int u = 0; u < cnt2; ++u) {
      int jj2 = (int)sbuf[sbase + u];
      int a = abase + jj2;
      int j = j0 + jj2;
      float d2 = d2np(px, py, pz, sqq, spx[a], spy[a], spz[a], ssq[a]);
      unsigned int key = f2key(d2);               // self never buffered
      if (key < ak[KMAX - 1]) {                   // strict: stable ties -> lower j
#pragma unroll
        for (int k = KMAX - 1; k >= 1; --k) {
          bool ck  = key < ak[k];
          bool ckm = key < ak[k - 1];
          unsigned int tk = ckm ? ak[k - 1] : key;
          int          ti = ckm ? ai[k - 1] : j;
          ak[k] = ck ? tk : ak[k];
          ai[k] = ck ? ti : ai[k];
        }
        bool c0b = key < ak[0];
        ak[0] = c0b ? key : ak[0];
        ai[0] = c0b ? j : ai[0];
      }
    }
  };

  int cnt = 0;
  for (int jj = 0; jj < CHSZ; ++jj) {
    int a = abase + jj;
    int j = j0 + jj;
    float d2 = d2np(px, py, pz, sqq, spx[a], spy[a], spz[a], ssq[a]);
    unsigned int key = f2key(d2);
    if (j == q) key = 0xFFFFFFFFu;               // self fails gate (T < max)
    if (key <= T) {
      if (cnt == CAP) { drain(CAP); cnt = 0; }   // rare; preserves j order
      sbuf[sbase + cnt] = (unsigned short)jj;
      ++cnt;
    }
  }
  drain(cnt);

  size_t obase = (((size_t)(b * NN + q)) * CH + c) * KMAX;
  unsigned short* oc = cand + obase;
  unsigned int* ok = candk + obase;
#pragma unroll
  for (int k = 0; k < KMAX; ++k) {
    oc[k] = (unsigned short)ai[k];
    ok[k] = ak[k];
  }
}

// ---------------------------------------------------------------------------
// K1b: KNN phase 2 — 8-way merge. FROZEN R9 bytes.
// ---------------------------------------------------------------------------
__global__ __launch_bounds__(64) void knn_p2(const unsigned int* __restrict__ candk,
                                             const unsigned short* __restrict__ cand,
                                             int* __restrict__ nbr) {
  int q = blockIdx.x * 64 + threadIdx.x;         // global query id (b*NN+n)
  const unsigned int* k8 = candk + (size_t)q * (CH * KMAX);
  const unsigned short* i8 = cand + (size_t)q * (CH * KMAX);

  int head[CH];
  unsigned int hk[CH];
#pragma unroll
  for (int c = 0; c < CH; ++c) {
    head[c] = 0;
    hk[c] = k8[c * KMAX];
  }

  int* onb = nbr + (size_t)q * KMAX;
#pragma unroll
  for (int r = 0; r < KMAX; ++r) {
    int bc = 0;
    unsigned int bk = hk[0];
#pragma unroll
    for (int c = 1; c < CH; ++c) {
      if (hk[c] < bk) { bk = hk[c]; bc = c; }    // strict: ties -> lower c = lower j
    }
    onb[r] = (int)i8[bc * KMAX + head[bc]];
    ++head[bc];
    hk[bc] = (head[bc] < KMAX) ? k8[bc * KMAX + head[bc]] : 0xFFFFFFFFu;
  }
}

// ---------------------------------------------------------------------------
// K-cvt: f32 (len = gridDim*1024) -> bf16. Used for x->xb.
// ---------------------------------------------------------------------------
__global__ __launch_bounds__(256) void cvt_x(const float* __restrict__ x,
                                             unsigned short* __restrict__ xb) {
  int t = blockIdx.x * 256 + threadIdx.x;
  float4 v = *(const float4*)(x + (size_t)t * 4);
  unsigned short o[4] = {f2bf(v.x), f2bf(v.y), f2bf(v.z), f2bf(v.w)};
  *(ushort2*)(xb + (size_t)t * 4 + 0) = make_ushort2(o[0], o[1]);
  *(ushort2*)(xb + (size_t)t * 4 + 2) = make_ushort2(o[2], o[3]);
}

// ---------------------------------------------------------------------------
// K-wcvt: 8 weight matrices (f32) -> bf16 B-fragment order.
// z=0..5: W_src[0,1], W_lin[0,1], W_dst[0,1]; z=6: Wg rows 0..127; z=7: W1.
// ---------------------------------------------------------------------------
__global__ __launch_bounds__(256) void wcvt(const float* __restrict__ Wa,
                                            const float* __restrict__ Wb,
                                            const float* __restrict__ Wc,
                                            const float* __restrict__ Wgm,
                                            const float* __restrict__ W1m,
                                            unsigned short* __restrict__ wf) {
  int t = blockIdx.x * 256 + threadIdx.x;        // 0 .. 16383
  int lane = t & 63;
  int ks = (t >> 6) & 3;
  int nt = (t >> 8) & 7;
  int z = t >> 11;
  const float* W = (z < 2) ? (Wa + (size_t)z * CC * CC)
                 : (z < 4) ? (Wb + (size_t)(z - 2) * CC * CC)
                 : (z < 6) ? (Wc + (size_t)(z - 4) * CC * CC)
                 : (z == 6) ? Wgm : W1m;
  int n = nt * 16 + (lane & 15);
  int kb = ks * 32 + (lane >> 4) * 8;
  unsigned short* o = wf + (size_t)t * 8;
#pragma unroll
  for (int j = 0; j < 8; ++j)
    o[j] = f2bf(W[(size_t)(kb + j) * CC + n]);
}

// ---------------------------------------------------------------------------
// K2-epi: bf16 MFMA GEMM + bias + optional pos-tail + leaky, f32 out.
// Standalone uses: Wg (fallback) and W1 (both paths).
// ---------------------------------------------------------------------------
__global__ __launch_bounds__(256) void mfma_epi(const unsigned short* __restrict__ ain,
                                                const unsigned short* __restrict__ wz,
                                                const float* __restrict__ bias,
                                                const float* __restrict__ wgtail,
                                                const float* __restrict__ posf,
                                                float* __restrict__ out) {
  int wave = threadIdx.x >> 6;
  int lane = threadIdx.x & 63;
  int m0 = (blockIdx.x * 4 + wave) * 16;
  int quad = lane >> 4;
  int am = m0 + (lane & 15);

  f32x4 acc[8];
#pragma unroll
  for (int nt = 0; nt < 8; ++nt) acc[nt] = (f32x4){0.f, 0.f, 0.f, 0.f};

#pragma unroll
  for (int ks = 0; ks < 4; ++ks) {
    bf16x8 a = *(const bf16x8*)(ain + (size_t)am * CC + ks * 32 + quad * 8);
#pragma unroll
    for (int nt = 0; nt < 8; ++nt) {
      bf16x8 b = *(const bf16x8*)(wz + (size_t)(((nt * 4 + ks) * 64 + lane) * 8));
      acc[nt] = __builtin_amdgcn_mfma_f32_16x16x32_bf16(a, b, acc[nt], 0, 0, 0);
    }
  }

  float posr[4][3];
  if (wgtail) {
#pragma unroll
    for (int r = 0; r < 4; ++r) {
      int m = m0 + quad * 4 + r;
      posr[r][0] = posf[m * 3 + 0];
      posr[r][1] = posf[m * 3 + 1];
      posr[r][2] = posf[m * 3 + 2];
    }
  }

  int col0 = lane & 15;
#pragma unroll
  for (int nt = 0; nt < 8; ++nt) {
    int col = nt * 16 + col0;
    float bv = bias[col];
    float t0 = 0.f, t1 = 0.f, t2 = 0.f;
    if (wgtail) {
      t0 = wgtail[col];
      t1 = wgtail[CC + col];
      t2 = wgtail[2 * CC + col];
    }
#pragma unroll
    for (int r = 0; r < 4; ++r) {
      float v = acc[nt][r] + bv;
      if (wgtail)
        v += posr[r][0] * t0 + posr[r][1] * t1 + posr[r][2] * t2;
      v = v > 0.f ? v : NEG * v;
      out[(size_t)(m0 + quad * 4 + r) * CC + col] = v;
    }
  }
}

// ---------------------------------------------------------------------------
// K2-mfma (fallback path only): 6-proj MFMA, bf16 out.
// ---------------------------------------------------------------------------
__global__ __launch_bounds__(256) void mfma_proj(const unsigned short* __restrict__ xb,
                                                 const unsigned short* __restrict__ wf,
                                                 unsigned short* __restrict__ projb) {
  int z = blockIdx.z;
  unsigned short* out = projb + (size_t)z * ((size_t)BB * NN * CC);
  int wave = threadIdx.x >> 6;
  int lane = threadIdx.x & 63;
  int m0 = (blockIdx.x * 4 + wave) * 16;
  int quad = lane >> 4;
  int am = m0 + (lane & 15);

  f32x4 acc[8];
#pragma unroll
  for (int nt = 0; nt < 8; ++nt) acc[nt] = (f32x4){0.f, 0.f, 0.f, 0.f};

  const unsigned short* wz = wf + (size_t)z * (8 * 4 * 64 * 8);
#pragma unroll
  for (int ks = 0; ks < 4; ++ks) {
    bf16x8 a = *(const bf16x8*)(xb + (size_t)am * CC + ks * 32 + quad * 8);
#pragma unroll
    for (int nt = 0; nt < 8; ++nt) {
      bf16x8 b = *(const bf16x8*)(wz + (size_t)(((nt * 4 + ks) * 64 + lane) * 8));
      acc[nt] = __builtin_amdgcn_mfma_f32_16x16x32_bf16(a, b, acc[nt], 0, 0, 0);
    }
  }

  int col0 = lane & 15;
#pragma unroll
  for (int nt = 0; nt < 8; ++nt)
#pragma unroll
    for (int r = 0; r < 4; ++r)
      out[(size_t)(m0 + quad * 4 + r) * CC + nt * 16 + col0] = f2bf(acc[nt][r]);
}

// ---------------------------------------------------------------------------
// K3: fused attention — bf16 s/v/t inputs, both dilations, batch swizzle.
// Writes hb (bf16) directly: identical numerics to old f2bf(cvt of f32 h).
// ---------------------------------------------------------------------------
__global__ __launch_bounds__(128) void attn2_kernel(
    const float* __restrict__ pos, const int* __restrict__ nbr,
    const unsigned short* __restrict__ s0, const unsigned short* __restrict__ v0,
    const unsigned short* __restrict__ t0,
    const unsigned short* __restrict__ s1, const unsigned short* __restrict__ v1,
    const unsigned short* __restrict__ t1,
    const float* __restrict__ Wpos, const float* __restrict__ bpos,
    const float* __restrict__ h, unsigned short* __restrict__ hb) {
  int b = blockIdx.x & 7;                        // XCD-locality swizzle
  int n = blockIdx.x >> 3;
  int bn = (b << 11) + n;
  int c = threadIdx.x;

  const float* pb = pos + (size_t)b * NN * 3;
  float pix = pb[n * 3 + 0], piy = pb[n * 3 + 1], piz = pb[n * 3 + 2];
  const int* nb = nbr + (size_t)bn * KMAX;

  float ht = h[(size_t)bn * CC + c];             // h_in (Wg output, f32)

#pragma unroll
  for (int l = 0; l < 2; ++l) {
    int dil = l + 1;
    const unsigned short* s = l ? s1 : s0;
    const unsigned short* v = l ? v1 : v0;
    const unsigned short* t = l ? t1 : t0;
    const float* Wp = Wpos + (size_t)l * 3 * CC;
    float w0 = Wp[c], w1 = Wp[CC + c], w2 = Wp[2 * CC + c];
    float bp = bpos[(size_t)l * CC + c];
    float tc = bf2f(t[(size_t)bn * CC + c]);

    float alpha[17], del[17];
    float mx = -1e30f;
#pragma unroll
    for (int j = 0; j < 17; ++j) {
      int idx = (j < 16) ? nb[j * dil] : n;
      float dx = pix - pb[idx * 3 + 0];
      float dy = piy - pb[idx * 3 + 1];
      float dz = piz - pb[idx * 3 + 2];
      float d = dx * w0 + dy * w1 + dz * w2 + bp;
      del[j] = d;
      float sc = bf2f(s[((size_t)(b * NN + idx)) * CC + c]);
      float a = tc - sc + d;
      alpha[j] = a;
      mx = fmaxf(mx, a);
    }
    float sum = 0.f;
#pragma unroll
    for (int j = 0; j < 17; ++j) {
      float w = expf(alpha[j] - mx);
      alpha[j] = w;
      sum += w;
    }
    float inv = 1.f / sum;
    float hc = 0.f;
#pragma unroll
    for (int j = 0; j < 17; ++j) {
      int idx = (j < 16) ? nb[j * dil] : n;
      float vc = bf2f(v[((size_t)(b * NN + idx)) * CC + c]);
      hc += alpha[j] * (vc + del[j]);
    }
    ht += hc * inv;
  }

  hb[(size_t)bn * CC + c] = f2bf(ht);
}

// ---------------------------------------------------------------------------
// K5: out[m][0..2] = g[m] @ W2 + b2 + pos[m].  One wave per point.
// ---------------------------------------------------------------------------
__global__ __launch_bounds__(64) void final_kernel(
    const float* __restrict__ g, const float* __restrict__ W2,
    const float* __restrict__ b2, const float* __restrict__ pos,
    float* __restrict__ out) {
  int m = blockIdx.x;
  int k = threadIdx.x;
  float g0 = g[(size_t)m * CC + k];
  float g1 = g[(size_t)m * CC + 64 + k];
  float p0 = g0 * W2[k * 3 + 0] + g1 * W2[(k + 64) * 3 + 0];
  float p1 = g0 * W2[k * 3 + 1] + g1 * W2[(k + 64) * 3 + 1];
  float p2 = g0 * W2[k * 3 + 2] + g1 * W2[(k + 64) * 3 + 2];
#pragma unroll
  for (int off = 32; off >= 1; off >>= 1) {
    p0 += __shfl_down(p0, off);
    p1 += __shfl_down(p1, off);
    p2 += __shfl_down(p2, off);
  }
  if (k == 0) {
    out[m * 3 + 0] = p0 + b2[0] + pos[m * 3 + 0];
    out[m * 3 + 1] = p1 + b2[1] + pos[m * 3 + 1];
    out[m * 3 + 2] = p2 + b2[2] + pos[m * 3 + 2];
  }
}

extern "C" void kernel_launch(void* const* d_in, const int* in_sizes, int n_in,
                              void* d_out, int out_size, void* d_ws, size_t ws_size,
                              hipStream_t stream) {
  const float* x     = (const float*)d_in[0];
  const float* pos   = (const float*)d_in[1];
  const float* W_lin = (const float*)d_in[2];
  const float* W_src = (const float*)d_in[3];
  const float* W_dst = (const float*)d_in[4];
  const float* W_pos = (const float*)d_in[5];
  const float* b_pos = (const float*)d_in[6];
  const float* Wg    = (const float*)d_in[7];
  const float* bg    = (const float*)d_in[8];
  const float* W1    = (const float*)d_in[9];
  const float* b1    = (const float*)d_in[10];
  const float* W2    = (const float*)d_in[11];
  const float* b2    = (const float*)d_in[12];
  float* out = (float*)d_out;

  const size_t M = (size_t)BB * NN;        // 16384
  const size_t MC = M * CC;                // 2,097,152

  // Layout: nbr 2MB | cand 8.39MB | fb region:
  //   projb (bf16, 6*MC ushorts = fb[0..3MC))   -- s0,s1,v0,v1,t0,t1
  //   candk (u32,  fb[3MC..5MC))                -- no longer aliases h!
  //   h     (f32,  fb[5MC..6MC))
  //   g     (f32,  fb[6MC..7MC))
  // xb/wf beyond old BASE (offsets proven to fit by R15/R16 fused runs).
  char* ws = (char*)d_ws;
  int* nbr = (int*)ws;
  unsigned short* cand = (unsigned short*)(ws + M * KMAX * sizeof(int));
  float* fb = (float*)(ws + M * KMAX * sizeof(int) + M * CH * KMAX * sizeof(unsigned short));
  unsigned short* projb = (unsigned short*)fb;
  unsigned short* sb0 = projb + 0 * MC;
  unsigned short* sb1 = projb + 1 * MC;
  unsigned short* vb0 = projb + 2 * MC;
  unsigned short* vb1 = projb + 3 * MC;
  unsigned short* tb0 = projb + 4 * MC;
  unsigned short* tb1 = projb + 5 * MC;
  unsigned int* candk = (unsigned int*)(fb + 3 * MC);
  float* h = fb + 5 * MC;
  float* g = fb + 6 * MC;

  const size_t BASE = M * KMAX * sizeof(int) + M * CH * KMAX * sizeof(unsigned short)
                    + 8 * MC * sizeof(float);                 // R16-proven offset
  const size_t XB_BYTES = MC * sizeof(unsigned short);        // 4 MB
  const size_t WF_BYTES = 8 * 16384 * sizeof(unsigned short); // 256 KB
  const size_t FRAG = (size_t)(8 * 4 * 64 * 8);               // bf16 elems per weight
  bool fused_ok = ws_size >= BASE + XB_BYTES + WF_BYTES;

  if (fused_ok) {
    unsigned short* xb = (unsigned short*)(ws + BASE);
    unsigned short* wf = (unsigned short*)(ws + BASE + XB_BYTES);
    unsigned short* hb = xb;   // xb dead after fused_front's Wg-epi

    cvt_x<<<MC / 1024, 256, 0, stream>>>(x, xb);
    wcvt<<<64, 256, 0, stream>>>(W_src, W_lin, W_dst, Wg, W1, wf);
    // knn_p1 [0,512) + 6-proj bf16 [512,2048) + Wg-epi [2048,2304)
    fused_front<<<2304, 256, 0, stream>>>(pos, cand, candk, xb, wf, projb,
                                          Wg + 128 * CC, bg, h);
    knn_p2<<<256, 64, 0, stream>>>(candk, cand, nbr);

    // h += attention (bf16 s/v/t gathers); writes hb = bf16(h_out)
    attn2_kernel<<<M, 128, 0, stream>>>(pos, nbr, sb0, vb0, tb0,
                                        sb1, vb1, tb1, W_pos, b_pos, h, hb);

    // g = leaky(h@W1 + b1)  -- bf16 MFMA from hb
    mfma_epi<<<M / 64, 256, 0, stream>>>(hb, wf + 7 * FRAG, b1,
                                         nullptr, nullptr, g);

    final_kernel<<<M, 64, 0, stream>>>(g, W2, b2, pos, out);
  } else {
    // Fallback: sequential, same numerics. xb/wf alias cand (dead after p2).
    unsigned short* xb = cand;
    unsigned short* wf = cand + MC;
    unsigned short* hb = cand;  // reused again after Wg-epi consumes xb
    knn_p1<<<512, 256, 0, stream>>>(pos, cand, candk);
    knn_p2<<<256, 64, 0, stream>>>(candk, cand, nbr);
    cvt_x<<<MC / 1024, 256, 0, stream>>>(x, xb);
    wcvt<<<64, 256, 0, stream>>>(W_src, W_lin, W_dst, Wg, W1, wf);
    mfma_proj<<<dim3(M / 64, 1, 6), 256, 0, stream>>>(xb, wf, projb);
    mfma_epi<<<M / 64, 256, 0, stream>>>(xb, wf + 6 * FRAG, bg,
                                         Wg + 128 * CC, pos, h);
    attn2_kernel<<<M, 128, 0, stream>>>(pos, nbr, sb0, vb0, tb0,
                                        sb1, vb1, tb1, W_pos, b_pos, h, hb);
    mfma_epi<<<M / 64, 256, 0, stream>>>(hb, wf + 7 * FRAG, b1,
                                         nullptr, nullptr, g);
    final_kernel<<<M, 64, 0, stream>>>(g, W2, b2, pos, out);
  }
}